// Round 4
// baseline (469.827 us; speedup 1.0000x reference)
//
#include <hip/hip_runtime.h>
#include <math.h>

// Problem constants: B=2, L=2048, D=1024, H=16, hd=64, Dff=4096
#define SEQ_L 2048
#define DM    1024
#define NH    16
#define HD    64
#define BL    4096          // B*L
#define DFF   4096
#define QKV_S 3072          // fused qkv row stride

typedef __attribute__((ext_vector_type(8))) short short8;   // 8 bf16 (4 VGPRs)
typedef __attribute__((ext_vector_type(4))) short s16x4;    // 4 bf16
typedef __attribute__((ext_vector_type(4))) float f32x4;    // MFMA C/D frag
typedef __attribute__((ext_vector_type(4))) int   i32x4;    // 4 packed bf16x2

// 0.25*log2(e), 0.125*log2(e) — fold exp->exp2 base change into the scales
#define C_QK  0.36067376022224085f
#define C_K2  0.18033688011112042f

#if __has_builtin(__builtin_amdgcn_exp2f)
#define EXP2(x) __builtin_amdgcn_exp2f(x)
#else
#define EXP2(x) exp2f(x)
#endif

// fp32 -> bf16 round-to-nearest-even
__device__ __forceinline__ short f2bf(float x) {
    unsigned u = __float_as_uint(x);
    u += 0x7fff + ((u >> 16) & 1);
    return (short)(u >> 16);
}
__device__ __forceinline__ float bf2f(short s) {
    return __uint_as_float(((unsigned)(unsigned short)s) << 16);
}
// pack two f32 -> one u32 of 2x bf16 (RNE); no builtin on gfx950 (m240)
__device__ __forceinline__ int cvt_pk_bf16(float lo, float hi) {
    int r;
    asm("v_cvt_pk_bf16_f32 %0, %1, %2" : "=v"(r) : "v"(lo), "v"(hi));
    return r;
}

// branch-free GELU (erf form) via A&S 7.1.26, |abs err| <= ~2e-7.
__device__ __forceinline__ float gelu_fast(float x) {
    const float xa = fabsf(x);
    const float z = xa * 0.70710678118654752440f;
    const float t = __builtin_amdgcn_rcpf(fmaf(0.3275911f, z, 1.f));
    float P = fmaf(t, 1.061405429f, -1.453152027f);
    P = fmaf(t, P, 1.421413741f);
    P = fmaf(t, P, -0.284496736f);
    P = fmaf(t, P, 0.254829592f);
    P *= t;
    const float e = __expf(-z * z);
    const float erfp = fmaf(-P, e, 1.f);   // erf(|x|/sqrt2)
    return 0.5f * fmaf(xa, erfp, x);
}

__device__ __forceinline__ float block_sum(float v, float* red, int tid) {
#pragma unroll
    for (int m = 32; m; m >>= 1) v += __shfl_xor(v, m);
    if ((tid & 63) == 0) red[tid >> 6] = v;
    __syncthreads();
    v = red[0] + red[1] + red[2] + red[3];
    __syncthreads();
    return v;
}

// ---------------------------------------------------------------------------
// Weight fp32 -> bf16: wq|wk|wv|wo|w1|w2 contiguous (fused QKV needs this).
// ---------------------------------------------------------------------------
__global__ __launch_bounds__(256) void cvt6_kernel(
    const float* __restrict__ wq, const float* __restrict__ wk,
    const float* __restrict__ wv, const float* __restrict__ wo,
    const float* __restrict__ w1, const float* __restrict__ w2,
    short* __restrict__ dst) {
    const size_t i = (size_t)blockIdx.x * 256 + threadIdx.x;  // float4 index
    const float* src;
    size_t off;
    if (i < 1048576) {
        const int seg = (int)(i >> 18);
        off = i & 262143;
        src = seg == 0 ? wq : seg == 1 ? wk : seg == 2 ? wv : wo;
    } else if (i < 2097152) { src = w1; off = i - 1048576; }
    else                    { src = w2; off = i - 2097152; }
    const float4 v = ((const float4*)src)[off];
    const s16x4 o = {f2bf(v.x), f2bf(v.y), f2bf(v.z), f2bf(v.w)};
    ((s16x4*)dst)[i] = o;
}

// ---------------------------------------------------------------------------
// LayerNorm over rows of 1024, bf16 output.
// ---------------------------------------------------------------------------
__global__ __launch_bounds__(256) void ln_bf16_kernel(const float* __restrict__ x,
                                                      const float* __restrict__ g,
                                                      const float* __restrict__ b,
                                                      short* __restrict__ out) {
    const int row = blockIdx.x;
    const int tid = threadIdx.x;
    __shared__ float red[4];
    const float4 xv = *(const float4*)(x + (size_t)row * DM + tid * 4);
    float s = xv.x + xv.y + xv.z + xv.w;
    s = block_sum(s, red, tid);
    const float mean = s * (1.f / (float)DM);
    float dx0 = xv.x - mean, dx1 = xv.y - mean, dx2 = xv.z - mean, dx3 = xv.w - mean;
    float ss = dx0 * dx0 + dx1 * dx1 + dx2 * dx2 + dx3 * dx3;
    ss = block_sum(ss, red, tid);
    const float rs = 1.f / sqrtf(ss * (1.f / (float)DM) + 1e-5f);
    const float4 gv = *(const float4*)(g + tid * 4);
    const float4 bv = *(const float4*)(b + tid * 4);
    const s16x4 ob = {f2bf(dx0 * rs * gv.x + bv.x), f2bf(dx1 * rs * gv.y + bv.y),
                      f2bf(dx2 * rs * gv.z + bv.z), f2bf(dx3 * rs * gv.w + bv.w)};
    *(s16x4*)(out + (size_t)row * DM + tid * 4) = ob;
}

// ---------------------------------------------------------------------------
// Residual + Poincare projection (fp32, in-place safe)
// ---------------------------------------------------------------------------
__global__ __launch_bounds__(256) void resproj_kernel(const float* __restrict__ a,
                                                      const float* __restrict__ c,
                                                      float* __restrict__ out) {
    const int row = blockIdx.x;
    const int tid = threadIdx.x;
    __shared__ float red[4];
    const float4 av = *(const float4*)(a + (size_t)row * DM + tid * 4);
    const float4 cv = *(const float4*)(c + (size_t)row * DM + tid * 4);
    float4 sv;
    sv.x = av.x + cv.x; sv.y = av.y + cv.y; sv.z = av.z + cv.z; sv.w = av.w + cv.w;
    float ss = sv.x * sv.x + sv.y * sv.y + sv.z * sv.z + sv.w * sv.w;
    ss = block_sum(ss, red, tid);
    const float n = sqrtf(ss);
    const float mx = 1.f - 1e-5f;
    const float scale = (n > mx) ? (mx / fmaxf(n, 1e-12f)) : 1.f;
    sv.x *= scale; sv.y *= scale; sv.z *= scale; sv.w *= scale;
    *(float4*)(out + (size_t)row * DM + tid * 4) = sv;
}

// ---------------------------------------------------------------------------
// Residual + TWO split-K partials + Poincare projection (fp32, in-place safe).
// ---------------------------------------------------------------------------
__global__ __launch_bounds__(256) void resproj2_kernel(const float* __restrict__ a,
                                                       const float* __restrict__ c0,
                                                       const float* __restrict__ c1,
                                                       float* __restrict__ out) {
    const int row = blockIdx.x;
    const int tid = threadIdx.x;
    __shared__ float red[4];
    const float4 av = *(const float4*)(a + (size_t)row * DM + tid * 4);
    const float4 cv = *(const float4*)(c0 + (size_t)row * DM + tid * 4);
    const float4 dv = *(const float4*)(c1 + (size_t)row * DM + tid * 4);
    float4 sv;
    sv.x = av.x + cv.x + dv.x; sv.y = av.y + cv.y + dv.y;
    sv.z = av.z + cv.z + dv.z; sv.w = av.w + cv.w + dv.w;
    float ss = sv.x * sv.x + sv.y * sv.y + sv.z * sv.z + sv.w * sv.w;
    ss = block_sum(ss, red, tid);
    const float n = sqrtf(ss);
    const float mx = 1.f - 1e-5f;
    const float scale = (n > mx) ? (mx / fmaxf(n, 1e-12f)) : 1.f;
    sv.x *= scale; sv.y *= scale; sv.z *= scale; sv.w *= scale;
    *(float4*)(out + (size_t)row * DM + tid * 4) = sv;
}

// ---------------------------------------------------------------------------
// q/k prep: per-head Poincare projection + attention-layout bf16 buffers.
// k2 prescaled by 0.125*log2(e) so attention can use exp2 directly.
// ---------------------------------------------------------------------------
__global__ __launch_bounds__(256) void qk_prep(const short* __restrict__ qkvB,
                                               short* __restrict__ Qb,
                                               short* __restrict__ Kb,
                                               float* __restrict__ k2) {
    const int tid = threadIdx.x, lane = tid & 63;
    const int vec = blockIdx.x * 4 + (tid >> 6);
    const int row = vec >> 4, h = vec & 15;
    const int b = row >> 11, l = row & 2047;
    const size_t dstv = ((size_t)(b * NH + h) * SEQ_L + l) * HD + lane;
    const float mx = 1.f - 1e-5f;
    {   // q
        const float v = bf2f(qkvB[(size_t)row * QKV_S + h * HD + lane]);
        float s = v * v;
#pragma unroll
        for (int m = 32; m; m >>= 1) s += __shfl_xor(s, m);
        const float n = sqrtf(s);
        const float sc = (n > mx) ? (mx / fmaxf(n, 1e-12f)) : 1.f;
        Qb[dstv] = f2bf(v * sc);
    }
    {   // k (+ prescaled squared norm, in log2 units)
        const float v = bf2f(qkvB[(size_t)row * QKV_S + DM + h * HD + lane]);
        float s = v * v;
#pragma unroll
        for (int m = 32; m; m >>= 1) s += __shfl_xor(s, m);
        const float n = sqrtf(s);
        const float sc = (n > mx) ? (mx / fmaxf(n, 1e-12f)) : 1.f;
        Kb[dstv] = f2bf(v * sc);
        if (lane == 0) k2[(size_t)(b * NH + h) * SEQ_L + l] = s * sc * sc * C_K2;
    }
}

// ---------------------------------------------------------------------------
// v prep: transpose to Vtb [b][h][64 hd][L] bf16, with the columns of each
// 32-wide k-block interleaved as [g0 lo4 | g0 hi4 | g1 lo4 | g1 hi4 | ...]
// (orig col c*32 + 4g+t -> c*32 + 8g+t ; orig c*32+16+4g+t -> c*32+8g+4+t)
// so the attention PV A-fragment (lane g=lane>>4 needs orig cols
// {q4..q4+3, 16+q4..16+q4+3}) is ONE contiguous aligned 16B load.
// ---------------------------------------------------------------------------
__global__ __launch_bounds__(256) void v_prep(const short* __restrict__ qkvB,
                                              short* __restrict__ Vtb) {
    const int blk = blockIdx.x;
    const int bh = blk >> 5, kt = blk & 31;
    const int b = bh >> 4, h = bh & 15;
    __shared__ short T[64 * 72];
    const int tid = threadIdx.x;
    {
        const int key = tid >> 2, ch = (tid & 3) * 16;
        const size_t src = ((size_t)b * SEQ_L + kt * 64 + key) * QKV_S + 2 * DM + h * HD + ch;
        *(short8*)&T[key * 72 + ch]     = *(const short8*)(qkvB + src);
        *(short8*)&T[key * 72 + ch + 8] = *(const short8*)(qkvB + src + 8);
    }
    __syncthreads();
    const int hd = tid >> 2, kc = (tid & 3) * 16;
    short8 o0, o1;
#pragma unroll
    for (int j = 0; j < 8; ++j) {
        o0[j] = T[(kc + j) * 72 + hd];
        o1[j] = T[(kc + 8 + j) * 72 + hd];
    }
    const int c32 = (kc >> 5) * 32;          // which 32-block (0 or 32)
    const int h4  = ((kc >> 4) & 1) * 4;     // low/high half of the block
    short* dst = Vtb + ((size_t)bh * HD + hd) * SEQ_L + kt * 64 + c32 + h4;
    const s16x4 w0 = {o0[0], o0[1], o0[2], o0[3]};
    const s16x4 w1 = {o0[4], o0[5], o0[6], o0[7]};
    const s16x4 w2 = {o1[0], o1[1], o1[2], o1[3]};
    const s16x4 w3 = {o1[4], o1[5], o1[6], o1[7]};
    *(s16x4*)(dst)      = w0;
    *(s16x4*)(dst + 8)  = w1;
    *(s16x4*)(dst + 16) = w2;
    *(s16x4*)(dst + 24) = w3;
}

// ---------------------------------------------------------------------------
// bf16 MFMA NT GEMM with REGISTER-PREFETCH DOUBLE BUFFER.
// LDS rows padded to 40 shorts (80 B): 16B-aligned AND conflict-free
// (bank-word stride 20 -> exact 32-bank coverage per 8 rows, 2-way max).
// Split-K=2 (BM=128) for the N=1024 GEMMs; reduction fused into resproj2.
// ---------------------------------------------------------------------------
template <int BM, int ACT, int OUTBF, int FUSED, int SPLITK>
__global__ __launch_bounds__(256) void gemm_mfma(
    const short* __restrict__ A, const short* __restrict__ Bw,
    const float* __restrict__ bb0, const float* __restrict__ bb1,
    const float* __restrict__ bb2, void* __restrict__ Cout,
    void* __restrict__ Cout2,
    int M, int N, int K) {
    constexpr int RT = BM / 32;
    constexpr int LDSR = 40;      // padded LDS row, in shorts (80 B, 16B-aligned)
    constexpr bool VEPI = (OUTBF != 0) && (BM == 128);
    constexpr int STAGE_BYTES = (BM + 128) * LDSR * 2;
    constexpr int SMEM_BYTES = VEPI ? (4 * 64 * 72 * 2) : STAGE_BYTES;
    static_assert(!VEPI || SMEM_BYTES >= STAGE_BYTES, "VEPI smem too small");
    __shared__ __align__(16) char raw[SMEM_BYTES];
    short* As = (short*)raw;
    short* Bs = As + BM * LDSR;
    const int tid = threadIdx.x;
    const int wv = tid >> 6, lane = tid & 63;
    const int m0 = blockIdx.y * BM, n0 = blockIdx.x * 128;
    const int wr = (wv & 1) * (BM / 2);
    const int wc = (wv >> 1) * 64;

    const int z = (SPLITK > 1) ? blockIdx.z : 0;
    const int Kc = K / SPLITK;              // this block's K-chunk length

    const int arow = wv * (BM / 4) + (lane >> 2);
    const int brow = wv * 32 + (lane >> 2);
    const short* Ag = A + (size_t)(m0 + arow) * K + z * Kc + (lane & 3) * 8;
    const short* Bg = Bw + (size_t)(n0 + brow) * K + z * Kc + (lane & 3) * 8;
    short* AsW = As + (wv * (BM / 4) + (lane >> 2)) * LDSR + (lane & 3) * 8;
    short* AsW2 = AsW + 16 * LDSR;
    short* BsW = Bs + (wv * 32 + (lane >> 2)) * LDSR + (lane & 3) * 8;
    short* BsW2 = BsW + 16 * LDSR;

    const f32x4 z4 = {0.f, 0.f, 0.f, 0.f};
    f32x4 acc[RT][4];
#pragma unroll
    for (int r = 0; r < RT; ++r)
#pragma unroll
        for (int c = 0; c < 4; ++c) acc[r][c] = z4;

    const int lrow = lane & 15, kq = (lane >> 4) * 8;

    // prologue: tile 0 into regs
    short8 ra0, ra1, rb0, rb1;
    ra0 = *(const short8*)(Ag);
    if constexpr (BM == 128) ra1 = *(const short8*)(Ag + (size_t)16 * K);
    rb0 = *(const short8*)(Bg);
    rb1 = *(const short8*)(Bg + (size_t)16 * K);

    for (int kt = 0; kt < Kc; kt += 32) {
        __syncthreads();                    // previous tile's ds_reads complete
        *(short8*)AsW = ra0;                // vmcnt wait (issued last iter) here
        if constexpr (BM == 128) *(short8*)AsW2 = ra1;
        *(short8*)BsW = rb0;
        *(short8*)BsW2 = rb1;
        short8 na0, na1, nb0, nb1;
        if (kt + 32 < Kc) {                 // prefetch tile k+1 (in flight
            na0 = *(const short8*)(Ag + kt + 32);          //  through MFMAs)
            if constexpr (BM == 128) na1 = *(const short8*)(Ag + (size_t)16 * K + kt + 32);
            nb0 = *(const short8*)(Bg + kt + 32);
            nb1 = *(const short8*)(Bg + (size_t)16 * K + kt + 32);
        }
        __syncthreads();                    // LDS writes visible
        short8 af[RT], bf[4];
#pragma unroll
        for (int r = 0; r < RT; ++r)
            af[r] = *(const short8*)&As[(wr + r * 16 + lrow) * LDSR + kq];
#pragma unroll
        for (int c = 0; c < 4; ++c)
            bf[c] = *(const short8*)&Bs[(wc + c * 16 + lrow) * LDSR + kq];
#pragma unroll
        for (int r = 0; r < RT; ++r)
#pragma unroll
            for (int c = 0; c < 4; ++c)
                acc[r][c] = __builtin_amdgcn_mfma_f32_16x16x32_bf16(af[r], bf[c], acc[r][c], 0, 0, 0);
        ra0 = na0; ra1 = na1; rb0 = nb0; rb1 = nb1;
    }

    void* Cbase = Cout;
    if constexpr (SPLITK > 1) { if (z) Cbase = Cout2; }

    const int col = lane & 15, rb = (lane >> 4) * 4;
    if constexpr (VEPI) {
        __syncthreads();   // staging dead; reuse raw as per-wave transpose buffers
        short* Ot = (short*)raw + wv * (64 * 72);
#pragma unroll
        for (int c = 0; c < 4; ++c) {
            const int gn = n0 + wc + c * 16 + col;
            float bias;
            if constexpr (FUSED) {
                const int seg = gn >> 10;
                bias = (seg == 0 ? bb0 : seg == 1 ? bb1 : bb2)[gn & 1023];
            } else {
                bias = bb0[gn];
            }
#pragma unroll
            for (int r = 0; r < RT; ++r)
#pragma unroll
                for (int i = 0; i < 4; ++i) {
                    float v = acc[r][c][i] + bias;
                    if constexpr (ACT) v = gelu_fast(v);
                    Ot[(r * 16 + rb + i) * 72 + c * 16 + col] = f2bf(v);
                }
        }
        const int orow = lane >> 3, oc = (lane & 7) * 8;
#pragma unroll
        for (int it = 0; it < 8; ++it) {
            const short8 vv = *(const short8*)&Ot[(it * 8 + orow) * 72 + oc];
            *(short8*)((short*)Cbase + (size_t)(m0 + wr + it * 8 + orow) * N + n0 + wc + oc) = vv;
        }
    } else {
#pragma unroll
        for (int c = 0; c < 4; ++c) {
            const int gn = n0 + wc + c * 16 + col;
            float bias;
            if constexpr (FUSED) {
                const int seg = gn >> 10;
                bias = (seg == 0 ? bb0 : seg == 1 ? bb1 : bb2)[gn & 1023];
            } else {
                bias = bb0[gn];
            }
            if constexpr (SPLITK > 1) { if (z) bias = 0.f; }  // bias only in partial 0
#pragma unroll
            for (int r = 0; r < RT; ++r) {
                const int gm = m0 + wr + r * 16 + rb;
#pragma unroll
                for (int i = 0; i < 4; ++i) {
                    float v = acc[r][c][i] + bias;
                    if constexpr (ACT) v = gelu_fast(v);
                    if constexpr (OUTBF)
                        ((short*)Cbase)[(size_t)(gm + i) * N + gn] = f2bf(v);
                    else
                        ((float*)Cbase)[(size_t)(gm + i) * N + gn] = v;
                }
            }
        }
    }
}

// ---------------------------------------------------------------------------
// MFMA flash attention v4: BARRIER-FREE, direct-from-L1/L2 K/V fragments.
// Round-4 change: round 3 showed the LDS-staged pipeline is stall-bound
// (VALU 35%, MFMA 17%, ~48% neither -> barrier drains + LDS round-trip).
// K/V per (b,h) is 256 KB each (L2-fits); the block's 4 waves read the
// SAME 16 KB tile, so L1 (32 KB/CU) provides the intra-block sharing that
// LDS was doing, without any barriers (learn_hip m169: drop staging when
// data cache-fits). Per K-tile per wave: 8 K-loads + 8 V-loads (16 B each,
// independent -> pipelined through L1), no __syncthreads anywhere in the
// main loop; waves free-run. LDS is only the wave-private Ot transpose.
// Softmax: fixed max (scores bounded by Poincare ball), exp2 with folded
// log2(e); P packed via v_cvt_pk_bf16_f32; O^T = V^T.P^T.
// ---------------------------------------------------------------------------
__global__ __launch_bounds__(256) void attn_mfma2(const short* __restrict__ Qb,
                                                  const short* __restrict__ Kb,
                                                  const short* __restrict__ Vtb,
                                                  const float* __restrict__ k2v,
                                                  short* __restrict__ aO) {
    const int qt = blockIdx.x, h = blockIdx.y, b = blockIdx.z;
    const int tid = threadIdx.x, wv = tid >> 6, lane = tid & 63;
    const int bh = b * NH + h;
    __shared__ __align__(16) short smem[4 * 32 * 72];   // per-wave Ot buffers
    const int lrow = lane & 15, q8 = (lane >> 4) * 8, q4 = (lane >> 4) * 4;

    const short* Qh = Qb + (size_t)bh * SEQ_L * HD;
    const short* Kh = Kb + (size_t)bh * SEQ_L * HD;
    const short* Vh = Vtb + (size_t)bh * HD * SEQ_L;
    const float* k2p = k2v + (size_t)bh * SEQ_L;

    short8 qf[2][2];
#pragma unroll
    for (int nt = 0; nt < 2; ++nt)
#pragma unroll
        for (int kc = 0; kc < 2; ++kc)
            qf[nt][kc] = *(const short8*)(Qh +
                (size_t)(qt * 128 + wv * 32 + nt * 16 + lrow) * HD + kc * 32 + q8);

    const f32x4 z4 = {0.f, 0.f, 0.f, 0.f};
    f32x4 o[4][2];   // O^T accum: [ht(hd)][nt(qrow)]
#pragma unroll
    for (int ht = 0; ht < 4; ++ht)
#pragma unroll
        for (int nt = 0; nt < 2; ++nt) o[ht][nt] = z4;
    float lsum[2] = {0.f, 0.f};

    // per-lane base pointers for direct fragment loads
    const short* Kl = Kh + (size_t)lrow * HD + q8;        // + (k0+mt*16)*HD
    const short* Vl = Vh + (size_t)lrow * SEQ_L + q8;     // + ht*16*SEQ_L + k0 + c*32

    for (int kt = 0; kt < SEQ_L / 64; ++kt) {
        const int k0 = kt * 64;
        i32x4 pw[2][2];   // [nt][c] packed bf16 P fragments (short8 each)
#pragma unroll
        for (int mt = 0; mt < 4; ++mt) {
            const short* kr = Kl + (size_t)(k0 + mt * 16) * HD;
            const short8 kf0 = *(const short8*)(kr);
            const short8 kf1 = *(const short8*)(kr + 32);
            const float4 kk = *(const float4*)(k2p + k0 + mt * 16 + q4);
            const int c = mt >> 1, wb = (mt & 1) * 2;
#pragma unroll
            for (int nt = 0; nt < 2; ++nt) {
                f32x4 s = z4;
                s = __builtin_amdgcn_mfma_f32_16x16x32_bf16(kf0, qf[nt][0], s, 0, 0, 0);
                s = __builtin_amdgcn_mfma_f32_16x16x32_bf16(kf1, qf[nt][1], s, 0, 0, 0);
                const float p0 = EXP2(fmaf(s[0], C_QK, -kk.x));
                const float p1 = EXP2(fmaf(s[1], C_QK, -kk.y));
                const float p2 = EXP2(fmaf(s[2], C_QK, -kk.z));
                const float p3 = EXP2(fmaf(s[3], C_QK, -kk.w));
                lsum[nt] += (p0 + p1) + (p2 + p3);
                pw[nt][c][wb]     = cvt_pk_bf16(p0, p1);
                pw[nt][c][wb + 1] = cvt_pk_bf16(p2, p3);
            }
        }
#pragma unroll
        for (int ht = 0; ht < 4; ++ht) {
#pragma unroll
            for (int c = 0; c < 2; ++c) {
                const short8 v8 = *(const short8*)(Vl + (size_t)(ht * 16) * SEQ_L + k0 + c * 32);
#pragma unroll
                for (int nt = 0; nt < 2; ++nt)
                    o[ht][nt] = __builtin_amdgcn_mfma_f32_16x16x32_bf16(
                        v8, __builtin_bit_cast(short8, pw[nt][c]), o[ht][nt], 0, 0, 0);
            }
        }
    }

#pragma unroll
    for (int nt = 0; nt < 2; ++nt) {
        lsum[nt] += __shfl_xor(lsum[nt], 16);
        lsum[nt] += __shfl_xor(lsum[nt], 32);
    }
    const float inv0 = 1.f / lsum[0], inv1 = 1.f / lsum[1];

    // wave-private Ot transpose buffer: no barrier needed anywhere
    short* Ot = smem + wv * (32 * 72);
#pragma unroll
    for (int ht = 0; ht < 4; ++ht)
#pragma unroll
        for (int nt = 0; nt < 2; ++nt) {
            const float iv = nt ? inv1 : inv0;
            const s16x4 ov = {f2bf(o[ht][nt][0] * iv), f2bf(o[ht][nt][1] * iv),
                              f2bf(o[ht][nt][2] * iv), f2bf(o[ht][nt][3] * iv)};
            *(s16x4*)&Ot[(nt * 16 + lrow) * 72 + ht * 16 + q4] = ov;
        }
    const int erow = lane >> 1, ec = (lane & 1) * 32;
    const short8 r0 = *(const short8*)&Ot[erow * 72 + ec + 0];
    const short8 r1 = *(const short8*)&Ot[erow * 72 + ec + 8];
    const short8 r2 = *(const short8*)&Ot[erow * 72 + ec + 16];
    const short8 r3 = *(const short8*)&Ot[erow * 72 + ec + 24];
    short* dst = aO + ((size_t)b * SEQ_L + qt * 128 + wv * 32 + erow) * DM + h * HD + ec;
    *(short8*)(dst + 0)  = r0;
    *(short8*)(dst + 8)  = r1;
    *(short8*)(dst + 16) = r2;
    *(short8*)(dst + 24) = r3;
}

// ---------------------------------------------------------------------------
// Launch
// ---------------------------------------------------------------------------
extern "C" void kernel_launch(void* const* d_in, const int* in_sizes, int n_in,
                              void* d_out, int out_size, void* d_ws, size_t ws_size,
                              hipStream_t stream) {
    const float* x   = (const float*)d_in[0];
    const float* wq  = (const float*)d_in[1];
    const float* bq  = (const float*)d_in[2];
    const float* wk  = (const float*)d_in[3];
    const float* bk  = (const float*)d_in[4];
    const float* wv  = (const float*)d_in[5];
    const float* bv  = (const float*)d_in[6];
    const float* wo  = (const float*)d_in[7];
    const float* bo  = (const float*)d_in[8];
    const float* g1  = (const float*)d_in[9];
    const float* b1  = (const float*)d_in[10];
    const float* g2  = (const float*)d_in[11];
    const float* b2  = (const float*)d_in[12];
    const float* w1  = (const float*)d_in[13];
    const float* bf1 = (const float*)d_in[14];
    const float* w2  = (const float*)d_in[15];
    const float* bf2 = (const float*)d_in[16];
    float* out = (float*)d_out;

    // ws layout (MiB, all offsets within the previously-validated 80.25 MiB):
    // [0,24)    wbf bf16 weights (wq..wo [0,8), w1 [8,16), w2 [16,24))
    // [24,48)   qkvB bf16 [BL][3072]; later hbuf bf16 [BL][4096] = [24,56)
    // [24,40)   P  fp32 out-proj partial 0 (over dead qkvB)
    // [40,56)   P2 fp32 out-proj partial 1 (dead qkvB tail + dead Qb)
    // [48,56)   xnb/Qb (dead after attn)
    // [56,64)   Kb (dead after attn)     [64,72) Vtb/xn2b (dead after FFN1)
    // [72,72.25) k2   [72.25,80.25) aO (dead after out-proj)
    // [0,16)    y0 fp32 FFN2 partial 0 (over dead wq..wo,w1; w2 [16,24) live)
    // [56,72)   y1 fp32 FFN2 partial 1 (over dead Kb,Vtb)
    char* base = (char*)d_ws;
    short* wbf  = (short*)base;
    short* qkvB = (short*)(base + (24u << 20));
    short* xnb  = (short*)(base + (48u << 20));
    short* Qb   = xnb;
    short* Kb   = (short*)(base + (56u << 20));
    short* Vtb  = (short*)(base + (64u << 20));
    float* k2   = (float*)(base + (72u << 20));
    short* aO   = (short*)(base + (72u << 20) + (256u << 10));
    float* P    = (float*)(base + (24u << 20));
    float* P2   = (float*)(base + (40u << 20));
    short* xn2b = Vtb;
    short* hbuf = qkvB;
    float* y0   = (float*)base;                     // FFN2 partial 0
    float* y1   = (float*)(base + (56u << 20));     // FFN2 partial 1

    // 0. weights -> bf16
    cvt6_kernel<<<12288, 256, 0, stream>>>(wq, wk, wv, wo, w1, w2, wbf);
    // 1. LN1 -> bf16
    ln_bf16_kernel<<<BL, 256, 0, stream>>>(x, g1, b1, xnb);
    // 2. fused QKV projection -> bf16 [BL][3072]
    gemm_mfma<128, 0, 1, 1, 1><<<dim3(24, 32), 256, 0, stream>>>(
        xnb, wbf, bq, bk, bv, qkvB, nullptr, BL, QKV_S, DM);
    // 3. prep: project q,k -> Qb/Kb [bh][L][64] + k2; transpose v -> Vtb
    qk_prep<<<16384, 256, 0, stream>>>(qkvB, Qb, Kb, k2);
    v_prep<<<1024, 256, 0, stream>>>(qkvB, Vtb);
    // 4. flash MFMA attention -> aO bf16
    attn_mfma2<<<dim3(16, 16, 2), 256, 0, stream>>>(Qb, Kb, Vtb, k2, aO);
    // 5. output projection, BM=128 split-K=2 -> P,P2 fp32 partials
    gemm_mfma<128, 0, 0, 0, 2><<<dim3(8, 32, 2), 256, 0, stream>>>(
        aO, wbf + 3145728, bo, bo, bo, P, P2, BL, DM, DM);
    // 6. x1 = project(x + P + P2) -> d_out
    resproj2_kernel<<<BL, 256, 0, stream>>>(x, P, P2, out);
    // 7. LN2 -> bf16
    ln_bf16_kernel<<<BL, 256, 0, stream>>>(out, g2, b2, xn2b);
    // 8. FFN1 + GELU -> bf16 hidden
    gemm_mfma<128, 1, 1, 0, 1><<<dim3(32, 32), 256, 0, stream>>>(
        xn2b, wbf + 4194304, bf1, bf1, bf1, hbuf, nullptr, BL, DFF, DM);
    // 9. FFN2, BM=128 split-K=2 -> y0,y1 fp32 partials
    gemm_mfma<128, 0, 0, 0, 2><<<dim3(8, 32, 2), 256, 0, stream>>>(
        hbuf, wbf + 8388608, bf2, bf2, bf2, y0, y1, BL, DM, DFF);
    // 10. out = project(x1 + y0 + y1)
    resproj2_kernel<<<BL, 256, 0, stream>>>(out, y0, y1, out);
}

// Round 5
// 384.879 us; speedup vs baseline: 1.2207x; 1.2207x over previous
//
#include <hip/hip_runtime.h>
#include <math.h>

// Problem constants: B=2, L=2048, D=1024, H=16, hd=64, Dff=4096
#define SEQ_L 2048
#define DM    1024
#define NH    16
#define HD    64
#define BL    4096          // B*L
#define DFF   4096
#define QKV_S 3072          // fused qkv row stride

typedef __attribute__((ext_vector_type(8))) short short8;   // 8 bf16 (4 VGPRs)
typedef __attribute__((ext_vector_type(4))) short s16x4;    // 4 bf16
typedef __attribute__((ext_vector_type(4))) float f32x4;    // MFMA C/D frag
typedef __attribute__((ext_vector_type(4))) int   i32x4;    // 4 packed bf16x2

// 0.25*log2(e), 0.125*log2(e) — fold exp->exp2 base change into the scales
#define C_QK  0.36067376022224085f
#define C_K2  0.18033688011112042f

#if __has_builtin(__builtin_amdgcn_exp2f)
#define EXP2(x) __builtin_amdgcn_exp2f(x)
#else
#define EXP2(x) exp2f(x)
#endif

// fp32 -> bf16 round-to-nearest-even
__device__ __forceinline__ short f2bf(float x) {
    unsigned u = __float_as_uint(x);
    u += 0x7fff + ((u >> 16) & 1);
    return (short)(u >> 16);
}
__device__ __forceinline__ float bf2f(short s) {
    return __uint_as_float(((unsigned)(unsigned short)s) << 16);
}
// pack two f32 -> one u32 of 2x bf16 (RNE); no builtin on gfx950 (m240)
__device__ __forceinline__ int cvt_pk_bf16(float lo, float hi) {
    int r;
    asm("v_cvt_pk_bf16_f32 %0, %1, %2" : "=v"(r) : "v"(lo), "v"(hi));
    return r;
}

// branch-free GELU (erf form) via A&S 7.1.26, |abs err| <= ~2e-7.
__device__ __forceinline__ float gelu_fast(float x) {
    const float xa = fabsf(x);
    const float z = xa * 0.70710678118654752440f;
    const float t = __builtin_amdgcn_rcpf(fmaf(0.3275911f, z, 1.f));
    float P = fmaf(t, 1.061405429f, -1.453152027f);
    P = fmaf(t, P, 1.421413741f);
    P = fmaf(t, P, -0.284496736f);
    P = fmaf(t, P, 0.254829592f);
    P *= t;
    const float e = __expf(-z * z);
    const float erfp = fmaf(-P, e, 1.f);   // erf(|x|/sqrt2)
    return 0.5f * fmaf(xa, erfp, x);
}

__device__ __forceinline__ float block_sum(float v, float* red, int tid) {
#pragma unroll
    for (int m = 32; m; m >>= 1) v += __shfl_xor(v, m);
    if ((tid & 63) == 0) red[tid >> 6] = v;
    __syncthreads();
    v = red[0] + red[1] + red[2] + red[3];
    __syncthreads();
    return v;
}

// ---------------------------------------------------------------------------
// Weight fp32 -> bf16: wq|wk|wv|wo|w1|w2 contiguous (fused QKV needs this).
// ---------------------------------------------------------------------------
__global__ __launch_bounds__(256) void cvt6_kernel(
    const float* __restrict__ wq, const float* __restrict__ wk,
    const float* __restrict__ wv, const float* __restrict__ wo,
    const float* __restrict__ w1, const float* __restrict__ w2,
    short* __restrict__ dst) {
    const size_t i = (size_t)blockIdx.x * 256 + threadIdx.x;  // float4 index
    const float* src;
    size_t off;
    if (i < 1048576) {
        const int seg = (int)(i >> 18);
        off = i & 262143;
        src = seg == 0 ? wq : seg == 1 ? wk : seg == 2 ? wv : wo;
    } else if (i < 2097152) { src = w1; off = i - 1048576; }
    else                    { src = w2; off = i - 2097152; }
    const float4 v = ((const float4*)src)[off];
    const s16x4 o = {f2bf(v.x), f2bf(v.y), f2bf(v.z), f2bf(v.w)};
    ((s16x4*)dst)[i] = o;
}

// ---------------------------------------------------------------------------
// LayerNorm over rows of 1024, bf16 output.
// ---------------------------------------------------------------------------
__global__ __launch_bounds__(256) void ln_bf16_kernel(const float* __restrict__ x,
                                                      const float* __restrict__ g,
                                                      const float* __restrict__ b,
                                                      short* __restrict__ out) {
    const int row = blockIdx.x;
    const int tid = threadIdx.x;
    __shared__ float red[4];
    const float4 xv = *(const float4*)(x + (size_t)row * DM + tid * 4);
    float s = xv.x + xv.y + xv.z + xv.w;
    s = block_sum(s, red, tid);
    const float mean = s * (1.f / (float)DM);
    float dx0 = xv.x - mean, dx1 = xv.y - mean, dx2 = xv.z - mean, dx3 = xv.w - mean;
    float ss = dx0 * dx0 + dx1 * dx1 + dx2 * dx2 + dx3 * dx3;
    ss = block_sum(ss, red, tid);
    const float rs = 1.f / sqrtf(ss * (1.f / (float)DM) + 1e-5f);
    const float4 gv = *(const float4*)(g + tid * 4);
    const float4 bv = *(const float4*)(b + tid * 4);
    const s16x4 ob = {f2bf(dx0 * rs * gv.x + bv.x), f2bf(dx1 * rs * gv.y + bv.y),
                      f2bf(dx2 * rs * gv.z + bv.z), f2bf(dx3 * rs * gv.w + bv.w)};
    *(s16x4*)(out + (size_t)row * DM + tid * 4) = ob;
}

// ---------------------------------------------------------------------------
// Residual + Poincare projection (fp32, in-place safe)
// ---------------------------------------------------------------------------
__global__ __launch_bounds__(256) void resproj_kernel(const float* __restrict__ a,
                                                      const float* __restrict__ c,
                                                      float* __restrict__ out) {
    const int row = blockIdx.x;
    const int tid = threadIdx.x;
    __shared__ float red[4];
    const float4 av = *(const float4*)(a + (size_t)row * DM + tid * 4);
    const float4 cv = *(const float4*)(c + (size_t)row * DM + tid * 4);
    float4 sv;
    sv.x = av.x + cv.x; sv.y = av.y + cv.y; sv.z = av.z + cv.z; sv.w = av.w + cv.w;
    float ss = sv.x * sv.x + sv.y * sv.y + sv.z * sv.z + sv.w * sv.w;
    ss = block_sum(ss, red, tid);
    const float n = sqrtf(ss);
    const float mx = 1.f - 1e-5f;
    const float scale = (n > mx) ? (mx / fmaxf(n, 1e-12f)) : 1.f;
    sv.x *= scale; sv.y *= scale; sv.z *= scale; sv.w *= scale;
    *(float4*)(out + (size_t)row * DM + tid * 4) = sv;
}

// ---------------------------------------------------------------------------
// Residual + TWO split-K partials + Poincare projection (fp32, in-place safe).
// ---------------------------------------------------------------------------
__global__ __launch_bounds__(256) void resproj2_kernel(const float* __restrict__ a,
                                                       const float* __restrict__ c0,
                                                       const float* __restrict__ c1,
                                                       float* __restrict__ out) {
    const int row = blockIdx.x;
    const int tid = threadIdx.x;
    __shared__ float red[4];
    const float4 av = *(const float4*)(a + (size_t)row * DM + tid * 4);
    const float4 cv = *(const float4*)(c0 + (size_t)row * DM + tid * 4);
    const float4 dv = *(const float4*)(c1 + (size_t)row * DM + tid * 4);
    float4 sv;
    sv.x = av.x + cv.x + dv.x; sv.y = av.y + cv.y + dv.y;
    sv.z = av.z + cv.z + dv.z; sv.w = av.w + cv.w + dv.w;
    float ss = sv.x * sv.x + sv.y * sv.y + sv.z * sv.z + sv.w * sv.w;
    ss = block_sum(ss, red, tid);
    const float n = sqrtf(ss);
    const float mx = 1.f - 1e-5f;
    const float scale = (n > mx) ? (mx / fmaxf(n, 1e-12f)) : 1.f;
    sv.x *= scale; sv.y *= scale; sv.z *= scale; sv.w *= scale;
    *(float4*)(out + (size_t)row * DM + tid * 4) = sv;
}

// ---------------------------------------------------------------------------
// q/k prep: per-head Poincare projection + attention-layout bf16 buffers.
// k2 prescaled by 0.125*log2(e) so attention can use exp2 directly.
// ---------------------------------------------------------------------------
__global__ __launch_bounds__(256) void qk_prep(const short* __restrict__ qkvB,
                                               short* __restrict__ Qb,
                                               short* __restrict__ Kb,
                                               float* __restrict__ k2) {
    const int tid = threadIdx.x, lane = tid & 63;
    const int vec = blockIdx.x * 4 + (tid >> 6);
    const int row = vec >> 4, h = vec & 15;
    const int b = row >> 11, l = row & 2047;
    const size_t dstv = ((size_t)(b * NH + h) * SEQ_L + l) * HD + lane;
    const float mx = 1.f - 1e-5f;
    {   // q
        const float v = bf2f(qkvB[(size_t)row * QKV_S + h * HD + lane]);
        float s = v * v;
#pragma unroll
        for (int m = 32; m; m >>= 1) s += __shfl_xor(s, m);
        const float n = sqrtf(s);
        const float sc = (n > mx) ? (mx / fmaxf(n, 1e-12f)) : 1.f;
        Qb[dstv] = f2bf(v * sc);
    }
    {   // k (+ prescaled squared norm, in log2 units)
        const float v = bf2f(qkvB[(size_t)row * QKV_S + DM + h * HD + lane]);
        float s = v * v;
#pragma unroll
        for (int m = 32; m; m >>= 1) s += __shfl_xor(s, m);
        const float n = sqrtf(s);
        const float sc = (n > mx) ? (mx / fmaxf(n, 1e-12f)) : 1.f;
        Kb[dstv] = f2bf(v * sc);
        if (lane == 0) k2[(size_t)(b * NH + h) * SEQ_L + l] = s * sc * sc * C_K2;
    }
}

// ---------------------------------------------------------------------------
// v prep: transpose to Vtb [b][h][64 hd][L] bf16, with the columns of each
// 32-wide k-block interleaved as [g0 lo4 | g0 hi4 | g1 lo4 | g1 hi4 | ...]
// (orig col c*32 + 4g+t -> c*32 + 8g+t ; orig c*32+16+4g+t -> c*32+8g+4+t)
// so the attention PV A-fragment (lane g=lane>>4 needs orig cols
// {q4..q4+3, 16+q4..16+q4+3}) is ONE contiguous aligned 16B load.
// ---------------------------------------------------------------------------
__global__ __launch_bounds__(256) void v_prep(const short* __restrict__ qkvB,
                                              short* __restrict__ Vtb) {
    const int blk = blockIdx.x;
    const int bh = blk >> 5, kt = blk & 31;
    const int b = bh >> 4, h = bh & 15;
    __shared__ short T[64 * 72];
    const int tid = threadIdx.x;
    {
        const int key = tid >> 2, ch = (tid & 3) * 16;
        const size_t src = ((size_t)b * SEQ_L + kt * 64 + key) * QKV_S + 2 * DM + h * HD + ch;
        *(short8*)&T[key * 72 + ch]     = *(const short8*)(qkvB + src);
        *(short8*)&T[key * 72 + ch + 8] = *(const short8*)(qkvB + src + 8);
    }
    __syncthreads();
    const int hd = tid >> 2, kc = (tid & 3) * 16;
    short8 o0, o1;
#pragma unroll
    for (int j = 0; j < 8; ++j) {
        o0[j] = T[(kc + j) * 72 + hd];
        o1[j] = T[(kc + 8 + j) * 72 + hd];
    }
    const int c32 = (kc >> 5) * 32;          // which 32-block (0 or 32)
    const int h4  = ((kc >> 4) & 1) * 4;     // low/high half of the block
    short* dst = Vtb + ((size_t)bh * HD + hd) * SEQ_L + kt * 64 + c32 + h4;
    const s16x4 w0 = {o0[0], o0[1], o0[2], o0[3]};
    const s16x4 w1 = {o0[4], o0[5], o0[6], o0[7]};
    const s16x4 w2 = {o1[0], o1[1], o1[2], o1[3]};
    const s16x4 w3 = {o1[4], o1[5], o1[6], o1[7]};
    *(s16x4*)(dst)      = w0;
    *(s16x4*)(dst + 8)  = w1;
    *(s16x4*)(dst + 16) = w2;
    *(s16x4*)(dst + 24) = w3;
}

// ---------------------------------------------------------------------------
// bf16 MFMA NT GEMM with REGISTER-PREFETCH DOUBLE BUFFER.
// LDS rows padded to 40 shorts (80 B): 16B-aligned AND conflict-free
// (bank-word stride 20 -> exact 32-bank coverage per 8 rows, 2-way max).
// Split-K=2 (BM=128) for the N=1024 GEMMs; reduction fused into resproj2.
// ---------------------------------------------------------------------------
template <int BM, int ACT, int OUTBF, int FUSED, int SPLITK>
__global__ __launch_bounds__(256) void gemm_mfma(
    const short* __restrict__ A, const short* __restrict__ Bw,
    const float* __restrict__ bb0, const float* __restrict__ bb1,
    const float* __restrict__ bb2, void* __restrict__ Cout,
    void* __restrict__ Cout2,
    int M, int N, int K) {
    constexpr int RT = BM / 32;
    constexpr int LDSR = 40;      // padded LDS row, in shorts (80 B, 16B-aligned)
    constexpr bool VEPI = (OUTBF != 0) && (BM == 128);
    constexpr int STAGE_BYTES = (BM + 128) * LDSR * 2;
    constexpr int SMEM_BYTES = VEPI ? (4 * 64 * 72 * 2) : STAGE_BYTES;
    static_assert(!VEPI || SMEM_BYTES >= STAGE_BYTES, "VEPI smem too small");
    __shared__ __align__(16) char raw[SMEM_BYTES];
    short* As = (short*)raw;
    short* Bs = As + BM * LDSR;
    const int tid = threadIdx.x;
    const int wv = tid >> 6, lane = tid & 63;
    const int m0 = blockIdx.y * BM, n0 = blockIdx.x * 128;
    const int wr = (wv & 1) * (BM / 2);
    const int wc = (wv >> 1) * 64;

    const int z = (SPLITK > 1) ? blockIdx.z : 0;
    const int Kc = K / SPLITK;              // this block's K-chunk length

    const int arow = wv * (BM / 4) + (lane >> 2);
    const int brow = wv * 32 + (lane >> 2);
    const short* Ag = A + (size_t)(m0 + arow) * K + z * Kc + (lane & 3) * 8;
    const short* Bg = Bw + (size_t)(n0 + brow) * K + z * Kc + (lane & 3) * 8;
    short* AsW = As + (wv * (BM / 4) + (lane >> 2)) * LDSR + (lane & 3) * 8;
    short* AsW2 = AsW + 16 * LDSR;
    short* BsW = Bs + (wv * 32 + (lane >> 2)) * LDSR + (lane & 3) * 8;
    short* BsW2 = BsW + 16 * LDSR;

    const f32x4 z4 = {0.f, 0.f, 0.f, 0.f};
    f32x4 acc[RT][4];
#pragma unroll
    for (int r = 0; r < RT; ++r)
#pragma unroll
        for (int c = 0; c < 4; ++c) acc[r][c] = z4;

    const int lrow = lane & 15, kq = (lane >> 4) * 8;

    // prologue: tile 0 into regs
    short8 ra0, ra1, rb0, rb1;
    ra0 = *(const short8*)(Ag);
    if constexpr (BM == 128) ra1 = *(const short8*)(Ag + (size_t)16 * K);
    rb0 = *(const short8*)(Bg);
    rb1 = *(const short8*)(Bg + (size_t)16 * K);

    for (int kt = 0; kt < Kc; kt += 32) {
        __syncthreads();                    // previous tile's ds_reads complete
        *(short8*)AsW = ra0;                // vmcnt wait (issued last iter) here
        if constexpr (BM == 128) *(short8*)AsW2 = ra1;
        *(short8*)BsW = rb0;
        *(short8*)BsW2 = rb1;
        short8 na0, na1, nb0, nb1;
        if (kt + 32 < Kc) {                 // prefetch tile k+1 (in flight
            na0 = *(const short8*)(Ag + kt + 32);          //  through MFMAs)
            if constexpr (BM == 128) na1 = *(const short8*)(Ag + (size_t)16 * K + kt + 32);
            nb0 = *(const short8*)(Bg + kt + 32);
            nb1 = *(const short8*)(Bg + (size_t)16 * K + kt + 32);
        }
        __syncthreads();                    // LDS writes visible
        short8 af[RT], bf[4];
#pragma unroll
        for (int r = 0; r < RT; ++r)
            af[r] = *(const short8*)&As[(wr + r * 16 + lrow) * LDSR + kq];
#pragma unroll
        for (int c = 0; c < 4; ++c)
            bf[c] = *(const short8*)&Bs[(wc + c * 16 + lrow) * LDSR + kq];
#pragma unroll
        for (int r = 0; r < RT; ++r)
#pragma unroll
            for (int c = 0; c < 4; ++c)
                acc[r][c] = __builtin_amdgcn_mfma_f32_16x16x32_bf16(af[r], bf[c], acc[r][c], 0, 0, 0);
        ra0 = na0; ra1 = na1; rb0 = nb0; rb1 = nb1;
    }

    void* Cbase = Cout;
    if constexpr (SPLITK > 1) { if (z) Cbase = Cout2; }

    const int col = lane & 15, rb = (lane >> 4) * 4;
    if constexpr (VEPI) {
        __syncthreads();   // staging dead; reuse raw as per-wave transpose buffers
        short* Ot = (short*)raw + wv * (64 * 72);
#pragma unroll
        for (int c = 0; c < 4; ++c) {
            const int gn = n0 + wc + c * 16 + col;
            float bias;
            if constexpr (FUSED) {
                const int seg = gn >> 10;
                bias = (seg == 0 ? bb0 : seg == 1 ? bb1 : bb2)[gn & 1023];
            } else {
                bias = bb0[gn];
            }
#pragma unroll
            for (int r = 0; r < RT; ++r)
#pragma unroll
                for (int i = 0; i < 4; ++i) {
                    float v = acc[r][c][i] + bias;
                    if constexpr (ACT) v = gelu_fast(v);
                    Ot[(r * 16 + rb + i) * 72 + c * 16 + col] = f2bf(v);
                }
        }
        const int orow = lane >> 3, oc = (lane & 7) * 8;
#pragma unroll
        for (int it = 0; it < 8; ++it) {
            const short8 vv = *(const short8*)&Ot[(it * 8 + orow) * 72 + oc];
            *(short8*)((short*)Cbase + (size_t)(m0 + wr + it * 8 + orow) * N + n0 + wc + oc) = vv;
        }
    } else {
#pragma unroll
        for (int c = 0; c < 4; ++c) {
            const int gn = n0 + wc + c * 16 + col;
            float bias;
            if constexpr (FUSED) {
                const int seg = gn >> 10;
                bias = (seg == 0 ? bb0 : seg == 1 ? bb1 : bb2)[gn & 1023];
            } else {
                bias = bb0[gn];
            }
            if constexpr (SPLITK > 1) { if (z) bias = 0.f; }  // bias only in partial 0
#pragma unroll
            for (int r = 0; r < RT; ++r) {
                const int gm = m0 + wr + r * 16 + rb;
#pragma unroll
                for (int i = 0; i < 4; ++i) {
                    float v = acc[r][c][i] + bias;
                    if constexpr (ACT) v = gelu_fast(v);
                    if constexpr (OUTBF)
                        ((short*)Cbase)[(size_t)(gm + i) * N + gn] = f2bf(v);
                    else
                        ((float*)Cbase)[(size_t)(gm + i) * N + gn] = v;
                }
            }
        }
    }
}

// ---------------------------------------------------------------------------
// MFMA flash attention v5: LDS double-buffer, ONE barrier per K/V tile.
// Round-5 schedule fix (r3's 2-barrier loop drained vmcnt(0) right after
// issuing the prefetch -> full latency exposed; r4's no-LDS direct loads
// were latency-bound at 2 waves/SIMD):
//   issue global loads for tile t+1 -> compute tile t from buf[t&1]
//   -> ds_write tile t+1 into buf[(t+1)&1] (vmcnt wait lands HERE, after
//   ~500 cyc of MFMA+softmax) -> ONE __syncthreads.
// k2 is staged to LDS once per block: in-loop vmem = prefetch loads only,
// so no mid-compute vmcnt drain (vmcnt is issue-ordered; a younger k2
// load would otherwise force draining the prefetch).
// Softmax: fixed max (Poincare-bounded scores), exp2 with folded log2(e),
// P packed via v_cvt_pk_bf16_f32, single-load interleaved V fragments.
// ---------------------------------------------------------------------------
__global__ __launch_bounds__(256) void attn_mfma2(const short* __restrict__ Qb,
                                                  const short* __restrict__ Kb,
                                                  const short* __restrict__ Vtb,
                                                  const float* __restrict__ k2v,
                                                  short* __restrict__ aO) {
    const int qt = blockIdx.x, h = blockIdx.y, b = blockIdx.z;
    const int tid = threadIdx.x, wv = tid >> 6, lane = tid & 63;
    const int bh = b * NH + h;
    constexpr int NT = SEQ_L / 64;
    constexpr int BUFS = 64 * 72;    // shorts per K (or V) tile buffer
    __shared__ __align__(16) short smem[4 * BUFS];  // {K,V} x double buffer; Ot reuse
    __shared__ __align__(16) float k2s[SEQ_L];
    const int lrow = lane & 15, q8 = (lane >> 4) * 8, q4 = (lane >> 4) * 4;

    const short* Qh = Qb + (size_t)bh * SEQ_L * HD;
    const short* Kh = Kb + (size_t)bh * SEQ_L * HD;
    const short* Vh = Vtb + (size_t)bh * HD * SEQ_L;
    const float* k2p = k2v + (size_t)bh * SEQ_L;

    short8 qf[2][2];
#pragma unroll
    for (int nt = 0; nt < 2; ++nt)
#pragma unroll
        for (int kc = 0; kc < 2; ++kc)
            qf[nt][kc] = *(const short8*)(Qh +
                (size_t)(qt * 128 + wv * 32 + nt * 16 + lrow) * HD + kc * 32 + q8);

    // k2 -> LDS (2048 floats, 8 per thread)
    {
        const float4 a0 = *(const float4*)(k2p + tid * 4);
        const float4 a1 = *(const float4*)(k2p + 1024 + tid * 4);
        *(float4*)&k2s[tid * 4] = a0;
        *(float4*)&k2s[1024 + tid * 4] = a1;
    }

    const int srow = tid >> 2, sch = (tid & 3) * 16;
    const short* gK = Kh + (size_t)srow * HD + sch;      // + (k0)*HD per tile
    const short* gV = Vh + (size_t)srow * SEQ_L + sch;   // + k0 per tile
    const int woff = srow * 72 + sch;

    // prologue: stage tile 0 into buf 0
    {
        const short8 k0a = *(const short8*)(gK);
        const short8 k0b = *(const short8*)(gK + 8);
        const short8 v0a = *(const short8*)(gV);
        const short8 v0b = *(const short8*)(gV + 8);
        *(short8*)&smem[woff]            = k0a;
        *(short8*)&smem[woff + 8]        = k0b;
        *(short8*)&smem[BUFS + woff]     = v0a;
        *(short8*)&smem[BUFS + woff + 8] = v0b;
    }
    __syncthreads();

    const f32x4 z4 = {0.f, 0.f, 0.f, 0.f};
    f32x4 o[4][2];   // O^T accum: [ht(hd)][nt(qrow)]
#pragma unroll
    for (int ht = 0; ht < 4; ++ht)
#pragma unroll
        for (int nt = 0; nt < 2; ++nt) o[ht][nt] = z4;
    float lsum[2] = {0.f, 0.f};

    for (int kt = 0; kt < NT; ++kt) {
        const int k0 = kt * 64;
        const short* Ks = smem + (kt & 1) * (2 * BUFS);
        const short* Vt = Ks + BUFS;
        // issue next tile's loads FIRST (latency hides under this tile's math)
        short8 nk0, nk1, nv0, nv1;
        const bool more = (kt + 1 < NT);
        if (more) {
            const short* g = gK + (size_t)(k0 + 64) * HD;
            nk0 = *(const short8*)(g);
            nk1 = *(const short8*)(g + 8);
            const short* gv2 = gV + (k0 + 64);
            nv0 = *(const short8*)(gv2);
            nv1 = *(const short8*)(gv2 + 8);
        }

        i32x4 pw[2][2];   // [nt][c] packed bf16 P fragments (short8 each)
#pragma unroll
        for (int mt = 0; mt < 4; ++mt) {
            const short8 kf0 = *(const short8*)&Ks[(mt * 16 + lrow) * 72 + q8];
            const short8 kf1 = *(const short8*)&Ks[(mt * 16 + lrow) * 72 + 32 + q8];
            const float4 kk = *(const float4*)&k2s[k0 + mt * 16 + q4];
            const int c = mt >> 1, wb = (mt & 1) * 2;
#pragma unroll
            for (int nt = 0; nt < 2; ++nt) {
                f32x4 s = z4;
                s = __builtin_amdgcn_mfma_f32_16x16x32_bf16(kf0, qf[nt][0], s, 0, 0, 0);
                s = __builtin_amdgcn_mfma_f32_16x16x32_bf16(kf1, qf[nt][1], s, 0, 0, 0);
                const float p0 = EXP2(fmaf(s[0], C_QK, -kk.x));
                const float p1 = EXP2(fmaf(s[1], C_QK, -kk.y));
                const float p2 = EXP2(fmaf(s[2], C_QK, -kk.z));
                const float p3 = EXP2(fmaf(s[3], C_QK, -kk.w));
                lsum[nt] += (p0 + p1) + (p2 + p3);
                pw[nt][c][wb]     = cvt_pk_bf16(p0, p1);
                pw[nt][c][wb + 1] = cvt_pk_bf16(p2, p3);
            }
        }
#pragma unroll
        for (int ht = 0; ht < 4; ++ht) {
#pragma unroll
            for (int c = 0; c < 2; ++c) {
                const short8 v8 = *(const short8*)&Vt[(ht * 16 + lrow) * 72 + c * 32 + q4 * 2];
#pragma unroll
                for (int nt = 0; nt < 2; ++nt)
                    o[ht][nt] = __builtin_amdgcn_mfma_f32_16x16x32_bf16(
                        v8, __builtin_bit_cast(short8, pw[nt][c]), o[ht][nt], 0, 0, 0);
            }
        }

        if (more) {   // vmcnt wait lands here, AFTER the compute above
            short* Kd = smem + ((kt + 1) & 1) * (2 * BUFS);
            *(short8*)&Kd[woff]            = nk0;
            *(short8*)&Kd[woff + 8]        = nk1;
            *(short8*)&Kd[BUFS + woff]     = nv0;
            *(short8*)&Kd[BUFS + woff + 8] = nv1;
        }
        __syncthreads();                    // single barrier per tile
    }

#pragma unroll
    for (int nt = 0; nt < 2; ++nt) {
        lsum[nt] += __shfl_xor(lsum[nt], 16);
        lsum[nt] += __shfl_xor(lsum[nt], 32);
    }
    const float inv0 = 1.f / lsum[0], inv1 = 1.f / lsum[1];

    // wave-private Ot transpose buffers (all loop reads done: post-barrier)
    short* Ot = smem + wv * (32 * 72);
#pragma unroll
    for (int ht = 0; ht < 4; ++ht)
#pragma unroll
        for (int nt = 0; nt < 2; ++nt) {
            const float iv = nt ? inv1 : inv0;
            const s16x4 ov = {f2bf(o[ht][nt][0] * iv), f2bf(o[ht][nt][1] * iv),
                              f2bf(o[ht][nt][2] * iv), f2bf(o[ht][nt][3] * iv)};
            *(s16x4*)&Ot[(nt * 16 + lrow) * 72 + ht * 16 + q4] = ov;
        }
    const int erow = lane >> 1, ec = (lane & 1) * 32;
    const short8 r0 = *(const short8*)&Ot[erow * 72 + ec + 0];
    const short8 r1 = *(const short8*)&Ot[erow * 72 + ec + 8];
    const short8 r2 = *(const short8*)&Ot[erow * 72 + ec + 16];
    const short8 r3 = *(const short8*)&Ot[erow * 72 + ec + 24];
    short* dst = aO + ((size_t)b * SEQ_L + qt * 128 + wv * 32 + erow) * DM + h * HD + ec;
    *(short8*)(dst + 0)  = r0;
    *(short8*)(dst + 8)  = r1;
    *(short8*)(dst + 16) = r2;
    *(short8*)(dst + 24) = r3;
}

// ---------------------------------------------------------------------------
// Launch
// ---------------------------------------------------------------------------
extern "C" void kernel_launch(void* const* d_in, const int* in_sizes, int n_in,
                              void* d_out, int out_size, void* d_ws, size_t ws_size,
                              hipStream_t stream) {
    const float* x   = (const float*)d_in[0];
    const float* wq  = (const float*)d_in[1];
    const float* bq  = (const float*)d_in[2];
    const float* wk  = (const float*)d_in[3];
    const float* bk  = (const float*)d_in[4];
    const float* wv  = (const float*)d_in[5];
    const float* bv  = (const float*)d_in[6];
    const float* wo  = (const float*)d_in[7];
    const float* bo  = (const float*)d_in[8];
    const float* g1  = (const float*)d_in[9];
    const float* b1  = (const float*)d_in[10];
    const float* g2  = (const float*)d_in[11];
    const float* b2  = (const float*)d_in[12];
    const float* w1  = (const float*)d_in[13];
    const float* bf1 = (const float*)d_in[14];
    const float* w2  = (const float*)d_in[15];
    const float* bf2 = (const float*)d_in[16];
    float* out = (float*)d_out;

    // ws layout (MiB, all offsets within the previously-validated 80.25 MiB):
    // [0,24)    wbf bf16 weights (wq..wo [0,8), w1 [8,16), w2 [16,24))
    // [24,48)   qkvB bf16 [BL][3072]; later hbuf bf16 [BL][4096] = [24,56)
    // [24,40)   P  fp32 out-proj partial 0 (over dead qkvB)
    // [40,56)   P2 fp32 out-proj partial 1 (dead qkvB tail + dead Qb)
    // [48,56)   xnb/Qb (dead after attn)
    // [56,64)   Kb (dead after attn)     [64,72) Vtb/xn2b (dead after FFN1)
    // [72,72.25) k2   [72.25,80.25) aO (dead after out-proj)
    // [0,16)    y0 fp32 FFN2 partial 0 (over dead wq..wo,w1; w2 [16,24) live)
    // [56,72)   y1 fp32 FFN2 partial 1 (over dead Kb,Vtb)
    char* base = (char*)d_ws;
    short* wbf  = (short*)base;
    short* qkvB = (short*)(base + (24u << 20));
    short* xnb  = (short*)(base + (48u << 20));
    short* Qb   = xnb;
    short* Kb   = (short*)(base + (56u << 20));
    short* Vtb  = (short*)(base + (64u << 20));
    float* k2   = (float*)(base + (72u << 20));
    short* aO   = (short*)(base + (72u << 20) + (256u << 10));
    float* P    = (float*)(base + (24u << 20));
    float* P2   = (float*)(base + (40u << 20));
    short* xn2b = Vtb;
    short* hbuf = qkvB;
    float* y0   = (float*)base;                     // FFN2 partial 0
    float* y1   = (float*)(base + (56u << 20));     // FFN2 partial 1

    // 0. weights -> bf16
    cvt6_kernel<<<12288, 256, 0, stream>>>(wq, wk, wv, wo, w1, w2, wbf);
    // 1. LN1 -> bf16
    ln_bf16_kernel<<<BL, 256, 0, stream>>>(x, g1, b1, xnb);
    // 2. fused QKV projection -> bf16 [BL][3072]
    gemm_mfma<128, 0, 1, 1, 1><<<dim3(24, 32), 256, 0, stream>>>(
        xnb, wbf, bq, bk, bv, qkvB, nullptr, BL, QKV_S, DM);
    // 3. prep: project q,k -> Qb/Kb [bh][L][64] + k2; transpose v -> Vtb
    qk_prep<<<16384, 256, 0, stream>>>(qkvB, Qb, Kb, k2);
    v_prep<<<1024, 256, 0, stream>>>(qkvB, Vtb);
    // 4. flash MFMA attention -> aO bf16
    attn_mfma2<<<dim3(16, 16, 2), 256, 0, stream>>>(Qb, Kb, Vtb, k2, aO);
    // 5. output projection, BM=128 split-K=2 -> P,P2 fp32 partials
    gemm_mfma<128, 0, 0, 0, 2><<<dim3(8, 32, 2), 256, 0, stream>>>(
        aO, wbf + 3145728, bo, bo, bo, P, P2, BL, DM, DM);
    // 6. x1 = project(x + P + P2) -> d_out
    resproj2_kernel<<<BL, 256, 0, stream>>>(x, P, P2, out);
    // 7. LN2 -> bf16
    ln_bf16_kernel<<<BL, 256, 0, stream>>>(out, g2, b2, xn2b);
    // 8. FFN1 + GELU -> bf16 hidden
    gemm_mfma<128, 1, 1, 0, 1><<<dim3(32, 32), 256, 0, stream>>>(
        xn2b, wbf + 4194304, bf1, bf1, bf1, hbuf, nullptr, BL, DFF, DM);
    // 9. FFN2, BM=128 split-K=2 -> y0,y1 fp32 partials
    gemm_mfma<128, 0, 0, 0, 2><<<dim3(8, 32, 2), 256, 0, stream>>>(
        hbuf, wbf + 8388608, bf2, bf2, bf2, y0, y1, BL, DM, DFF);
    // 10. out = project(x1 + y0 + y1)
    resproj2_kernel<<<BL, 256, 0, stream>>>(out, y0, y1, out);
}

// Round 6
// 378.771 us; speedup vs baseline: 1.2404x; 1.0161x over previous
//
#include <hip/hip_runtime.h>
#include <math.h>

// Problem constants: B=2, L=2048, D=1024, H=16, hd=64, Dff=4096
#define SEQ_L 2048
#define DM    1024
#define NH    16
#define HD    64
#define BL    4096          // B*L
#define DFF   4096
#define QKV_S 3072          // fused qkv row stride

typedef __attribute__((ext_vector_type(8))) short short8;   // 8 bf16 (4 VGPRs)
typedef __attribute__((ext_vector_type(4))) short s16x4;    // 4 bf16
typedef __attribute__((ext_vector_type(4))) float f32x4;    // MFMA C/D frag
typedef __attribute__((ext_vector_type(4))) int   i32x4;    // 4 packed bf16x2

// 0.25*log2(e), 0.125*log2(e) — fold exp->exp2 base change into the scales
#define C_QK  0.36067376022224085f
#define C_K2  0.18033688011112042f

#if __has_builtin(__builtin_amdgcn_exp2f)
#define EXP2(x) __builtin_amdgcn_exp2f(x)
#else
#define EXP2(x) exp2f(x)
#endif

// fp32 -> bf16 round-to-nearest-even
__device__ __forceinline__ short f2bf(float x) {
    unsigned u = __float_as_uint(x);
    u += 0x7fff + ((u >> 16) & 1);
    return (short)(u >> 16);
}
__device__ __forceinline__ float bf2f(short s) {
    return __uint_as_float(((unsigned)(unsigned short)s) << 16);
}
// pack two f32 -> one u32 of 2x bf16 (RNE); no builtin on gfx950 (m240)
__device__ __forceinline__ int cvt_pk_bf16(float lo, float hi) {
    int r;
    asm("v_cvt_pk_bf16_f32 %0, %1, %2" : "=v"(r) : "v"(lo), "v"(hi));
    return r;
}

// branch-free GELU (erf form) via A&S 7.1.26, |abs err| <= ~2e-7.
__device__ __forceinline__ float gelu_fast(float x) {
    const float xa = fabsf(x);
    const float z = xa * 0.70710678118654752440f;
    const float t = __builtin_amdgcn_rcpf(fmaf(0.3275911f, z, 1.f));
    float P = fmaf(t, 1.061405429f, -1.453152027f);
    P = fmaf(t, P, 1.421413741f);
    P = fmaf(t, P, -0.284496736f);
    P = fmaf(t, P, 0.254829592f);
    P *= t;
    const float e = __expf(-z * z);
    const float erfp = fmaf(-P, e, 1.f);   // erf(|x|/sqrt2)
    return 0.5f * fmaf(xa, erfp, x);
}

__device__ __forceinline__ float block_sum(float v, float* red, int tid) {
#pragma unroll
    for (int m = 32; m; m >>= 1) v += __shfl_xor(v, m);
    if ((tid & 63) == 0) red[tid >> 6] = v;
    __syncthreads();
    v = red[0] + red[1] + red[2] + red[3];
    __syncthreads();
    return v;
}

// ---------------------------------------------------------------------------
// Weight fp32 -> bf16: wq|wk|wv|wo|w1|w2 contiguous (fused QKV needs this).
// ---------------------------------------------------------------------------
__global__ __launch_bounds__(256) void cvt6_kernel(
    const float* __restrict__ wq, const float* __restrict__ wk,
    const float* __restrict__ wv, const float* __restrict__ wo,
    const float* __restrict__ w1, const float* __restrict__ w2,
    short* __restrict__ dst) {
    const size_t i = (size_t)blockIdx.x * 256 + threadIdx.x;  // float4 index
    const float* src;
    size_t off;
    if (i < 1048576) {
        const int seg = (int)(i >> 18);
        off = i & 262143;
        src = seg == 0 ? wq : seg == 1 ? wk : seg == 2 ? wv : wo;
    } else if (i < 2097152) { src = w1; off = i - 1048576; }
    else                    { src = w2; off = i - 2097152; }
    const float4 v = ((const float4*)src)[off];
    const s16x4 o = {f2bf(v.x), f2bf(v.y), f2bf(v.z), f2bf(v.w)};
    ((s16x4*)dst)[i] = o;
}

// ---------------------------------------------------------------------------
// LayerNorm over rows of 1024, bf16 output.
// ---------------------------------------------------------------------------
__global__ __launch_bounds__(256) void ln_bf16_kernel(const float* __restrict__ x,
                                                      const float* __restrict__ g,
                                                      const float* __restrict__ b,
                                                      short* __restrict__ out) {
    const int row = blockIdx.x;
    const int tid = threadIdx.x;
    __shared__ float red[4];
    const float4 xv = *(const float4*)(x + (size_t)row * DM + tid * 4);
    float s = xv.x + xv.y + xv.z + xv.w;
    s = block_sum(s, red, tid);
    const float mean = s * (1.f / (float)DM);
    float dx0 = xv.x - mean, dx1 = xv.y - mean, dx2 = xv.z - mean, dx3 = xv.w - mean;
    float ss = dx0 * dx0 + dx1 * dx1 + dx2 * dx2 + dx3 * dx3;
    ss = block_sum(ss, red, tid);
    const float rs = 1.f / sqrtf(ss * (1.f / (float)DM) + 1e-5f);
    const float4 gv = *(const float4*)(g + tid * 4);
    const float4 bv = *(const float4*)(b + tid * 4);
    const s16x4 ob = {f2bf(dx0 * rs * gv.x + bv.x), f2bf(dx1 * rs * gv.y + bv.y),
                      f2bf(dx2 * rs * gv.z + bv.z), f2bf(dx3 * rs * gv.w + bv.w)};
    *(s16x4*)(out + (size_t)row * DM + tid * 4) = ob;
}

// ---------------------------------------------------------------------------
// Residual + Poincare projection (fp32, in-place safe)
// ---------------------------------------------------------------------------
__global__ __launch_bounds__(256) void resproj_kernel(const float* __restrict__ a,
                                                      const float* __restrict__ c,
                                                      float* __restrict__ out) {
    const int row = blockIdx.x;
    const int tid = threadIdx.x;
    __shared__ float red[4];
    const float4 av = *(const float4*)(a + (size_t)row * DM + tid * 4);
    const float4 cv = *(const float4*)(c + (size_t)row * DM + tid * 4);
    float4 sv;
    sv.x = av.x + cv.x; sv.y = av.y + cv.y; sv.z = av.z + cv.z; sv.w = av.w + cv.w;
    float ss = sv.x * sv.x + sv.y * sv.y + sv.z * sv.z + sv.w * sv.w;
    ss = block_sum(ss, red, tid);
    const float n = sqrtf(ss);
    const float mx = 1.f - 1e-5f;
    const float scale = (n > mx) ? (mx / fmaxf(n, 1e-12f)) : 1.f;
    sv.x *= scale; sv.y *= scale; sv.z *= scale; sv.w *= scale;
    *(float4*)(out + (size_t)row * DM + tid * 4) = sv;
}

// ---------------------------------------------------------------------------
// Residual + TWO split-K partials + Poincare projection (fp32, in-place safe).
// ---------------------------------------------------------------------------
__global__ __launch_bounds__(256) void resproj2_kernel(const float* __restrict__ a,
                                                       const float* __restrict__ c0,
                                                       const float* __restrict__ c1,
                                                       float* __restrict__ out) {
    const int row = blockIdx.x;
    const int tid = threadIdx.x;
    __shared__ float red[4];
    const float4 av = *(const float4*)(a + (size_t)row * DM + tid * 4);
    const float4 cv = *(const float4*)(c0 + (size_t)row * DM + tid * 4);
    const float4 dv = *(const float4*)(c1 + (size_t)row * DM + tid * 4);
    float4 sv;
    sv.x = av.x + cv.x + dv.x; sv.y = av.y + cv.y + dv.y;
    sv.z = av.z + cv.z + dv.z; sv.w = av.w + cv.w + dv.w;
    float ss = sv.x * sv.x + sv.y * sv.y + sv.z * sv.z + sv.w * sv.w;
    ss = block_sum(ss, red, tid);
    const float n = sqrtf(ss);
    const float mx = 1.f - 1e-5f;
    const float scale = (n > mx) ? (mx / fmaxf(n, 1e-12f)) : 1.f;
    sv.x *= scale; sv.y *= scale; sv.z *= scale; sv.w *= scale;
    *(float4*)(out + (size_t)row * DM + tid * 4) = sv;
}

// ---------------------------------------------------------------------------
// q/k prep: per-head Poincare projection + attention-layout bf16 buffers.
// k2 prescaled by 0.125*log2(e) so attention can use exp2 directly.
// ---------------------------------------------------------------------------
__global__ __launch_bounds__(256) void qk_prep(const short* __restrict__ qkvB,
                                               short* __restrict__ Qb,
                                               short* __restrict__ Kb,
                                               float* __restrict__ k2) {
    const int tid = threadIdx.x, lane = tid & 63;
    const int vec = blockIdx.x * 4 + (tid >> 6);
    const int row = vec >> 4, h = vec & 15;
    const int b = row >> 11, l = row & 2047;
    const size_t dstv = ((size_t)(b * NH + h) * SEQ_L + l) * HD + lane;
    const float mx = 1.f - 1e-5f;
    {   // q
        const float v = bf2f(qkvB[(size_t)row * QKV_S + h * HD + lane]);
        float s = v * v;
#pragma unroll
        for (int m = 32; m; m >>= 1) s += __shfl_xor(s, m);
        const float n = sqrtf(s);
        const float sc = (n > mx) ? (mx / fmaxf(n, 1e-12f)) : 1.f;
        Qb[dstv] = f2bf(v * sc);
    }
    {   // k (+ prescaled squared norm, in log2 units)
        const float v = bf2f(qkvB[(size_t)row * QKV_S + DM + h * HD + lane]);
        float s = v * v;
#pragma unroll
        for (int m = 32; m; m >>= 1) s += __shfl_xor(s, m);
        const float n = sqrtf(s);
        const float sc = (n > mx) ? (mx / fmaxf(n, 1e-12f)) : 1.f;
        Kb[dstv] = f2bf(v * sc);
        if (lane == 0) k2[(size_t)(b * NH + h) * SEQ_L + l] = s * sc * sc * C_K2;
    }
}

// ---------------------------------------------------------------------------
// v prep: transpose to Vtb [b][h][64 hd][L] bf16, with the columns of each
// 32-wide k-block interleaved as [g0 lo4 | g0 hi4 | g1 lo4 | g1 hi4 | ...]
// (orig col c*32 + 4g+t -> c*32 + 8g+t ; orig c*32+16+4g+t -> c*32+8g+4+t)
// so the attention PV A-fragment (lane g=lane>>4 needs orig cols
// {q4..q4+3, 16+q4..16+q4+3}) is ONE contiguous aligned 16B load.
// ---------------------------------------------------------------------------
__global__ __launch_bounds__(256) void v_prep(const short* __restrict__ qkvB,
                                              short* __restrict__ Vtb) {
    const int blk = blockIdx.x;
    const int bh = blk >> 5, kt = blk & 31;
    const int b = bh >> 4, h = bh & 15;
    __shared__ short T[64 * 72];
    const int tid = threadIdx.x;
    {
        const int key = tid >> 2, ch = (tid & 3) * 16;
        const size_t src = ((size_t)b * SEQ_L + kt * 64 + key) * QKV_S + 2 * DM + h * HD + ch;
        *(short8*)&T[key * 72 + ch]     = *(const short8*)(qkvB + src);
        *(short8*)&T[key * 72 + ch + 8] = *(const short8*)(qkvB + src + 8);
    }
    __syncthreads();
    const int hd = tid >> 2, kc = (tid & 3) * 16;
    short8 o0, o1;
#pragma unroll
    for (int j = 0; j < 8; ++j) {
        o0[j] = T[(kc + j) * 72 + hd];
        o1[j] = T[(kc + 8 + j) * 72 + hd];
    }
    const int c32 = (kc >> 5) * 32;          // which 32-block (0 or 32)
    const int h4  = ((kc >> 4) & 1) * 4;     // low/high half of the block
    short* dst = Vtb + ((size_t)bh * HD + hd) * SEQ_L + kt * 64 + c32 + h4;
    const s16x4 w0 = {o0[0], o0[1], o0[2], o0[3]};
    const s16x4 w1 = {o0[4], o0[5], o0[6], o0[7]};
    const s16x4 w2 = {o1[0], o1[1], o1[2], o1[3]};
    const s16x4 w3 = {o1[4], o1[5], o1[6], o1[7]};
    *(s16x4*)(dst)      = w0;
    *(s16x4*)(dst + 8)  = w1;
    *(s16x4*)(dst + 16) = w2;
    *(s16x4*)(dst + 24) = w3;
}

// ---------------------------------------------------------------------------
// bf16 MFMA NT GEMM, BK=64 (round 6): 32 MFMAs per barrier-pair (was 16),
// half the loop iterations / vmcnt drains; register-prefetch double buffer
// unchanged in structure. LDS rows = 72 shorts (144 B = 9*16B: aligned;
// bank-word stride 36 -> uniform 8-access/bank floor on both staging
// writes and b128 fragment reads). XCD-aware block swizzle: consecutive
// linear block ids (which share the A m-panel) land on one XCD's L2.
// Split-K=2 (BM=128) for the N=1024 GEMMs; reduction fused into resproj2.
// ---------------------------------------------------------------------------
template <int BM, int ACT, int OUTBF, int FUSED, int SPLITK>
__global__ __launch_bounds__(256) void gemm_mfma(
    const short* __restrict__ A, const short* __restrict__ Bw,
    const float* __restrict__ bb0, const float* __restrict__ bb1,
    const float* __restrict__ bb2, void* __restrict__ Cout,
    void* __restrict__ Cout2,
    int M, int N, int K) {
    static_assert(BM == 128, "BK=64 staging assumes BM=128");
    constexpr int RT = BM / 32;
    constexpr int LDSR = 72;      // 64 shorts + 8 pad (144 B, 16B-aligned)
    constexpr bool VEPI = (OUTBF != 0) && (BM == 128);
    constexpr int STAGE_SHORTS = (BM + 128) * LDSR;   // 18432 shorts = 36864 B
    static_assert(!VEPI || STAGE_SHORTS >= 4 * 64 * 72, "VEPI smem too small");
    __shared__ __align__(16) short raw[STAGE_SHORTS];
    short* As = raw;
    short* Bs = raw + BM * LDSR;
    const int tid = threadIdx.x;
    const int wv = tid >> 6, lane = tid & 63;

    // XCD-aware bijective swizzle (grid size % 8 == 0 for all launches)
    const int gx = gridDim.x, gy = gridDim.y;
    const int nwg = gx * gy * gridDim.z;
    int d = blockIdx.x + gx * (blockIdx.y + gy * blockIdx.z);
    d = (d & 7) * (nwg >> 3) + (d >> 3);
    const int bx = d % gx;
    const int byz = d / gx;
    const int by = byz % gy;
    const int bz = byz / gy;

    const int m0 = by * BM, n0 = bx * 128;
    const int wr = (wv & 1) * (BM / 2);
    const int wc = (wv >> 1) * 64;

    const int z = (SPLITK > 1) ? bz : 0;
    const int Kc = K / SPLITK;              // this block's K-chunk length

    // staging: thread t covers rows (t>>3)+32j (j=0..3), chunk (t&7)*8 shorts
    const int srow = tid >> 3, sc8 = (tid & 7) * 8;
    const short* Ag = A + (size_t)(m0 + srow) * K + z * Kc + sc8;
    const short* Bg = Bw + (size_t)(n0 + srow) * K + z * Kc + sc8;
    short* AsW = As + srow * LDSR + sc8;
    short* BsW = Bs + srow * LDSR + sc8;

    const f32x4 z4 = {0.f, 0.f, 0.f, 0.f};
    f32x4 acc[RT][4];
#pragma unroll
    for (int r = 0; r < RT; ++r)
#pragma unroll
        for (int c = 0; c < 4; ++c) acc[r][c] = z4;

    const int lrow = lane & 15, kq = (lane >> 4) * 8;

    // prologue: tile 0 into regs (8 x short8 = 32 VGPRs)
    short8 ra[4], rb[4];
#pragma unroll
    for (int j = 0; j < 4; ++j) {
        ra[j] = *(const short8*)(Ag + (size_t)(32 * j) * K);
        rb[j] = *(const short8*)(Bg + (size_t)(32 * j) * K);
    }

    for (int kt = 0; kt < Kc; kt += 64) {
        __syncthreads();                    // previous tile's ds_reads complete
#pragma unroll
        for (int j = 0; j < 4; ++j) {       // vmcnt wait (issued last iter) here
            *(short8*)(AsW + (32 * j) * LDSR) = ra[j];
            *(short8*)(BsW + (32 * j) * LDSR) = rb[j];
        }
        if (kt + 64 < Kc) {                 // prefetch tile k+1 (in flight
#pragma unroll
            for (int j = 0; j < 4; ++j) {   //  through the 32 MFMAs below)
                ra[j] = *(const short8*)(Ag + (size_t)(32 * j) * K + kt + 64);
                rb[j] = *(const short8*)(Bg + (size_t)(32 * j) * K + kt + 64);
            }
        }
        __syncthreads();                    // LDS writes visible
#pragma unroll
        for (int h = 0; h < 2; ++h) {
            short8 af[RT], bf[4];
#pragma unroll
            for (int r = 0; r < RT; ++r)
                af[r] = *(const short8*)&As[(wr + r * 16 + lrow) * LDSR + h * 32 + kq];
#pragma unroll
            for (int c = 0; c < 4; ++c)
                bf[c] = *(const short8*)&Bs[(wc + c * 16 + lrow) * LDSR + h * 32 + kq];
#pragma unroll
            for (int r = 0; r < RT; ++r)
#pragma unroll
                for (int c = 0; c < 4; ++c)
                    acc[r][c] = __builtin_amdgcn_mfma_f32_16x16x32_bf16(af[r], bf[c], acc[r][c], 0, 0, 0);
        }
    }

    void* Cbase = Cout;
    if constexpr (SPLITK > 1) { if (z) Cbase = Cout2; }

    const int col = lane & 15, rb4 = (lane >> 4) * 4;
    if constexpr (VEPI) {
        __syncthreads();   // staging dead; reuse raw as per-wave transpose buffers
        short* Ot = raw + wv * (64 * 72);
#pragma unroll
        for (int c = 0; c < 4; ++c) {
            const int gn = n0 + wc + c * 16 + col;
            float bias;
            if constexpr (FUSED) {
                const int seg = gn >> 10;
                bias = (seg == 0 ? bb0 : seg == 1 ? bb1 : bb2)[gn & 1023];
            } else {
                bias = bb0[gn];
            }
#pragma unroll
            for (int r = 0; r < RT; ++r)
#pragma unroll
                for (int i = 0; i < 4; ++i) {
                    float v = acc[r][c][i] + bias;
                    if constexpr (ACT) v = gelu_fast(v);
                    Ot[(r * 16 + rb4 + i) * 72 + c * 16 + col] = f2bf(v);
                }
        }
        const int orow = lane >> 3, oc = (lane & 7) * 8;
#pragma unroll
        for (int it = 0; it < 8; ++it) {
            const short8 vv = *(const short8*)&Ot[(it * 8 + orow) * 72 + oc];
            *(short8*)((short*)Cbase + (size_t)(m0 + wr + it * 8 + orow) * N + n0 + wc + oc) = vv;
        }
    } else {
#pragma unroll
        for (int c = 0; c < 4; ++c) {
            const int gn = n0 + wc + c * 16 + col;
            float bias;
            if constexpr (FUSED) {
                const int seg = gn >> 10;
                bias = (seg == 0 ? bb0 : seg == 1 ? bb1 : bb2)[gn & 1023];
            } else {
                bias = bb0[gn];
            }
            if constexpr (SPLITK > 1) { if (z) bias = 0.f; }  // bias only in partial 0
#pragma unroll
            for (int r = 0; r < RT; ++r) {
                const int gm = m0 + wr + r * 16 + rb4;
#pragma unroll
                for (int i = 0; i < 4; ++i) {
                    float v = acc[r][c][i] + bias;
                    if constexpr (ACT) v = gelu_fast(v);
                    if constexpr (OUTBF)
                        ((short*)Cbase)[(size_t)(gm + i) * N + gn] = f2bf(v);
                    else
                        ((float*)Cbase)[(size_t)(gm + i) * N + gn] = v;
                }
            }
        }
    }
}

// ---------------------------------------------------------------------------
// MFMA flash attention v6: r5's single-barrier LDS double-buffer schedule,
// plus XCD-aware block swizzle (round 6). FETCH was 70.7 MB vs ~25 MB of
// inputs: the 16 qt-blocks sharing one (b,h)'s K/V (512 KB) were spread
// round-robin over all 8 XCDs, so every per-XCD L2 re-fetched nearly every
// head. The bijective chunked remap puts 4 complete (b,h) groups (2 MB of
// K/V) on each XCD -> fits its 4 MB L2.
// ---------------------------------------------------------------------------
__global__ __launch_bounds__(256) void attn_mfma2(const short* __restrict__ Qb,
                                                  const short* __restrict__ Kb,
                                                  const short* __restrict__ Vtb,
                                                  const float* __restrict__ k2v,
                                                  short* __restrict__ aO) {
    int d = blockIdx.x + 16 * (blockIdx.y + 16 * blockIdx.z);
    d = (d & 7) * 64 + (d >> 3);            // 512 blocks, bijective
    const int qt = d & 15, h = (d >> 4) & 15, b = d >> 8;
    const int tid = threadIdx.x, wv = tid >> 6, lane = tid & 63;
    const int bh = b * NH + h;
    constexpr int NT = SEQ_L / 64;
    constexpr int BUFS = 64 * 72;    // shorts per K (or V) tile buffer
    __shared__ __align__(16) short smem[4 * BUFS];  // {K,V} x double buffer; Ot reuse
    __shared__ __align__(16) float k2s[SEQ_L];
    const int lrow = lane & 15, q8 = (lane >> 4) * 8, q4 = (lane >> 4) * 4;

    const short* Qh = Qb + (size_t)bh * SEQ_L * HD;
    const short* Kh = Kb + (size_t)bh * SEQ_L * HD;
    const short* Vh = Vtb + (size_t)bh * HD * SEQ_L;
    const float* k2p = k2v + (size_t)bh * SEQ_L;

    short8 qf[2][2];
#pragma unroll
    for (int nt = 0; nt < 2; ++nt)
#pragma unroll
        for (int kc = 0; kc < 2; ++kc)
            qf[nt][kc] = *(const short8*)(Qh +
                (size_t)(qt * 128 + wv * 32 + nt * 16 + lrow) * HD + kc * 32 + q8);

    // k2 -> LDS (2048 floats, 8 per thread)
    {
        const float4 a0 = *(const float4*)(k2p + tid * 4);
        const float4 a1 = *(const float4*)(k2p + 1024 + tid * 4);
        *(float4*)&k2s[tid * 4] = a0;
        *(float4*)&k2s[1024 + tid * 4] = a1;
    }

    const int srow = tid >> 2, sch = (tid & 3) * 16;
    const short* gK = Kh + (size_t)srow * HD + sch;      // + (k0)*HD per tile
    const short* gV = Vh + (size_t)srow * SEQ_L + sch;   // + k0 per tile
    const int woff = srow * 72 + sch;

    // prologue: stage tile 0 into buf 0
    {
        const short8 k0a = *(const short8*)(gK);
        const short8 k0b = *(const short8*)(gK + 8);
        const short8 v0a = *(const short8*)(gV);
        const short8 v0b = *(const short8*)(gV + 8);
        *(short8*)&smem[woff]            = k0a;
        *(short8*)&smem[woff + 8]        = k0b;
        *(short8*)&smem[BUFS + woff]     = v0a;
        *(short8*)&smem[BUFS + woff + 8] = v0b;
    }
    __syncthreads();

    const f32x4 z4 = {0.f, 0.f, 0.f, 0.f};
    f32x4 o[4][2];   // O^T accum: [ht(hd)][nt(qrow)]
#pragma unroll
    for (int ht = 0; ht < 4; ++ht)
#pragma unroll
        for (int nt = 0; nt < 2; ++nt) o[ht][nt] = z4;
    float lsum[2] = {0.f, 0.f};

    for (int kt = 0; kt < NT; ++kt) {
        const int k0 = kt * 64;
        const short* Ks = smem + (kt & 1) * (2 * BUFS);
        const short* Vt = Ks + BUFS;
        // issue next tile's loads FIRST (latency hides under this tile's math)
        short8 nk0, nk1, nv0, nv1;
        const bool more = (kt + 1 < NT);
        if (more) {
            const short* g = gK + (size_t)(k0 + 64) * HD;
            nk0 = *(const short8*)(g);
            nk1 = *(const short8*)(g + 8);
            const short* gv2 = gV + (k0 + 64);
            nv0 = *(const short8*)(gv2);
            nv1 = *(const short8*)(gv2 + 8);
        }

        i32x4 pw[2][2];   // [nt][c] packed bf16 P fragments (short8 each)
#pragma unroll
        for (int mt = 0; mt < 4; ++mt) {
            const short8 kf0 = *(const short8*)&Ks[(mt * 16 + lrow) * 72 + q8];
            const short8 kf1 = *(const short8*)&Ks[(mt * 16 + lrow) * 72 + 32 + q8];
            const float4 kk = *(const float4*)&k2s[k0 + mt * 16 + q4];
            const int c = mt >> 1, wb = (mt & 1) * 2;
#pragma unroll
            for (int nt = 0; nt < 2; ++nt) {
                f32x4 s = z4;
                s = __builtin_amdgcn_mfma_f32_16x16x32_bf16(kf0, qf[nt][0], s, 0, 0, 0);
                s = __builtin_amdgcn_mfma_f32_16x16x32_bf16(kf1, qf[nt][1], s, 0, 0, 0);
                const float p0 = EXP2(fmaf(s[0], C_QK, -kk.x));
                const float p1 = EXP2(fmaf(s[1], C_QK, -kk.y));
                const float p2 = EXP2(fmaf(s[2], C_QK, -kk.z));
                const float p3 = EXP2(fmaf(s[3], C_QK, -kk.w));
                lsum[nt] += (p0 + p1) + (p2 + p3);
                pw[nt][c][wb]     = cvt_pk_bf16(p0, p1);
                pw[nt][c][wb + 1] = cvt_pk_bf16(p2, p3);
            }
        }
#pragma unroll
        for (int ht = 0; ht < 4; ++ht) {
#pragma unroll
            for (int c = 0; c < 2; ++c) {
                const short8 v8 = *(const short8*)&Vt[(ht * 16 + lrow) * 72 + c * 32 + q4 * 2];
#pragma unroll
                for (int nt = 0; nt < 2; ++nt)
                    o[ht][nt] = __builtin_amdgcn_mfma_f32_16x16x32_bf16(
                        v8, __builtin_bit_cast(short8, pw[nt][c]), o[ht][nt], 0, 0, 0);
            }
        }

        if (more) {   // vmcnt wait lands here, AFTER the compute above
            short* Kd = smem + ((kt + 1) & 1) * (2 * BUFS);
            *(short8*)&Kd[woff]            = nk0;
            *(short8*)&Kd[woff + 8]        = nk1;
            *(short8*)&Kd[BUFS + woff]     = nv0;
            *(short8*)&Kd[BUFS + woff + 8] = nv1;
        }
        __syncthreads();                    // single barrier per tile
    }

#pragma unroll
    for (int nt = 0; nt < 2; ++nt) {
        lsum[nt] += __shfl_xor(lsum[nt], 16);
        lsum[nt] += __shfl_xor(lsum[nt], 32);
    }
    const float inv0 = 1.f / lsum[0], inv1 = 1.f / lsum[1];

    // wave-private Ot transpose buffers (all loop reads done: post-barrier)
    short* Ot = smem + wv * (32 * 72);
#pragma unroll
    for (int ht = 0; ht < 4; ++ht)
#pragma unroll
        for (int nt = 0; nt < 2; ++nt) {
            const float iv = nt ? inv1 : inv0;
            const s16x4 ov = {f2bf(o[ht][nt][0] * iv), f2bf(o[ht][nt][1] * iv),
                              f2bf(o[ht][nt][2] * iv), f2bf(o[ht][nt][3] * iv)};
            *(s16x4*)&Ot[(nt * 16 + lrow) * 72 + ht * 16 + q4] = ov;
        }
    const int erow = lane >> 1, ec = (lane & 1) * 32;
    const short8 r0 = *(const short8*)&Ot[erow * 72 + ec + 0];
    const short8 r1 = *(const short8*)&Ot[erow * 72 + ec + 8];
    const short8 r2 = *(const short8*)&Ot[erow * 72 + ec + 16];
    const short8 r3 = *(const short8*)&Ot[erow * 72 + ec + 24];
    short* dst = aO + ((size_t)b * SEQ_L + qt * 128 + wv * 32 + erow) * DM + h * HD + ec;
    *(short8*)(dst + 0)  = r0;
    *(short8*)(dst + 8)  = r1;
    *(short8*)(dst + 16) = r2;
    *(short8*)(dst + 24) = r3;
}

// ---------------------------------------------------------------------------
// Launch
// ---------------------------------------------------------------------------
extern "C" void kernel_launch(void* const* d_in, const int* in_sizes, int n_in,
                              void* d_out, int out_size, void* d_ws, size_t ws_size,
                              hipStream_t stream) {
    const float* x   = (const float*)d_in[0];
    const float* wq  = (const float*)d_in[1];
    const float* bq  = (const float*)d_in[2];
    const float* wk  = (const float*)d_in[3];
    const float* bk  = (const float*)d_in[4];
    const float* wv  = (const float*)d_in[5];
    const float* bv  = (const float*)d_in[6];
    const float* wo  = (const float*)d_in[7];
    const float* bo  = (const float*)d_in[8];
    const float* g1  = (const float*)d_in[9];
    const float* b1  = (const float*)d_in[10];
    const float* g2  = (const float*)d_in[11];
    const float* b2  = (const float*)d_in[12];
    const float* w1  = (const float*)d_in[13];
    const float* bf1 = (const float*)d_in[14];
    const float* w2  = (const float*)d_in[15];
    const float* bf2 = (const float*)d_in[16];
    float* out = (float*)d_out;

    // ws layout (MiB, all offsets within the previously-validated 80.25 MiB):
    // [0,24)    wbf bf16 weights (wq..wo [0,8), w1 [8,16), w2 [16,24))
    // [24,48)   qkvB bf16 [BL][3072]; later hbuf bf16 [BL][4096] = [24,56)
    // [24,40)   P  fp32 out-proj partial 0 (over dead qkvB)
    // [40,56)   P2 fp32 out-proj partial 1 (dead qkvB tail + dead Qb)
    // [48,56)   xnb/Qb (dead after attn)
    // [56,64)   Kb (dead after attn)     [64,72) Vtb/xn2b (dead after FFN1)
    // [72,72.25) k2   [72.25,80.25) aO (dead after out-proj)
    // [0,16)    y0 fp32 FFN2 partial 0 (over dead wq..wo,w1; w2 [16,24) live)
    // [56,72)   y1 fp32 FFN2 partial 1 (over dead Kb,Vtb)
    char* base = (char*)d_ws;
    short* wbf  = (short*)base;
    short* qkvB = (short*)(base + (24u << 20));
    short* xnb  = (short*)(base + (48u << 20));
    short* Qb   = xnb;
    short* Kb   = (short*)(base + (56u << 20));
    short* Vtb  = (short*)(base + (64u << 20));
    float* k2   = (float*)(base + (72u << 20));
    short* aO   = (short*)(base + (72u << 20) + (256u << 10));
    float* P    = (float*)(base + (24u << 20));
    float* P2   = (float*)(base + (40u << 20));
    short* xn2b = Vtb;
    short* hbuf = qkvB;
    float* y0   = (float*)base;                     // FFN2 partial 0
    float* y1   = (float*)(base + (56u << 20));     // FFN2 partial 1

    // 0. weights -> bf16
    cvt6_kernel<<<12288, 256, 0, stream>>>(wq, wk, wv, wo, w1, w2, wbf);
    // 1. LN1 -> bf16
    ln_bf16_kernel<<<BL, 256, 0, stream>>>(x, g1, b1, xnb);
    // 2. fused QKV projection -> bf16 [BL][3072]
    gemm_mfma<128, 0, 1, 1, 1><<<dim3(24, 32), 256, 0, stream>>>(
        xnb, wbf, bq, bk, bv, qkvB, nullptr, BL, QKV_S, DM);
    // 3. prep: project q,k -> Qb/Kb [bh][L][64] + k2; transpose v -> Vtb
    qk_prep<<<16384, 256, 0, stream>>>(qkvB, Qb, Kb, k2);
    v_prep<<<1024, 256, 0, stream>>>(qkvB, Vtb);
    // 4. flash MFMA attention -> aO bf16
    attn_mfma2<<<dim3(16, 16, 2), 256, 0, stream>>>(Qb, Kb, Vtb, k2, aO);
    // 5. output projection, BM=128 split-K=2 -> P,P2 fp32 partials
    gemm_mfma<128, 0, 0, 0, 2><<<dim3(8, 32, 2), 256, 0, stream>>>(
        aO, wbf + 3145728, bo, bo, bo, P, P2, BL, DM, DM);
    // 6. x1 = project(x + P + P2) -> d_out
    resproj2_kernel<<<BL, 256, 0, stream>>>(x, P, P2, out);
    // 7. LN2 -> bf16
    ln_bf16_kernel<<<BL, 256, 0, stream>>>(out, g2, b2, xn2b);
    // 8. FFN1 + GELU -> bf16 hidden
    gemm_mfma<128, 1, 1, 0, 1><<<dim3(32, 32), 256, 0, stream>>>(
        xn2b, wbf + 4194304, bf1, bf1, bf1, hbuf, nullptr, BL, DFF, DM);
    // 9. FFN2, BM=128 split-K=2 -> y0,y1 fp32 partials
    gemm_mfma<128, 0, 0, 0, 2><<<dim3(8, 32, 2), 256, 0, stream>>>(
        hbuf, wbf + 8388608, bf2, bf2, bf2, y0, y1, BL, DM, DFF);
    // 10. out = project(x1 + y0 + y1)
    resproj2_kernel<<<BL, 256, 0, stream>>>(out, y0, y1, out);
}

// Round 7
// 378.755 us; speedup vs baseline: 1.2405x; 1.0000x over previous
//
#include <hip/hip_runtime.h>
#include <math.h>

// Problem constants: B=2, L=2048, D=1024, H=16, hd=64, Dff=4096
#define SEQ_L 2048
#define DM    1024
#define NH    16
#define HD    64
#define BL    4096          // B*L
#define DFF   4096
#define QKV_S 3072          // fused qkv row stride

typedef __attribute__((ext_vector_type(8))) short short8;   // 8 bf16 (4 VGPRs)
typedef __attribute__((ext_vector_type(4))) short s16x4;    // 4 bf16
typedef __attribute__((ext_vector_type(4))) float f32x4;    // MFMA C/D frag
typedef __attribute__((ext_vector_type(4))) int   i32x4;    // 4 packed bf16x2

// 0.25*log2(e), 0.125*log2(e) — fold exp->exp2 base change into the scales
#define C_QK  0.36067376022224085f
#define C_K2  0.18033688011112042f

#if __has_builtin(__builtin_amdgcn_exp2f)
#define EXP2(x) __builtin_amdgcn_exp2f(x)
#else
#define EXP2(x) exp2f(x)
#endif

// fp32 -> bf16 round-to-nearest-even
__device__ __forceinline__ short f2bf(float x) {
    unsigned u = __float_as_uint(x);
    u += 0x7fff + ((u >> 16) & 1);
    return (short)(u >> 16);
}
__device__ __forceinline__ float bf2f(short s) {
    return __uint_as_float(((unsigned)(unsigned short)s) << 16);
}
// pack two f32 -> one u32 of 2x bf16 (RNE); no builtin on gfx950 (m240)
__device__ __forceinline__ int cvt_pk_bf16(float lo, float hi) {
    int r;
    asm("v_cvt_pk_bf16_f32 %0, %1, %2" : "=v"(r) : "v"(lo), "v"(hi));
    return r;
}
// async global->LDS, 16 B per lane; LDS dest is wave-uniform base + lane*16
__device__ __forceinline__ void async_copy16(const short* gsrc, short* ldst) {
    __builtin_amdgcn_global_load_lds(
        (const __attribute__((address_space(1))) unsigned int*)gsrc,
        (__attribute__((address_space(3))) unsigned int*)ldst, 16, 0, 0);
}

// branch-free GELU (erf form) via A&S 7.1.26, |abs err| <= ~2e-7.
__device__ __forceinline__ float gelu_fast(float x) {
    const float xa = fabsf(x);
    const float z = xa * 0.70710678118654752440f;
    const float t = __builtin_amdgcn_rcpf(fmaf(0.3275911f, z, 1.f));
    float P = fmaf(t, 1.061405429f, -1.453152027f);
    P = fmaf(t, P, 1.421413741f);
    P = fmaf(t, P, -0.284496736f);
    P = fmaf(t, P, 0.254829592f);
    P *= t;
    const float e = __expf(-z * z);
    const float erfp = fmaf(-P, e, 1.f);   // erf(|x|/sqrt2)
    return 0.5f * fmaf(xa, erfp, x);
}

__device__ __forceinline__ float block_sum(float v, float* red, int tid) {
#pragma unroll
    for (int m = 32; m; m >>= 1) v += __shfl_xor(v, m);
    if ((tid & 63) == 0) red[tid >> 6] = v;
    __syncthreads();
    v = red[0] + red[1] + red[2] + red[3];
    __syncthreads();
    return v;
}

// ---------------------------------------------------------------------------
// Weight fp32 -> bf16: wq|wk|wv|wo|w1|w2 contiguous (fused QKV needs this).
// ---------------------------------------------------------------------------
__global__ __launch_bounds__(256) void cvt6_kernel(
    const float* __restrict__ wq, const float* __restrict__ wk,
    const float* __restrict__ wv, const float* __restrict__ wo,
    const float* __restrict__ w1, const float* __restrict__ w2,
    short* __restrict__ dst) {
    const size_t i = (size_t)blockIdx.x * 256 + threadIdx.x;  // float4 index
    const float* src;
    size_t off;
    if (i < 1048576) {
        const int seg = (int)(i >> 18);
        off = i & 262143;
        src = seg == 0 ? wq : seg == 1 ? wk : seg == 2 ? wv : wo;
    } else if (i < 2097152) { src = w1; off = i - 1048576; }
    else                    { src = w2; off = i - 2097152; }
    const float4 v = ((const float4*)src)[off];
    const s16x4 o = {f2bf(v.x), f2bf(v.y), f2bf(v.z), f2bf(v.w)};
    ((s16x4*)dst)[i] = o;
}

// ---------------------------------------------------------------------------
// LayerNorm over rows of 1024, bf16 output.
// ---------------------------------------------------------------------------
__global__ __launch_bounds__(256) void ln_bf16_kernel(const float* __restrict__ x,
                                                      const float* __restrict__ g,
                                                      const float* __restrict__ b,
                                                      short* __restrict__ out) {
    const int row = blockIdx.x;
    const int tid = threadIdx.x;
    __shared__ float red[4];
    const float4 xv = *(const float4*)(x + (size_t)row * DM + tid * 4);
    float s = xv.x + xv.y + xv.z + xv.w;
    s = block_sum(s, red, tid);
    const float mean = s * (1.f / (float)DM);
    float dx0 = xv.x - mean, dx1 = xv.y - mean, dx2 = xv.z - mean, dx3 = xv.w - mean;
    float ss = dx0 * dx0 + dx1 * dx1 + dx2 * dx2 + dx3 * dx3;
    ss = block_sum(ss, red, tid);
    const float rs = 1.f / sqrtf(ss * (1.f / (float)DM) + 1e-5f);
    const float4 gv = *(const float4*)(g + tid * 4);
    const float4 bv = *(const float4*)(b + tid * 4);
    const s16x4 ob = {f2bf(dx0 * rs * gv.x + bv.x), f2bf(dx1 * rs * gv.y + bv.y),
                      f2bf(dx2 * rs * gv.z + bv.z), f2bf(dx3 * rs * gv.w + bv.w)};
    *(s16x4*)(out + (size_t)row * DM + tid * 4) = ob;
}

// ---------------------------------------------------------------------------
// Residual + TWO split-K partials + Poincare projection (fp32, in-place safe).
// ---------------------------------------------------------------------------
__global__ __launch_bounds__(256) void resproj2_kernel(const float* __restrict__ a,
                                                       const float* __restrict__ c0,
                                                       const float* __restrict__ c1,
                                                       float* __restrict__ out) {
    const int row = blockIdx.x;
    const int tid = threadIdx.x;
    __shared__ float red[4];
    const float4 av = *(const float4*)(a + (size_t)row * DM + tid * 4);
    const float4 cv = *(const float4*)(c0 + (size_t)row * DM + tid * 4);
    const float4 dv = *(const float4*)(c1 + (size_t)row * DM + tid * 4);
    float4 sv;
    sv.x = av.x + cv.x + dv.x; sv.y = av.y + cv.y + dv.y;
    sv.z = av.z + cv.z + dv.z; sv.w = av.w + cv.w + dv.w;
    float ss = sv.x * sv.x + sv.y * sv.y + sv.z * sv.z + sv.w * sv.w;
    ss = block_sum(ss, red, tid);
    const float n = sqrtf(ss);
    const float mx = 1.f - 1e-5f;
    const float scale = (n > mx) ? (mx / fmaxf(n, 1e-12f)) : 1.f;
    sv.x *= scale; sv.y *= scale; sv.z *= scale; sv.w *= scale;
    *(float4*)(out + (size_t)row * DM + tid * 4) = sv;
}

// ---------------------------------------------------------------------------
// FUSED: residual + two split-K partials + Poincare projection + LayerNorm.
// Writes the projected row (fp32, the residual for the next block) AND the
// LN'd bf16 row. Saves one full 16 MB re-read vs separate kernels.
// ---------------------------------------------------------------------------
__global__ __launch_bounds__(256) void resproj2_ln_kernel(
    const float* __restrict__ a, const float* __restrict__ c0,
    const float* __restrict__ c1, const float* __restrict__ g,
    const float* __restrict__ b, float* __restrict__ out,
    short* __restrict__ obf) {
    const int row = blockIdx.x;
    const int tid = threadIdx.x;
    __shared__ float red[4];
    const float4 av = *(const float4*)(a + (size_t)row * DM + tid * 4);
    const float4 cv = *(const float4*)(c0 + (size_t)row * DM + tid * 4);
    const float4 dv = *(const float4*)(c1 + (size_t)row * DM + tid * 4);
    float4 sv;
    sv.x = av.x + cv.x + dv.x; sv.y = av.y + cv.y + dv.y;
    sv.z = av.z + cv.z + dv.z; sv.w = av.w + cv.w + dv.w;
    float ss = sv.x * sv.x + sv.y * sv.y + sv.z * sv.z + sv.w * sv.w;
    ss = block_sum(ss, red, tid);
    const float n = sqrtf(ss);
    const float mx = 1.f - 1e-5f;
    const float scale = (n > mx) ? (mx / fmaxf(n, 1e-12f)) : 1.f;
    sv.x *= scale; sv.y *= scale; sv.z *= scale; sv.w *= scale;
    *(float4*)(out + (size_t)row * DM + tid * 4) = sv;
    // LayerNorm on the projected row (values already in registers)
    float s = sv.x + sv.y + sv.z + sv.w;
    s = block_sum(s, red, tid);
    const float mean = s * (1.f / (float)DM);
    const float dx0 = sv.x - mean, dx1 = sv.y - mean,
                dx2 = sv.z - mean, dx3 = sv.w - mean;
    float s2 = dx0 * dx0 + dx1 * dx1 + dx2 * dx2 + dx3 * dx3;
    s2 = block_sum(s2, red, tid);
    const float rs = 1.f / sqrtf(s2 * (1.f / (float)DM) + 1e-5f);
    const float4 gv = *(const float4*)(g + tid * 4);
    const float4 bv = *(const float4*)(b + tid * 4);
    const s16x4 ob = {f2bf(dx0 * rs * gv.x + bv.x), f2bf(dx1 * rs * gv.y + bv.y),
                      f2bf(dx2 * rs * gv.z + bv.z), f2bf(dx3 * rs * gv.w + bv.w)};
    *(s16x4*)(obf + (size_t)row * DM + tid * 4) = ob;
}

// ---------------------------------------------------------------------------
// q/k prep: per-head Poincare projection + attention-layout bf16 buffers.
// k2 prescaled by 0.125*log2(e) so attention can use exp2 directly.
// ---------------------------------------------------------------------------
__global__ __launch_bounds__(256) void qk_prep(const short* __restrict__ qkvB,
                                               short* __restrict__ Qb,
                                               short* __restrict__ Kb,
                                               float* __restrict__ k2) {
    const int tid = threadIdx.x, lane = tid & 63;
    const int vec = blockIdx.x * 4 + (tid >> 6);
    const int row = vec >> 4, h = vec & 15;
    const int b = row >> 11, l = row & 2047;
    const size_t dstv = ((size_t)(b * NH + h) * SEQ_L + l) * HD + lane;
    const float mx = 1.f - 1e-5f;
    {   // q
        const float v = bf2f(qkvB[(size_t)row * QKV_S + h * HD + lane]);
        float s = v * v;
#pragma unroll
        for (int m = 32; m; m >>= 1) s += __shfl_xor(s, m);
        const float n = sqrtf(s);
        const float sc = (n > mx) ? (mx / fmaxf(n, 1e-12f)) : 1.f;
        Qb[dstv] = f2bf(v * sc);
    }
    {   // k (+ prescaled squared norm, in log2 units)
        const float v = bf2f(qkvB[(size_t)row * QKV_S + DM + h * HD + lane]);
        float s = v * v;
#pragma unroll
        for (int m = 32; m; m >>= 1) s += __shfl_xor(s, m);
        const float n = sqrtf(s);
        const float sc = (n > mx) ? (mx / fmaxf(n, 1e-12f)) : 1.f;
        Kb[dstv] = f2bf(v * sc);
        if (lane == 0) k2[(size_t)(b * NH + h) * SEQ_L + l] = s * sc * sc * C_K2;
    }
}

// ---------------------------------------------------------------------------
// v prep: transpose to Vtb [b][h][64 hd][L] bf16, with the columns of each
// 32-wide k-block interleaved as [g0 lo4 | g0 hi4 | g1 lo4 | g1 hi4 | ...]
// so the attention PV A-fragment is ONE contiguous aligned 16B load.
// ---------------------------------------------------------------------------
__global__ __launch_bounds__(256) void v_prep(const short* __restrict__ qkvB,
                                              short* __restrict__ Vtb) {
    const int blk = blockIdx.x;
    const int bh = blk >> 5, kt = blk & 31;
    const int b = bh >> 4, h = bh & 15;
    __shared__ short T[64 * 72];
    const int tid = threadIdx.x;
    {
        const int key = tid >> 2, ch = (tid & 3) * 16;
        const size_t src = ((size_t)b * SEQ_L + kt * 64 + key) * QKV_S + 2 * DM + h * HD + ch;
        *(short8*)&T[key * 72 + ch]     = *(const short8*)(qkvB + src);
        *(short8*)&T[key * 72 + ch + 8] = *(const short8*)(qkvB + src + 8);
    }
    __syncthreads();
    const int hd = tid >> 2, kc = (tid & 3) * 16;
    short8 o0, o1;
#pragma unroll
    for (int j = 0; j < 8; ++j) {
        o0[j] = T[(kc + j) * 72 + hd];
        o1[j] = T[(kc + 8 + j) * 72 + hd];
    }
    const int c32 = (kc >> 5) * 32;          // which 32-block (0 or 32)
    const int h4  = ((kc >> 4) & 1) * 4;     // low/high half of the block
    short* dst = Vtb + ((size_t)bh * HD + hd) * SEQ_L + kt * 64 + c32 + h4;
    const s16x4 w0 = {o0[0], o0[1], o0[2], o0[3]};
    const s16x4 w1 = {o0[4], o0[5], o0[6], o0[7]};
    const s16x4 w2 = {o1[0], o1[1], o1[2], o1[3]};
    const s16x4 w3 = {o1[4], o1[5], o1[6], o1[7]};
    *(s16x4*)(dst)      = w0;
    *(s16x4*)(dst + 8)  = w1;
    *(s16x4*)(dst + 16) = w2;
    *(s16x4*)(dst + 24) = w3;
}

// ---------------------------------------------------------------------------
// bf16 MFMA NT GEMM, round 7: global_load_lds staging (m97 structure; m151:
// +35% vs reg-staging at 128^2 tiles) with XOR-swizzled SOURCE addressing
// (rule #21 / m173: gload_lds writes linearly, so lane l fetches global
// column-slot (l&7)^(l>>3); fragment reads XOR the slot with row&7 ->
// conflict-free b128 reads at the exact 8-access/bank floor; without the
// swizzle, linear [128][64] rows are a 2x read penalty).
// Per K-step (BK=64): barrier -> 8x global_load_lds (A,B tiles) -> barrier
// (vmcnt drains; TLP across 3-4 blocks/CU hides it) -> ds_read frags ->
// 32 MFMA. XCD-aware block swizzle retained. Split-K=2 for N=1024 GEMMs.
// ---------------------------------------------------------------------------
template <int BM, int ACT, int OUTBF, int FUSED, int SPLITK>
__global__ __launch_bounds__(256) void gemm_mfma(
    const short* __restrict__ A, const short* __restrict__ Bw,
    const float* __restrict__ bb0, const float* __restrict__ bb1,
    const float* __restrict__ bb2, void* __restrict__ Cout,
    void* __restrict__ Cout2,
    int M, int N, int K) {
    static_assert(BM == 128, "staging assumes BM=128");
    constexpr int RT = BM / 32;
    constexpr bool VEPI = (OUTBF != 0) && (BM == 128);
    // stage: A[128][64] + B[128][64] shorts = 32 KB; VEPI Ot needs 36 KB
    constexpr int RAWS = VEPI ? (4 * 64 * 72) : (2 * 128 * 64);
    __shared__ __align__(16) short raw[RAWS];
    short* As = raw;
    short* Bs = raw + 128 * 64;
    const int tid = threadIdx.x;
    const int wv = tid >> 6, lane = tid & 63;

    // XCD-aware bijective swizzle (grid size % 8 == 0 for all launches)
    const int gx = gridDim.x, gy = gridDim.y;
    const int nwg = gx * gy * gridDim.z;
    int d = blockIdx.x + gx * (blockIdx.y + gy * blockIdx.z);
    d = (d & 7) * (nwg >> 3) + (d >> 3);
    const int bx = d % gx;
    const int byz = d / gx;
    const int by = byz % gy;
    const int bz = byz / gy;

    const int m0 = by * BM, n0 = bx * 128;
    const int wr = (wv & 1) * (BM / 2);
    const int wc = (wv >> 1) * 64;

    const int z = (SPLITK > 1) ? bz : 0;
    const int Kc = K / SPLITK;              // this block's K-chunk length

    // staging source (per-lane, PRE-SWIZZLED column): lane l of each 8-row
    // issue covers LDS (row = base + (l>>3), slot = l&7); it must fetch
    // global slot (l&7)^(row&7) = (l&7)^(l>>3).
    const int srl = lane >> 3;                     // row within 8-row issue
    const int scol = ((lane & 7) ^ srl) * 8;       // swizzled source col (shorts)
    const short* Ag = A + (size_t)(m0 + wv * 32 + srl) * K + z * Kc + scol;
    const short* Bg = Bw + (size_t)(n0 + wv * 32 + srl) * K + z * Kc + scol;
    short* AsW = As + (wv * 32) * 64;              // wave-uniform LDS dest
    short* BsW = Bs + (wv * 32) * 64;

    const f32x4 z4 = {0.f, 0.f, 0.f, 0.f};
    f32x4 acc[RT][4];
#pragma unroll
    for (int r = 0; r < RT; ++r)
#pragma unroll
        for (int c = 0; c < 4; ++c) acc[r][c] = z4;

    const int lrow = lane & 15;
    // fragment read slot offsets (shorts), XOR-unswizzled per row:
    // logical slot = h*4 + (lane>>4); physical = slot ^ (row&7), row&7 = lane&7
    const int roff0 = (((lane >> 4)) ^ (lane & 7)) * 8;
    const int roff1 = ((4 + (lane >> 4)) ^ (lane & 7)) * 8;

    for (int kt = 0; kt < Kc; kt += 64) {
        __syncthreads();                    // prev tile's ds_reads complete
#pragma unroll
        for (int j = 0; j < 4; ++j) {
            async_copy16(Ag + (size_t)(j * 8) * K + kt, AsW + j * 512);
            async_copy16(Bg + (size_t)(j * 8) * K + kt, BsW + j * 512);
        }
        __syncthreads();                    // vmcnt drains: tile in LDS
#pragma unroll
        for (int h = 0; h < 2; ++h) {
            const int ro = h ? roff1 : roff0;
            short8 af[RT], bf[4];
#pragma unroll
            for (int r = 0; r < RT; ++r)
                af[r] = *(const short8*)&As[(wr + r * 16 + lrow) * 64 + ro];
#pragma unroll
            for (int c = 0; c < 4; ++c)
                bf[c] = *(const short8*)&Bs[(wc + c * 16 + lrow) * 64 + ro];
#pragma unroll
            for (int r = 0; r < RT; ++r)
#pragma unroll
                for (int c = 0; c < 4; ++c)
                    acc[r][c] = __builtin_amdgcn_mfma_f32_16x16x32_bf16(af[r], bf[c], acc[r][c], 0, 0, 0);
        }
    }

    void* Cbase = Cout;
    if constexpr (SPLITK > 1) { if (z) Cbase = Cout2; }

    const int col = lane & 15, rb4 = (lane >> 4) * 4;
    if constexpr (VEPI) {
        __syncthreads();   // staging dead; reuse raw as per-wave transpose buffers
        short* Ot = raw + wv * (64 * 72);
#pragma unroll
        for (int c = 0; c < 4; ++c) {
            const int gn = n0 + wc + c * 16 + col;
            float bias;
            if constexpr (FUSED) {
                const int seg = gn >> 10;
                bias = (seg == 0 ? bb0 : seg == 1 ? bb1 : bb2)[gn & 1023];
            } else {
                bias = bb0[gn];
            }
#pragma unroll
            for (int r = 0; r < RT; ++r)
#pragma unroll
                for (int i = 0; i < 4; ++i) {
                    float v = acc[r][c][i] + bias;
                    if constexpr (ACT) v = gelu_fast(v);
                    Ot[(r * 16 + rb4 + i) * 72 + c * 16 + col] = f2bf(v);
                }
        }
        const int orow = lane >> 3, oc = (lane & 7) * 8;
#pragma unroll
        for (int it = 0; it < 8; ++it) {
            const short8 vv = *(const short8*)&Ot[(it * 8 + orow) * 72 + oc];
            *(short8*)((short*)Cbase + (size_t)(m0 + wr + it * 8 + orow) * N + n0 + wc + oc) = vv;
        }
    } else {
#pragma unroll
        for (int c = 0; c < 4; ++c) {
            const int gn = n0 + wc + c * 16 + col;
            float bias;
            if constexpr (FUSED) {
                const int seg = gn >> 10;
                bias = (seg == 0 ? bb0 : seg == 1 ? bb1 : bb2)[gn & 1023];
            } else {
                bias = bb0[gn];
            }
            if constexpr (SPLITK > 1) { if (z) bias = 0.f; }  // bias only in partial 0
#pragma unroll
            for (int r = 0; r < RT; ++r) {
                const int gm = m0 + wr + r * 16 + rb4;
#pragma unroll
                for (int i = 0; i < 4; ++i) {
                    float v = acc[r][c][i] + bias;
                    if constexpr (ACT) v = gelu_fast(v);
                    if constexpr (OUTBF)
                        ((short*)Cbase)[(size_t)(gm + i) * N + gn] = f2bf(v);
                    else
                        ((float*)Cbase)[(size_t)(gm + i) * N + gn] = v;
                }
            }
        }
    }
}

// ---------------------------------------------------------------------------
// MFMA flash attention (unchanged from round 6): single-barrier LDS double
// buffer + XCD swizzle. FETCH 12.5 MB (L2-resident); VALU-limited.
// ---------------------------------------------------------------------------
__global__ __launch_bounds__(256) void attn_mfma2(const short* __restrict__ Qb,
                                                  const short* __restrict__ Kb,
                                                  const short* __restrict__ Vtb,
                                                  const float* __restrict__ k2v,
                                                  short* __restrict__ aO) {
    int d = blockIdx.x + 16 * (blockIdx.y + 16 * blockIdx.z);
    d = (d & 7) * 64 + (d >> 3);            // 512 blocks, bijective
    const int qt = d & 15, h = (d >> 4) & 15, b = d >> 8;
    const int tid = threadIdx.x, wv = tid >> 6, lane = tid & 63;
    const int bh = b * NH + h;
    constexpr int NT = SEQ_L / 64;
    constexpr int BUFS = 64 * 72;    // shorts per K (or V) tile buffer
    __shared__ __align__(16) short smem[4 * BUFS];  // {K,V} x double buffer; Ot reuse
    __shared__ __align__(16) float k2s[SEQ_L];
    const int lrow = lane & 15, q8 = (lane >> 4) * 8, q4 = (lane >> 4) * 4;

    const short* Qh = Qb + (size_t)bh * SEQ_L * HD;
    const short* Kh = Kb + (size_t)bh * SEQ_L * HD;
    const short* Vh = Vtb + (size_t)bh * HD * SEQ_L;
    const float* k2p = k2v + (size_t)bh * SEQ_L;

    short8 qf[2][2];
#pragma unroll
    for (int nt = 0; nt < 2; ++nt)
#pragma unroll
        for (int kc = 0; kc < 2; ++kc)
            qf[nt][kc] = *(const short8*)(Qh +
                (size_t)(qt * 128 + wv * 32 + nt * 16 + lrow) * HD + kc * 32 + q8);

    // k2 -> LDS (2048 floats, 8 per thread)
    {
        const float4 a0 = *(const float4*)(k2p + tid * 4);
        const float4 a1 = *(const float4*)(k2p + 1024 + tid * 4);
        *(float4*)&k2s[tid * 4] = a0;
        *(float4*)&k2s[1024 + tid * 4] = a1;
    }

    const int srow = tid >> 2, sch = (tid & 3) * 16;
    const short* gK = Kh + (size_t)srow * HD + sch;      // + (k0)*HD per tile
    const short* gV = Vh + (size_t)srow * SEQ_L + sch;   // + k0 per tile
    const int woff = srow * 72 + sch;

    // prologue: stage tile 0 into buf 0
    {
        const short8 k0a = *(const short8*)(gK);
        const short8 k0b = *(const short8*)(gK + 8);
        const short8 v0a = *(const short8*)(gV);
        const short8 v0b = *(const short8*)(gV + 8);
        *(short8*)&smem[woff]            = k0a;
        *(short8*)&smem[woff + 8]        = k0b;
        *(short8*)&smem[BUFS + woff]     = v0a;
        *(short8*)&smem[BUFS + woff + 8] = v0b;
    }
    __syncthreads();

    const f32x4 z4 = {0.f, 0.f, 0.f, 0.f};
    f32x4 o[4][2];   // O^T accum: [ht(hd)][nt(qrow)]
#pragma unroll
    for (int ht = 0; ht < 4; ++ht)
#pragma unroll
        for (int nt = 0; nt < 2; ++nt) o[ht][nt] = z4;
    float lsum[2] = {0.f, 0.f};

    for (int kt = 0; kt < NT; ++kt) {
        const int k0 = kt * 64;
        const short* Ks = smem + (kt & 1) * (2 * BUFS);
        const short* Vt = Ks + BUFS;
        // issue next tile's loads FIRST (latency hides under this tile's math)
        short8 nk0, nk1, nv0, nv1;
        const bool more = (kt + 1 < NT);
        if (more) {
            const short* g = gK + (size_t)(k0 + 64) * HD;
            nk0 = *(const short8*)(g);
            nk1 = *(const short8*)(g + 8);
            const short* gv2 = gV + (k0 + 64);
            nv0 = *(const short8*)(gv2);
            nv1 = *(const short8*)(gv2 + 8);
        }

        i32x4 pw[2][2];   // [nt][c] packed bf16 P fragments (short8 each)
#pragma unroll
        for (int mt = 0; mt < 4; ++mt) {
            const short8 kf0 = *(const short8*)&Ks[(mt * 16 + lrow) * 72 + q8];
            const short8 kf1 = *(const short8*)&Ks[(mt * 16 + lrow) * 72 + 32 + q8];
            const float4 kk = *(const float4*)&k2s[k0 + mt * 16 + q4];
            const int c = mt >> 1, wb = (mt & 1) * 2;
#pragma unroll
            for (int nt = 0; nt < 2; ++nt) {
                f32x4 s = z4;
                s = __builtin_amdgcn_mfma_f32_16x16x32_bf16(kf0, qf[nt][0], s, 0, 0, 0);
                s = __builtin_amdgcn_mfma_f32_16x16x32_bf16(kf1, qf[nt][1], s, 0, 0, 0);
                const float p0 = EXP2(fmaf(s[0], C_QK, -kk.x));
                const float p1 = EXP2(fmaf(s[1], C_QK, -kk.y));
                const float p2 = EXP2(fmaf(s[2], C_QK, -kk.z));
                const float p3 = EXP2(fmaf(s[3], C_QK, -kk.w));
                lsum[nt] += (p0 + p1) + (p2 + p3);
                pw[nt][c][wb]     = cvt_pk_bf16(p0, p1);
                pw[nt][c][wb + 1] = cvt_pk_bf16(p2, p3);
            }
        }
#pragma unroll
        for (int ht = 0; ht < 4; ++ht) {
#pragma unroll
            for (int c = 0; c < 2; ++c) {
                const short8 v8 = *(const short8*)&Vt[(ht * 16 + lrow) * 72 + c * 32 + q4 * 2];
#pragma unroll
                for (int nt = 0; nt < 2; ++nt)
                    o[ht][nt] = __builtin_amdgcn_mfma_f32_16x16x32_bf16(
                        v8, __builtin_bit_cast(short8, pw[nt][c]), o[ht][nt], 0, 0, 0);
            }
        }

        if (more) {   // vmcnt wait lands here, AFTER the compute above
            short* Kd = smem + ((kt + 1) & 1) * (2 * BUFS);
            *(short8*)&Kd[woff]            = nk0;
            *(short8*)&Kd[woff + 8]        = nk1;
            *(short8*)&Kd[BUFS + woff]     = nv0;
            *(short8*)&Kd[BUFS + woff + 8] = nv1;
        }
        __syncthreads();                    // single barrier per tile
    }

#pragma unroll
    for (int nt = 0; nt < 2; ++nt) {
        lsum[nt] += __shfl_xor(lsum[nt], 16);
        lsum[nt] += __shfl_xor(lsum[nt], 32);
    }
    const float inv0 = 1.f / lsum[0], inv1 = 1.f / lsum[1];

    // wave-private Ot transpose buffers (all loop reads done: post-barrier)
    short* Ot = smem + wv * (32 * 72);
#pragma unroll
    for (int ht = 0; ht < 4; ++ht)
#pragma unroll
        for (int nt = 0; nt < 2; ++nt) {
            const float iv = nt ? inv1 : inv0;
            const s16x4 ov = {f2bf(o[ht][nt][0] * iv), f2bf(o[ht][nt][1] * iv),
                              f2bf(o[ht][nt][2] * iv), f2bf(o[ht][nt][3] * iv)};
            *(s16x4*)&Ot[(nt * 16 + lrow) * 72 + ht * 16 + q4] = ov;
        }
    const int erow = lane >> 1, ec = (lane & 1) * 32;
    const short8 r0 = *(const short8*)&Ot[erow * 72 + ec + 0];
    const short8 r1 = *(const short8*)&Ot[erow * 72 + ec + 8];
    const short8 r2 = *(const short8*)&Ot[erow * 72 + ec + 16];
    const short8 r3 = *(const short8*)&Ot[erow * 72 + ec + 24];
    short* dst = aO + ((size_t)b * SEQ_L + qt * 128 + wv * 32 + erow) * DM + h * HD + ec;
    *(short8*)(dst + 0)  = r0;
    *(short8*)(dst + 8)  = r1;
    *(short8*)(dst + 16) = r2;
    *(short8*)(dst + 24) = r3;
}

// ---------------------------------------------------------------------------
// Launch
// ---------------------------------------------------------------------------
extern "C" void kernel_launch(void* const* d_in, const int* in_sizes, int n_in,
                              void* d_out, int out_size, void* d_ws, size_t ws_size,
                              hipStream_t stream) {
    const float* x   = (const float*)d_in[0];
    const float* wq  = (const float*)d_in[1];
    const float* bq  = (const float*)d_in[2];
    const float* wk  = (const float*)d_in[3];
    const float* bk  = (const float*)d_in[4];
    const float* wv  = (const float*)d_in[5];
    const float* bv  = (const float*)d_in[6];
    const float* wo  = (const float*)d_in[7];
    const float* bo  = (const float*)d_in[8];
    const float* g1  = (const float*)d_in[9];
    const float* b1  = (const float*)d_in[10];
    const float* g2  = (const float*)d_in[11];
    const float* b2  = (const float*)d_in[12];
    const float* w1  = (const float*)d_in[13];
    const float* bf1 = (const float*)d_in[14];
    const float* w2  = (const float*)d_in[15];
    const float* bf2 = (const float*)d_in[16];
    float* out = (float*)d_out;

    // ws layout (MiB, all offsets within the previously-validated 80.25 MiB):
    // [0,24)    wbf bf16 weights (wq..wo [0,8), w1 [8,16), w2 [16,24))
    // [24,48)   qkvB bf16 [BL][3072]; later hbuf bf16 [BL][4096] = [24,56)
    // [24,40)   P  fp32 out-proj partial 0 (over dead qkvB)
    // [40,56)   P2 fp32 out-proj partial 1 (dead qkvB tail + dead Qb)
    // [48,56)   xnb/Qb (dead after attn)
    // [56,64)   Kb (dead after attn)     [64,72) Vtb/xn2b (dead after FFN1)
    // [72,72.25) k2   [72.25,80.25) aO (dead after out-proj)
    // [0,16)    y0 fp32 FFN2 partial 0 (over dead wq..wo,w1; w2 [16,24) live)
    // [56,72)   y1 fp32 FFN2 partial 1 (over dead Kb,Vtb)
    char* base = (char*)d_ws;
    short* wbf  = (short*)base;
    short* qkvB = (short*)(base + (24u << 20));
    short* xnb  = (short*)(base + (48u << 20));
    short* Qb   = xnb;
    short* Kb   = (short*)(base + (56u << 20));
    short* Vtb  = (short*)(base + (64u << 20));
    float* k2   = (float*)(base + (72u << 20));
    short* aO   = (short*)(base + (72u << 20) + (256u << 10));
    float* P    = (float*)(base + (24u << 20));
    float* P2   = (float*)(base + (40u << 20));
    short* xn2b = Vtb;
    short* hbuf = qkvB;
    float* y0   = (float*)base;                     // FFN2 partial 0
    float* y1   = (float*)(base + (56u << 20));     // FFN2 partial 1

    // 0. weights -> bf16
    cvt6_kernel<<<12288, 256, 0, stream>>>(wq, wk, wv, wo, w1, w2, wbf);
    // 1. LN1 -> bf16
    ln_bf16_kernel<<<BL, 256, 0, stream>>>(x, g1, b1, xnb);
    // 2. fused QKV projection -> bf16 [BL][3072]
    gemm_mfma<128, 0, 1, 1, 1><<<dim3(24, 32), 256, 0, stream>>>(
        xnb, wbf, bq, bk, bv, qkvB, nullptr, BL, QKV_S, DM);
    // 3. prep: project q,k -> Qb/Kb [bh][L][64] + k2; transpose v -> Vtb
    qk_prep<<<16384, 256, 0, stream>>>(qkvB, Qb, Kb, k2);
    v_prep<<<1024, 256, 0, stream>>>(qkvB, Vtb);
    // 4. flash MFMA attention -> aO bf16
    attn_mfma2<<<dim3(16, 16, 2), 256, 0, stream>>>(Qb, Kb, Vtb, k2, aO);
    // 5. output projection, BM=128 split-K=2 -> P,P2 fp32 partials
    gemm_mfma<128, 0, 0, 0, 2><<<dim3(8, 32, 2), 256, 0, stream>>>(
        aO, wbf + 3145728, bo, bo, bo, P, P2, BL, DM, DM);
    // 6+7. x1 = project(x + P + P2) -> d_out, fused with LN2 -> xn2b
    resproj2_ln_kernel<<<BL, 256, 0, stream>>>(x, P, P2, g2, b2, out, xn2b);
    // 8. FFN1 + GELU -> bf16 hidden
    gemm_mfma<128, 1, 1, 0, 1><<<dim3(32, 32), 256, 0, stream>>>(
        xn2b, wbf + 4194304, bf1, bf1, bf1, hbuf, nullptr, BL, DFF, DM);
    // 9. FFN2, BM=128 split-K=2 -> y0,y1 fp32 partials
    gemm_mfma<128, 0, 0, 0, 2><<<dim3(8, 32, 2), 256, 0, stream>>>(
        hbuf, wbf + 8388608, bf2, bf2, bf2, y0, y1, BL, DM, DFF);
    // 10. out = project(x1 + y0 + y1)
    resproj2_kernel<<<BL, 256, 0, stream>>>(out, y0, y1, out);
}

// Round 8
// 373.264 us; speedup vs baseline: 1.2587x; 1.0147x over previous
//
#include <hip/hip_runtime.h>
#include <math.h>

// Problem constants: B=2, L=2048, D=1024, H=16, hd=64, Dff=4096
#define SEQ_L 2048
#define DM    1024
#define NH    16
#define HD    64
#define BL    4096          // B*L
#define DFF   4096
#define QKV_S 3072          // fused qkv row stride

typedef __attribute__((ext_vector_type(8))) short short8;   // 8 bf16 (4 VGPRs)
typedef __attribute__((ext_vector_type(4))) short s16x4;    // 4 bf16
typedef __attribute__((ext_vector_type(4))) float f32x4;    // MFMA C/D frag
typedef __attribute__((ext_vector_type(4))) int   i32x4;    // 4 packed bf16x2

// 0.25*log2(e), 0.125*log2(e) — fold exp->exp2 base change into the scales
#define C_QK  0.36067376022224085f
#define C_K2  0.18033688011112042f

#if __has_builtin(__builtin_amdgcn_exp2f)
#define EXP2(x) __builtin_amdgcn_exp2f(x)
#else
#define EXP2(x) exp2f(x)
#endif

// fp32 -> bf16 round-to-nearest-even
__device__ __forceinline__ short f2bf(float x) {
    unsigned u = __float_as_uint(x);
    u += 0x7fff + ((u >> 16) & 1);
    return (short)(u >> 16);
}
__device__ __forceinline__ float bf2f(short s) {
    return __uint_as_float(((unsigned)(unsigned short)s) << 16);
}
// pack two f32 -> one u32 of 2x bf16 (RNE); no builtin on gfx950 (m240)
__device__ __forceinline__ int cvt_pk_bf16(float lo, float hi) {
    int r;
    asm("v_cvt_pk_bf16_f32 %0, %1, %2" : "=v"(r) : "v"(lo), "v"(hi));
    return r;
}
// async global->LDS, 16 B per lane; LDS dest is wave-uniform base + lane*16
__device__ __forceinline__ void async_copy16(const short* gsrc, short* ldst) {
    __builtin_amdgcn_global_load_lds(
        (const __attribute__((address_space(1))) unsigned int*)gsrc,
        (__attribute__((address_space(3))) unsigned int*)ldst, 16, 0, 0);
}

// branch-free GELU (erf form) via A&S 7.1.26, |abs err| <= ~2e-7.
__device__ __forceinline__ float gelu_fast(float x) {
    const float xa = fabsf(x);
    const float z = xa * 0.70710678118654752440f;
    const float t = __builtin_amdgcn_rcpf(fmaf(0.3275911f, z, 1.f));
    float P = fmaf(t, 1.061405429f, -1.453152027f);
    P = fmaf(t, P, 1.421413741f);
    P = fmaf(t, P, -0.284496736f);
    P = fmaf(t, P, 0.254829592f);
    P *= t;
    const float e = __expf(-z * z);
    const float erfp = fmaf(-P, e, 1.f);   // erf(|x|/sqrt2)
    return 0.5f * fmaf(xa, erfp, x);
}

__device__ __forceinline__ float block_sum(float v, float* red, int tid) {
#pragma unroll
    for (int m = 32; m; m >>= 1) v += __shfl_xor(v, m);
    if ((tid & 63) == 0) red[tid >> 6] = v;
    __syncthreads();
    v = red[0] + red[1] + red[2] + red[3];
    __syncthreads();
    return v;
}

// ---------------------------------------------------------------------------
// Weight fp32 -> bf16: wq|wk|wv|wo|w1|w2 contiguous (fused QKV needs this).
// ---------------------------------------------------------------------------
__global__ __launch_bounds__(256) void cvt6_kernel(
    const float* __restrict__ wq, const float* __restrict__ wk,
    const float* __restrict__ wv, const float* __restrict__ wo,
    const float* __restrict__ w1, const float* __restrict__ w2,
    short* __restrict__ dst) {
    const size_t i = (size_t)blockIdx.x * 256 + threadIdx.x;  // float4 index
    const float* src;
    size_t off;
    if (i < 1048576) {
        const int seg = (int)(i >> 18);
        off = i & 262143;
        src = seg == 0 ? wq : seg == 1 ? wk : seg == 2 ? wv : wo;
    } else if (i < 2097152) { src = w1; off = i - 1048576; }
    else                    { src = w2; off = i - 2097152; }
    const float4 v = ((const float4*)src)[off];
    const s16x4 o = {f2bf(v.x), f2bf(v.y), f2bf(v.z), f2bf(v.w)};
    ((s16x4*)dst)[i] = o;
}

// ---------------------------------------------------------------------------
// LayerNorm over rows of 1024, bf16 output.
// ---------------------------------------------------------------------------
__global__ __launch_bounds__(256) void ln_bf16_kernel(const float* __restrict__ x,
                                                      const float* __restrict__ g,
                                                      const float* __restrict__ b,
                                                      short* __restrict__ out) {
    const int row = blockIdx.x;
    const int tid = threadIdx.x;
    __shared__ float red[4];
    const float4 xv = *(const float4*)(x + (size_t)row * DM + tid * 4);
    float s = xv.x + xv.y + xv.z + xv.w;
    s = block_sum(s, red, tid);
    const float mean = s * (1.f / (float)DM);
    float dx0 = xv.x - mean, dx1 = xv.y - mean, dx2 = xv.z - mean, dx3 = xv.w - mean;
    float ss = dx0 * dx0 + dx1 * dx1 + dx2 * dx2 + dx3 * dx3;
    ss = block_sum(ss, red, tid);
    const float rs = 1.f / sqrtf(ss * (1.f / (float)DM) + 1e-5f);
    const float4 gv = *(const float4*)(g + tid * 4);
    const float4 bv = *(const float4*)(b + tid * 4);
    const s16x4 ob = {f2bf(dx0 * rs * gv.x + bv.x), f2bf(dx1 * rs * gv.y + bv.y),
                      f2bf(dx2 * rs * gv.z + bv.z), f2bf(dx3 * rs * gv.w + bv.w)};
    *(s16x4*)(out + (size_t)row * DM + tid * 4) = ob;
}

// ---------------------------------------------------------------------------
// Residual + TWO split-K partials + Poincare projection (fp32, in-place safe).
// ---------------------------------------------------------------------------
__global__ __launch_bounds__(256) void resproj2_kernel(const float* __restrict__ a,
                                                       const float* __restrict__ c0,
                                                       const float* __restrict__ c1,
                                                       float* __restrict__ out) {
    const int row = blockIdx.x;
    const int tid = threadIdx.x;
    __shared__ float red[4];
    const float4 av = *(const float4*)(a + (size_t)row * DM + tid * 4);
    const float4 cv = *(const float4*)(c0 + (size_t)row * DM + tid * 4);
    const float4 dv = *(const float4*)(c1 + (size_t)row * DM + tid * 4);
    float4 sv;
    sv.x = av.x + cv.x + dv.x; sv.y = av.y + cv.y + dv.y;
    sv.z = av.z + cv.z + dv.z; sv.w = av.w + cv.w + dv.w;
    float ss = sv.x * sv.x + sv.y * sv.y + sv.z * sv.z + sv.w * sv.w;
    ss = block_sum(ss, red, tid);
    const float n = sqrtf(ss);
    const float mx = 1.f - 1e-5f;
    const float scale = (n > mx) ? (mx / fmaxf(n, 1e-12f)) : 1.f;
    sv.x *= scale; sv.y *= scale; sv.z *= scale; sv.w *= scale;
    *(float4*)(out + (size_t)row * DM + tid * 4) = sv;
}

// ---------------------------------------------------------------------------
// FUSED: residual + two split-K partials + Poincare projection + LayerNorm.
// ---------------------------------------------------------------------------
__global__ __launch_bounds__(256) void resproj2_ln_kernel(
    const float* __restrict__ a, const float* __restrict__ c0,
    const float* __restrict__ c1, const float* __restrict__ g,
    const float* __restrict__ b, float* __restrict__ out,
    short* __restrict__ obf) {
    const int row = blockIdx.x;
    const int tid = threadIdx.x;
    __shared__ float red[4];
    const float4 av = *(const float4*)(a + (size_t)row * DM + tid * 4);
    const float4 cv = *(const float4*)(c0 + (size_t)row * DM + tid * 4);
    const float4 dv = *(const float4*)(c1 + (size_t)row * DM + tid * 4);
    float4 sv;
    sv.x = av.x + cv.x + dv.x; sv.y = av.y + cv.y + dv.y;
    sv.z = av.z + cv.z + dv.z; sv.w = av.w + cv.w + dv.w;
    float ss = sv.x * sv.x + sv.y * sv.y + sv.z * sv.z + sv.w * sv.w;
    ss = block_sum(ss, red, tid);
    const float n = sqrtf(ss);
    const float mx = 1.f - 1e-5f;
    const float scale = (n > mx) ? (mx / fmaxf(n, 1e-12f)) : 1.f;
    sv.x *= scale; sv.y *= scale; sv.z *= scale; sv.w *= scale;
    *(float4*)(out + (size_t)row * DM + tid * 4) = sv;
    // LayerNorm on the projected row (values already in registers)
    float s = sv.x + sv.y + sv.z + sv.w;
    s = block_sum(s, red, tid);
    const float mean = s * (1.f / (float)DM);
    const float dx0 = sv.x - mean, dx1 = sv.y - mean,
                dx2 = sv.z - mean, dx3 = sv.w - mean;
    float s2 = dx0 * dx0 + dx1 * dx1 + dx2 * dx2 + dx3 * dx3;
    s2 = block_sum(s2, red, tid);
    const float rs = 1.f / sqrtf(s2 * (1.f / (float)DM) + 1e-5f);
    const float4 gv = *(const float4*)(g + tid * 4);
    const float4 bv = *(const float4*)(b + tid * 4);
    const s16x4 ob = {f2bf(dx0 * rs * gv.x + bv.x), f2bf(dx1 * rs * gv.y + bv.y),
                      f2bf(dx2 * rs * gv.z + bv.z), f2bf(dx3 * rs * gv.w + bv.w)};
    *(s16x4*)(obf + (size_t)row * DM + tid * 4) = ob;
}

// ---------------------------------------------------------------------------
// q/k prep: per-head Poincare projection + attention-layout bf16 buffers.
// k2 prescaled by 0.125*log2(e) so attention can use exp2 directly.
// ---------------------------------------------------------------------------
__global__ __launch_bounds__(256) void qk_prep(const short* __restrict__ qkvB,
                                               short* __restrict__ Qb,
                                               short* __restrict__ Kb,
                                               float* __restrict__ k2) {
    const int tid = threadIdx.x, lane = tid & 63;
    const int vec = blockIdx.x * 4 + (tid >> 6);
    const int row = vec >> 4, h = vec & 15;
    const int b = row >> 11, l = row & 2047;
    const size_t dstv = ((size_t)(b * NH + h) * SEQ_L + l) * HD + lane;
    const float mx = 1.f - 1e-5f;
    {   // q
        const float v = bf2f(qkvB[(size_t)row * QKV_S + h * HD + lane]);
        float s = v * v;
#pragma unroll
        for (int m = 32; m; m >>= 1) s += __shfl_xor(s, m);
        const float n = sqrtf(s);
        const float sc = (n > mx) ? (mx / fmaxf(n, 1e-12f)) : 1.f;
        Qb[dstv] = f2bf(v * sc);
    }
    {   // k (+ prescaled squared norm, in log2 units)
        const float v = bf2f(qkvB[(size_t)row * QKV_S + DM + h * HD + lane]);
        float s = v * v;
#pragma unroll
        for (int m = 32; m; m >>= 1) s += __shfl_xor(s, m);
        const float n = sqrtf(s);
        const float sc = (n > mx) ? (mx / fmaxf(n, 1e-12f)) : 1.f;
        Kb[dstv] = f2bf(v * sc);
        if (lane == 0) k2[(size_t)(b * NH + h) * SEQ_L + l] = s * sc * sc * C_K2;
    }
}

// ---------------------------------------------------------------------------
// v prep: transpose to Vtb [b][h][64 hd][L] bf16, with the columns of each
// 32-wide k-block interleaved as [g0 lo4 | g0 hi4 | g1 lo4 | g1 hi4 | ...]
// so the attention PV A-fragment is ONE contiguous aligned 16B load.
// ---------------------------------------------------------------------------
__global__ __launch_bounds__(256) void v_prep(const short* __restrict__ qkvB,
                                              short* __restrict__ Vtb) {
    const int blk = blockIdx.x;
    const int bh = blk >> 5, kt = blk & 31;
    const int b = bh >> 4, h = bh & 15;
    __shared__ short T[64 * 72];
    const int tid = threadIdx.x;
    {
        const int key = tid >> 2, ch = (tid & 3) * 16;
        const size_t src = ((size_t)b * SEQ_L + kt * 64 + key) * QKV_S + 2 * DM + h * HD + ch;
        *(short8*)&T[key * 72 + ch]     = *(const short8*)(qkvB + src);
        *(short8*)&T[key * 72 + ch + 8] = *(const short8*)(qkvB + src + 8);
    }
    __syncthreads();
    const int hd = tid >> 2, kc = (tid & 3) * 16;
    short8 o0, o1;
#pragma unroll
    for (int j = 0; j < 8; ++j) {
        o0[j] = T[(kc + j) * 72 + hd];
        o1[j] = T[(kc + 8 + j) * 72 + hd];
    }
    const int c32 = (kc >> 5) * 32;          // which 32-block (0 or 32)
    const int h4  = ((kc >> 4) & 1) * 4;     // low/high half of the block
    short* dst = Vtb + ((size_t)bh * HD + hd) * SEQ_L + kt * 64 + c32 + h4;
    const s16x4 w0 = {o0[0], o0[1], o0[2], o0[3]};
    const s16x4 w1 = {o0[4], o0[5], o0[6], o0[7]};
    const s16x4 w2 = {o1[0], o1[1], o1[2], o1[3]};
    const s16x4 w3 = {o1[4], o1[5], o1[6], o1[7]};
    *(s16x4*)(dst)      = w0;
    *(s16x4*)(dst + 8)  = w1;
    *(s16x4*)(dst + 16) = w2;
    *(s16x4*)(dst + 24) = w3;
}

// ---------------------------------------------------------------------------
// bf16 MFMA NT GEMM, round 8: SINGLE-BARRIER double-buffered global_load_lds
// (catalog "minimum 2-phase"; same schedule fix that took attention 79->60
// in r5). Round 7's m97-style 2-barrier loop exposed the full staging
// latency between its two barriers (neutral result). Now, per BK=32 step:
//   barrier (drains stage-t writes + all waves' prev ds_reads)
//   -> issue 4 global_load_lds for tile t+1 into buf^1 (async, in flight
//      through the compute below)
//   -> ds_read frags from buf -> 16 MFMA -> cur ^= 1
// Race audit: the barrier forces vmcnt(0)+lgkmcnt(0) on every wave, so no
// wave still reads buf^1 when another starts staging it, and stage-t data
// is complete before any wave reads it.
// LDS: 2 x (A[128][32]+B[128][32]) = 32 KB -> 4-5 blocks/CU.
// Swizzle (32-short rows, b128 uniform-bank floor): write source col slot
// (l&3)^((l>>3)&3); read slot (lane>>4)^((lrow>>1)&3).
// XCD-aware block swizzle + split-K=2 for N=1024 GEMMs retained.
// ---------------------------------------------------------------------------
template <int BM, int ACT, int OUTBF, int FUSED, int SPLITK>
__global__ __launch_bounds__(256) void gemm_mfma(
    const short* __restrict__ A, const short* __restrict__ Bw,
    const float* __restrict__ bb0, const float* __restrict__ bb1,
    const float* __restrict__ bb2, void* __restrict__ Cout,
    void* __restrict__ Cout2,
    int M, int N, int K) {
    static_assert(BM == 128, "staging assumes BM=128");
    constexpr int RT = BM / 32;
    constexpr bool VEPI = (OUTBF != 0) && (BM == 128);
    constexpr int BUFSH = 2 * 128 * 32;     // A+B per buffer (8192 shorts)
    constexpr int RAWS = VEPI ? (4 * 64 * 72) : (2 * BUFSH);
    static_assert(!VEPI || RAWS >= 2 * BUFSH, "VEPI smem too small");
    __shared__ __align__(16) short raw[RAWS];
    const int tid = threadIdx.x;
    const int wv = tid >> 6, lane = tid & 63;

    // XCD-aware bijective swizzle (grid size % 8 == 0 for all launches)
    const int gx = gridDim.x, gy = gridDim.y;
    const int nwg = gx * gy * gridDim.z;
    int d = blockIdx.x + gx * (blockIdx.y + gy * blockIdx.z);
    d = (d & 7) * (nwg >> 3) + (d >> 3);
    const int bx = d % gx;
    const int byz = d / gx;
    const int by = byz % gy;
    const int bz = byz / gy;

    const int m0 = by * BM, n0 = bx * 128;
    const int wr = (wv & 1) * (BM / 2);
    const int wc = (wv >> 1) * 64;

    const int z = (SPLITK > 1) ? bz : 0;
    const int Kc = K / SPLITK;              // this block's K-chunk length

    // staging: wave wv covers A rows [wv*32, wv*32+32) and B rows same,
    // 2 issues each (16 rows x 32 shorts = 1 KB per issue).
    const int srl = lane >> 2;                       // row within 16-row issue
    const int scol = ((lane & 3) ^ ((lane >> 3) & 3)) * 8;  // swizzled src col
    const short* Ag = A + (size_t)(m0 + wv * 32 + srl) * K + z * Kc + scol;
    const short* Bg = Bw + (size_t)(n0 + wv * 32 + srl) * K + z * Kc + scol;
    short* ldsA = raw + (wv * 32) * 32;              // + buf*BUFSH ; +j*16*32
    short* ldsB = raw + 128 * 32 + (wv * 32) * 32;

    const f32x4 z4 = {0.f, 0.f, 0.f, 0.f};
    f32x4 acc[RT][4];
#pragma unroll
    for (int r = 0; r < RT; ++r)
#pragma unroll
        for (int c = 0; c < 4; ++c) acc[r][c] = z4;

    const int lrow = lane & 15;
    const int rdoff = ((lane >> 4) ^ ((lrow >> 1) & 3)) * 8;  // phys slot (shorts)

    // prologue: stage tile 0 into buffer 0 (async; drained at first barrier)
#pragma unroll
    for (int j = 0; j < 2; ++j) {
        async_copy16(Ag + (size_t)(16 * j) * K, ldsA + (16 * j) * 32);
        async_copy16(Bg + (size_t)(16 * j) * K, ldsB + (16 * j) * 32);
    }

    int cur = 0;
    for (int kt = 0; kt < Kc; kt += 32) {
        __syncthreads();        // drains vmcnt (stage t landed) + lgkm (reads done)
        if (kt + 32 < Kc) {     // stage t+1 into the other buffer, async
            const int nb = (cur ^ 1) * BUFSH;
#pragma unroll
            for (int j = 0; j < 2; ++j) {
                async_copy16(Ag + (size_t)(16 * j) * K + kt + 32, ldsA + nb + (16 * j) * 32);
                async_copy16(Bg + (size_t)(16 * j) * K + kt + 32, ldsB + nb + (16 * j) * 32);
            }
        }
        const short* As = raw + cur * BUFSH;
        const short* Bs = As + 128 * 32;
        short8 af[RT], bf[4];
#pragma unroll
        for (int r = 0; r < RT; ++r)
            af[r] = *(const short8*)&As[(wr + r * 16 + lrow) * 32 + rdoff];
#pragma unroll
        for (int c = 0; c < 4; ++c)
            bf[c] = *(const short8*)&Bs[(wc + c * 16 + lrow) * 32 + rdoff];
#pragma unroll
        for (int r = 0; r < RT; ++r)
#pragma unroll
            for (int c = 0; c < 4; ++c)
                acc[r][c] = __builtin_amdgcn_mfma_f32_16x16x32_bf16(af[r], bf[c], acc[r][c], 0, 0, 0);
        cur ^= 1;
    }

    void* Cbase = Cout;
    if constexpr (SPLITK > 1) { if (z) Cbase = Cout2; }

    const int col = lane & 15, rb4 = (lane >> 4) * 4;
    if constexpr (VEPI) {
        __syncthreads();   // staging dead; reuse raw as per-wave transpose buffers
        short* Ot = raw + wv * (64 * 72);
#pragma unroll
        for (int c = 0; c < 4; ++c) {
            const int gn = n0 + wc + c * 16 + col;
            float bias;
            if constexpr (FUSED) {
                const int seg = gn >> 10;
                bias = (seg == 0 ? bb0 : seg == 1 ? bb1 : bb2)[gn & 1023];
            } else {
                bias = bb0[gn];
            }
#pragma unroll
            for (int r = 0; r < RT; ++r)
#pragma unroll
                for (int i = 0; i < 4; ++i) {
                    float v = acc[r][c][i] + bias;
                    if constexpr (ACT) v = gelu_fast(v);
                    Ot[(r * 16 + rb4 + i) * 72 + c * 16 + col] = f2bf(v);
                }
        }
        const int orow = lane >> 3, oc = (lane & 7) * 8;
#pragma unroll
        for (int it = 0; it < 8; ++it) {
            const short8 vv = *(const short8*)&Ot[(it * 8 + orow) * 72 + oc];
            *(short8*)((short*)Cbase + (size_t)(m0 + wr + it * 8 + orow) * N + n0 + wc + oc) = vv;
        }
    } else {
#pragma unroll
        for (int c = 0; c < 4; ++c) {
            const int gn = n0 + wc + c * 16 + col;
            float bias;
            if constexpr (FUSED) {
                const int seg = gn >> 10;
                bias = (seg == 0 ? bb0 : seg == 1 ? bb1 : bb2)[gn & 1023];
            } else {
                bias = bb0[gn];
            }
            if constexpr (SPLITK > 1) { if (z) bias = 0.f; }  // bias only in partial 0
#pragma unroll
            for (int r = 0; r < RT; ++r) {
                const int gm = m0 + wr + r * 16 + rb4;
#pragma unroll
                for (int i = 0; i < 4; ++i) {
                    float v = acc[r][c][i] + bias;
                    if constexpr (ACT) v = gelu_fast(v);
                    if constexpr (OUTBF)
                        ((short*)Cbase)[(size_t)(gm + i) * N + gn] = f2bf(v);
                    else
                        ((float*)Cbase)[(size_t)(gm + i) * N + gn] = v;
                }
            }
        }
    }
}

// ---------------------------------------------------------------------------
// MFMA flash attention (unchanged from round 6): single-barrier LDS double
// buffer + XCD swizzle. FETCH 12.5 MB (L2-resident); VALU-limited.
// ---------------------------------------------------------------------------
__global__ __launch_bounds__(256) void attn_mfma2(const short* __restrict__ Qb,
                                                  const short* __restrict__ Kb,
                                                  const short* __restrict__ Vtb,
                                                  const float* __restrict__ k2v,
                                                  short* __restrict__ aO) {
    int d = blockIdx.x + 16 * (blockIdx.y + 16 * blockIdx.z);
    d = (d & 7) * 64 + (d >> 3);            // 512 blocks, bijective
    const int qt = d & 15, h = (d >> 4) & 15, b = d >> 8;
    const int tid = threadIdx.x, wv = tid >> 6, lane = tid & 63;
    const int bh = b * NH + h;
    constexpr int NT = SEQ_L / 64;
    constexpr int BUFS = 64 * 72;    // shorts per K (or V) tile buffer
    __shared__ __align__(16) short smem[4 * BUFS];  // {K,V} x double buffer; Ot reuse
    __shared__ __align__(16) float k2s[SEQ_L];
    const int lrow = lane & 15, q8 = (lane >> 4) * 8, q4 = (lane >> 4) * 4;

    const short* Qh = Qb + (size_t)bh * SEQ_L * HD;
    const short* Kh = Kb + (size_t)bh * SEQ_L * HD;
    const short* Vh = Vtb + (size_t)bh * HD * SEQ_L;
    const float* k2p = k2v + (size_t)bh * SEQ_L;

    short8 qf[2][2];
#pragma unroll
    for (int nt = 0; nt < 2; ++nt)
#pragma unroll
        for (int kc = 0; kc < 2; ++kc)
            qf[nt][kc] = *(const short8*)(Qh +
                (size_t)(qt * 128 + wv * 32 + nt * 16 + lrow) * HD + kc * 32 + q8);

    // k2 -> LDS (2048 floats, 8 per thread)
    {
        const float4 a0 = *(const float4*)(k2p + tid * 4);
        const float4 a1 = *(const float4*)(k2p + 1024 + tid * 4);
        *(float4*)&k2s[tid * 4] = a0;
        *(float4*)&k2s[1024 + tid * 4] = a1;
    }

    const int srow = tid >> 2, sch = (tid & 3) * 16;
    const short* gK = Kh + (size_t)srow * HD + sch;      // + (k0)*HD per tile
    const short* gV = Vh + (size_t)srow * SEQ_L + sch;   // + k0 per tile
    const int woff = srow * 72 + sch;

    // prologue: stage tile 0 into buf 0
    {
        const short8 k0a = *(const short8*)(gK);
        const short8 k0b = *(const short8*)(gK + 8);
        const short8 v0a = *(const short8*)(gV);
        const short8 v0b = *(const short8*)(gV + 8);
        *(short8*)&smem[woff]            = k0a;
        *(short8*)&smem[woff + 8]        = k0b;
        *(short8*)&smem[BUFS + woff]     = v0a;
        *(short8*)&smem[BUFS + woff + 8] = v0b;
    }
    __syncthreads();

    const f32x4 z4 = {0.f, 0.f, 0.f, 0.f};
    f32x4 o[4][2];   // O^T accum: [ht(hd)][nt(qrow)]
#pragma unroll
    for (int ht = 0; ht < 4; ++ht)
#pragma unroll
        for (int nt = 0; nt < 2; ++nt) o[ht][nt] = z4;
    float lsum[2] = {0.f, 0.f};

    for (int kt = 0; kt < NT; ++kt) {
        const int k0 = kt * 64;
        const short* Ks = smem + (kt & 1) * (2 * BUFS);
        const short* Vt = Ks + BUFS;
        // issue next tile's loads FIRST (latency hides under this tile's math)
        short8 nk0, nk1, nv0, nv1;
        const bool more = (kt + 1 < NT);
        if (more) {
            const short* g = gK + (size_t)(k0 + 64) * HD;
            nk0 = *(const short8*)(g);
            nk1 = *(const short8*)(g + 8);
            const short* gv2 = gV + (k0 + 64);
            nv0 = *(const short8*)(gv2);
            nv1 = *(const short8*)(gv2 + 8);
        }

        i32x4 pw[2][2];   // [nt][c] packed bf16 P fragments (short8 each)
#pragma unroll
        for (int mt = 0; mt < 4; ++mt) {
            const short8 kf0 = *(const short8*)&Ks[(mt * 16 + lrow) * 72 + q8];
            const short8 kf1 = *(const short8*)&Ks[(mt * 16 + lrow) * 72 + 32 + q8];
            const float4 kk = *(const float4*)&k2s[k0 + mt * 16 + q4];
            const int c = mt >> 1, wb = (mt & 1) * 2;
#pragma unroll
            for (int nt = 0; nt < 2; ++nt) {
                f32x4 s = z4;
                s = __builtin_amdgcn_mfma_f32_16x16x32_bf16(kf0, qf[nt][0], s, 0, 0, 0);
                s = __builtin_amdgcn_mfma_f32_16x16x32_bf16(kf1, qf[nt][1], s, 0, 0, 0);
                const float p0 = EXP2(fmaf(s[0], C_QK, -kk.x));
                const float p1 = EXP2(fmaf(s[1], C_QK, -kk.y));
                const float p2 = EXP2(fmaf(s[2], C_QK, -kk.z));
                const float p3 = EXP2(fmaf(s[3], C_QK, -kk.w));
                lsum[nt] += (p0 + p1) + (p2 + p3);
                pw[nt][c][wb]     = cvt_pk_bf16(p0, p1);
                pw[nt][c][wb + 1] = cvt_pk_bf16(p2, p3);
            }
        }
#pragma unroll
        for (int ht = 0; ht < 4; ++ht) {
#pragma unroll
            for (int c = 0; c < 2; ++c) {
                const short8 v8 = *(const short8*)&Vt[(ht * 16 + lrow) * 72 + c * 32 + q4 * 2];
#pragma unroll
                for (int nt = 0; nt < 2; ++nt)
                    o[ht][nt] = __builtin_amdgcn_mfma_f32_16x16x32_bf16(
                        v8, __builtin_bit_cast(short8, pw[nt][c]), o[ht][nt], 0, 0, 0);
            }
        }

        if (more) {   // vmcnt wait lands here, AFTER the compute above
            short* Kd = smem + ((kt + 1) & 1) * (2 * BUFS);
            *(short8*)&Kd[woff]            = nk0;
            *(short8*)&Kd[woff + 8]        = nk1;
            *(short8*)&Kd[BUFS + woff]     = nv0;
            *(short8*)&Kd[BUFS + woff + 8] = nv1;
        }
        __syncthreads();                    // single barrier per tile
    }

#pragma unroll
    for (int nt = 0; nt < 2; ++nt) {
        lsum[nt] += __shfl_xor(lsum[nt], 16);
        lsum[nt] += __shfl_xor(lsum[nt], 32);
    }
    const float inv0 = 1.f / lsum[0], inv1 = 1.f / lsum[1];

    // wave-private Ot transpose buffers (all loop reads done: post-barrier)
    short* Ot = smem + wv * (32 * 72);
#pragma unroll
    for (int ht = 0; ht < 4; ++ht)
#pragma unroll
        for (int nt = 0; nt < 2; ++nt) {
            const float iv = nt ? inv1 : inv0;
            const s16x4 ov = {f2bf(o[ht][nt][0] * iv), f2bf(o[ht][nt][1] * iv),
                              f2bf(o[ht][nt][2] * iv), f2bf(o[ht][nt][3] * iv)};
            *(s16x4*)&Ot[(nt * 16 + lrow) * 72 + ht * 16 + q4] = ov;
        }
    const int erow = lane >> 1, ec = (lane & 1) * 32;
    const short8 r0 = *(const short8*)&Ot[erow * 72 + ec + 0];
    const short8 r1 = *(const short8*)&Ot[erow * 72 + ec + 8];
    const short8 r2 = *(const short8*)&Ot[erow * 72 + ec + 16];
    const short8 r3 = *(const short8*)&Ot[erow * 72 + ec + 24];
    short* dst = aO + ((size_t)b * SEQ_L + qt * 128 + wv * 32 + erow) * DM + h * HD + ec;
    *(short8*)(dst + 0)  = r0;
    *(short8*)(dst + 8)  = r1;
    *(short8*)(dst + 16) = r2;
    *(short8*)(dst + 24) = r3;
}

// ---------------------------------------------------------------------------
// Launch
// ---------------------------------------------------------------------------
extern "C" void kernel_launch(void* const* d_in, const int* in_sizes, int n_in,
                              void* d_out, int out_size, void* d_ws, size_t ws_size,
                              hipStream_t stream) {
    const float* x   = (const float*)d_in[0];
    const float* wq  = (const float*)d_in[1];
    const float* bq  = (const float*)d_in[2];
    const float* wk  = (const float*)d_in[3];
    const float* bk  = (const float*)d_in[4];
    const float* wv  = (const float*)d_in[5];
    const float* bv  = (const float*)d_in[6];
    const float* wo  = (const float*)d_in[7];
    const float* bo  = (const float*)d_in[8];
    const float* g1  = (const float*)d_in[9];
    const float* b1  = (const float*)d_in[10];
    const float* g2  = (const float*)d_in[11];
    const float* b2  = (const float*)d_in[12];
    const float* w1  = (const float*)d_in[13];
    const float* bf1 = (const float*)d_in[14];
    const float* w2  = (const float*)d_in[15];
    const float* bf2 = (const float*)d_in[16];
    float* out = (float*)d_out;

    // ws layout (MiB, all offsets within the previously-validated 80.25 MiB):
    // [0,24)    wbf bf16 weights (wq..wo [0,8), w1 [8,16), w2 [16,24))
    // [24,48)   qkvB bf16 [BL][3072]; later hbuf bf16 [BL][4096] = [24,56)
    // [24,40)   P  fp32 out-proj partial 0 (over dead qkvB)
    // [40,56)   P2 fp32 out-proj partial 1 (dead qkvB tail + dead Qb)
    // [48,56)   xnb/Qb (dead after attn)
    // [56,64)   Kb (dead after attn)     [64,72) Vtb/xn2b (dead after FFN1)
    // [72,72.25) k2   [72.25,80.25) aO (dead after out-proj)
    // [0,16)    y0 fp32 FFN2 partial 0 (over dead wq..wo,w1; w2 [16,24) live)
    // [56,72)   y1 fp32 FFN2 partial 1 (over dead Kb,Vtb)
    char* base = (char*)d_ws;
    short* wbf  = (short*)base;
    short* qkvB = (short*)(base + (24u << 20));
    short* xnb  = (short*)(base + (48u << 20));
    short* Qb   = xnb;
    short* Kb   = (short*)(base + (56u << 20));
    short* Vtb  = (short*)(base + (64u << 20));
    float* k2   = (float*)(base + (72u << 20));
    short* aO   = (short*)(base + (72u << 20) + (256u << 10));
    float* P    = (float*)(base + (24u << 20));
    float* P2   = (float*)(base + (40u << 20));
    short* xn2b = Vtb;
    short* hbuf = qkvB;
    float* y0   = (float*)base;                     // FFN2 partial 0
    float* y1   = (float*)(base + (56u << 20));     // FFN2 partial 1

    // 0. weights -> bf16
    cvt6_kernel<<<12288, 256, 0, stream>>>(wq, wk, wv, wo, w1, w2, wbf);
    // 1. LN1 -> bf16
    ln_bf16_kernel<<<BL, 256, 0, stream>>>(x, g1, b1, xnb);
    // 2. fused QKV projection -> bf16 [BL][3072]
    gemm_mfma<128, 0, 1, 1, 1><<<dim3(24, 32), 256, 0, stream>>>(
        xnb, wbf, bq, bk, bv, qkvB, nullptr, BL, QKV_S, DM);
    // 3. prep: project q,k -> Qb/Kb [bh][L][64] + k2; transpose v -> Vtb
    qk_prep<<<16384, 256, 0, stream>>>(qkvB, Qb, Kb, k2);
    v_prep<<<1024, 256, 0, stream>>>(qkvB, Vtb);
    // 4. flash MFMA attention -> aO bf16
    attn_mfma2<<<dim3(16, 16, 2), 256, 0, stream>>>(Qb, Kb, Vtb, k2, aO);
    // 5. output projection, BM=128 split-K=2 -> P,P2 fp32 partials
    gemm_mfma<128, 0, 0, 0, 2><<<dim3(8, 32, 2), 256, 0, stream>>>(
        aO, wbf + 3145728, bo, bo, bo, P, P2, BL, DM, DM);
    // 6+7. x1 = project(x + P + P2) -> d_out, fused with LN2 -> xn2b
    resproj2_ln_kernel<<<BL, 256, 0, stream>>>(x, P, P2, g2, b2, out, xn2b);
    // 8. FFN1 + GELU -> bf16 hidden
    gemm_mfma<128, 1, 1, 0, 1><<<dim3(32, 32), 256, 0, stream>>>(
        xn2b, wbf + 4194304, bf1, bf1, bf1, hbuf, nullptr, BL, DFF, DM);
    // 9. FFN2, BM=128 split-K=2 -> y0,y1 fp32 partials
    gemm_mfma<128, 0, 0, 0, 2><<<dim3(8, 32, 2), 256, 0, stream>>>(
        hbuf, wbf + 8388608, bf2, bf2, bf2, y0, y1, BL, DM, DFF);
    // 10. out = project(x1 + y0 + y1)
    resproj2_kernel<<<BL, 256, 0, stream>>>(out, y0, y1, out);
}

// Round 9
// 370.948 us; speedup vs baseline: 1.2666x; 1.0062x over previous
//
#include <hip/hip_runtime.h>
#include <math.h>

// Problem constants: B=2, L=2048, D=1024, H=16, hd=64, Dff=4096
#define SEQ_L 2048
#define DM    1024
#define NH    16
#define HD    64
#define BL    4096          // B*L
#define DFF   4096
#define QKV_S 3072          // fused qkv row stride

typedef __attribute__((ext_vector_type(8))) short short8;   // 8 bf16 (4 VGPRs)
typedef __attribute__((ext_vector_type(4))) short s16x4;    // 4 bf16
typedef __attribute__((ext_vector_type(4))) float f32x4;    // MFMA C/D frag
typedef __attribute__((ext_vector_type(4))) int   i32x4;    // 4 packed bf16x2

// 0.25*log2(e), 0.125*log2(e) — fold exp->exp2 base change into the scales
#define C_QK  0.36067376022224085f
#define C_K2  0.18033688011112042f

#if __has_builtin(__builtin_amdgcn_exp2f)
#define EXP2(x) __builtin_amdgcn_exp2f(x)
#else
#define EXP2(x) exp2f(x)
#endif

// fp32 -> bf16 round-to-nearest-even
__device__ __forceinline__ short f2bf(float x) {
    unsigned u = __float_as_uint(x);
    u += 0x7fff + ((u >> 16) & 1);
    return (short)(u >> 16);
}
__device__ __forceinline__ float bf2f(short s) {
    return __uint_as_float(((unsigned)(unsigned short)s) << 16);
}
// pack two f32 -> one u32 of 2x bf16 (RNE); no builtin on gfx950 (m240)
__device__ __forceinline__ int cvt_pk_bf16(float lo, float hi) {
    int r;
    asm("v_cvt_pk_bf16_f32 %0, %1, %2" : "=v"(r) : "v"(lo), "v"(hi));
    return r;
}
// async global->LDS, 16 B per lane; LDS dest is wave-uniform base + lane*16
__device__ __forceinline__ void async_copy16(const short* gsrc, short* ldst) {
    __builtin_amdgcn_global_load_lds(
        (const __attribute__((address_space(1))) unsigned int*)gsrc,
        (__attribute__((address_space(3))) unsigned int*)ldst, 16, 0, 0);
}

// branch-free GELU (erf form) via A&S 7.1.26, |abs err| <= ~2e-7.
__device__ __forceinline__ float gelu_fast(float x) {
    const float xa = fabsf(x);
    const float z = xa * 0.70710678118654752440f;
    const float t = __builtin_amdgcn_rcpf(fmaf(0.3275911f, z, 1.f));
    float P = fmaf(t, 1.061405429f, -1.453152027f);
    P = fmaf(t, P, 1.421413741f);
    P = fmaf(t, P, -0.284496736f);
    P = fmaf(t, P, 0.254829592f);
    P *= t;
    const float e = __expf(-z * z);
    const float erfp = fmaf(-P, e, 1.f);   // erf(|x|/sqrt2)
    return 0.5f * fmaf(xa, erfp, x);
}

__device__ __forceinline__ float block_sum(float v, float* red, int tid) {
#pragma unroll
    for (int m = 32; m; m >>= 1) v += __shfl_xor(v, m);
    if ((tid & 63) == 0) red[tid >> 6] = v;
    __syncthreads();
    v = red[0] + red[1] + red[2] + red[3];
    __syncthreads();
    return v;
}

// ---------------------------------------------------------------------------
// Weight fp32 -> bf16: wq|wk|wv|wo|w1|w2 contiguous (fused QKV needs this).
// ---------------------------------------------------------------------------
__global__ __launch_bounds__(256) void cvt6_kernel(
    const float* __restrict__ wq, const float* __restrict__ wk,
    const float* __restrict__ wv, const float* __restrict__ wo,
    const float* __restrict__ w1, const float* __restrict__ w2,
    short* __restrict__ dst) {
    const size_t i = (size_t)blockIdx.x * 256 + threadIdx.x;  // float4 index
    const float* src;
    size_t off;
    if (i < 1048576) {
        const int seg = (int)(i >> 18);
        off = i & 262143;
        src = seg == 0 ? wq : seg == 1 ? wk : seg == 2 ? wv : wo;
    } else if (i < 2097152) { src = w1; off = i - 1048576; }
    else                    { src = w2; off = i - 2097152; }
    const float4 v = ((const float4*)src)[off];
    const s16x4 o = {f2bf(v.x), f2bf(v.y), f2bf(v.z), f2bf(v.w)};
    ((s16x4*)dst)[i] = o;
}

// ---------------------------------------------------------------------------
// LayerNorm over rows of 1024, bf16 output.
// ---------------------------------------------------------------------------
__global__ __launch_bounds__(256) void ln_bf16_kernel(const float* __restrict__ x,
                                                      const float* __restrict__ g,
                                                      const float* __restrict__ b,
                                                      short* __restrict__ out) {
    const int row = blockIdx.x;
    const int tid = threadIdx.x;
    __shared__ float red[4];
    const float4 xv = *(const float4*)(x + (size_t)row * DM + tid * 4);
    float s = xv.x + xv.y + xv.z + xv.w;
    s = block_sum(s, red, tid);
    const float mean = s * (1.f / (float)DM);
    float dx0 = xv.x - mean, dx1 = xv.y - mean, dx2 = xv.z - mean, dx3 = xv.w - mean;
    float ss = dx0 * dx0 + dx1 * dx1 + dx2 * dx2 + dx3 * dx3;
    ss = block_sum(ss, red, tid);
    const float rs = 1.f / sqrtf(ss * (1.f / (float)DM) + 1e-5f);
    const float4 gv = *(const float4*)(g + tid * 4);
    const float4 bv = *(const float4*)(b + tid * 4);
    const s16x4 ob = {f2bf(dx0 * rs * gv.x + bv.x), f2bf(dx1 * rs * gv.y + bv.y),
                      f2bf(dx2 * rs * gv.z + bv.z), f2bf(dx3 * rs * gv.w + bv.w)};
    *(s16x4*)(out + (size_t)row * DM + tid * 4) = ob;
}

// ---------------------------------------------------------------------------
// Residual + TWO split-K partials + Poincare projection (fp32, in-place safe).
// ---------------------------------------------------------------------------
__global__ __launch_bounds__(256) void resproj2_kernel(const float* __restrict__ a,
                                                       const float* __restrict__ c0,
                                                       const float* __restrict__ c1,
                                                       float* __restrict__ out) {
    const int row = blockIdx.x;
    const int tid = threadIdx.x;
    __shared__ float red[4];
    const float4 av = *(const float4*)(a + (size_t)row * DM + tid * 4);
    const float4 cv = *(const float4*)(c0 + (size_t)row * DM + tid * 4);
    const float4 dv = *(const float4*)(c1 + (size_t)row * DM + tid * 4);
    float4 sv;
    sv.x = av.x + cv.x + dv.x; sv.y = av.y + cv.y + dv.y;
    sv.z = av.z + cv.z + dv.z; sv.w = av.w + cv.w + dv.w;
    float ss = sv.x * sv.x + sv.y * sv.y + sv.z * sv.z + sv.w * sv.w;
    ss = block_sum(ss, red, tid);
    const float n = sqrtf(ss);
    const float mx = 1.f - 1e-5f;
    const float scale = (n > mx) ? (mx / fmaxf(n, 1e-12f)) : 1.f;
    sv.x *= scale; sv.y *= scale; sv.z *= scale; sv.w *= scale;
    *(float4*)(out + (size_t)row * DM + tid * 4) = sv;
}

// ---------------------------------------------------------------------------
// FUSED: residual + two split-K partials + Poincare projection + LayerNorm.
// ---------------------------------------------------------------------------
__global__ __launch_bounds__(256) void resproj2_ln_kernel(
    const float* __restrict__ a, const float* __restrict__ c0,
    const float* __restrict__ c1, const float* __restrict__ g,
    const float* __restrict__ b, float* __restrict__ out,
    short* __restrict__ obf) {
    const int row = blockIdx.x;
    const int tid = threadIdx.x;
    __shared__ float red[4];
    const float4 av = *(const float4*)(a + (size_t)row * DM + tid * 4);
    const float4 cv = *(const float4*)(c0 + (size_t)row * DM + tid * 4);
    const float4 dv = *(const float4*)(c1 + (size_t)row * DM + tid * 4);
    float4 sv;
    sv.x = av.x + cv.x + dv.x; sv.y = av.y + cv.y + dv.y;
    sv.z = av.z + cv.z + dv.z; sv.w = av.w + cv.w + dv.w;
    float ss = sv.x * sv.x + sv.y * sv.y + sv.z * sv.z + sv.w * sv.w;
    ss = block_sum(ss, red, tid);
    const float n = sqrtf(ss);
    const float mx = 1.f - 1e-5f;
    const float scale = (n > mx) ? (mx / fmaxf(n, 1e-12f)) : 1.f;
    sv.x *= scale; sv.y *= scale; sv.z *= scale; sv.w *= scale;
    *(float4*)(out + (size_t)row * DM + tid * 4) = sv;
    // LayerNorm on the projected row (values already in registers)
    float s = sv.x + sv.y + sv.z + sv.w;
    s = block_sum(s, red, tid);
    const float mean = s * (1.f / (float)DM);
    const float dx0 = sv.x - mean, dx1 = sv.y - mean,
                dx2 = sv.z - mean, dx3 = sv.w - mean;
    float s2 = dx0 * dx0 + dx1 * dx1 + dx2 * dx2 + dx3 * dx3;
    s2 = block_sum(s2, red, tid);
    const float rs = 1.f / sqrtf(s2 * (1.f / (float)DM) + 1e-5f);
    const float4 gv = *(const float4*)(g + tid * 4);
    const float4 bv = *(const float4*)(b + tid * 4);
    const s16x4 ob = {f2bf(dx0 * rs * gv.x + bv.x), f2bf(dx1 * rs * gv.y + bv.y),
                      f2bf(dx2 * rs * gv.z + bv.z), f2bf(dx3 * rs * gv.w + bv.w)};
    *(s16x4*)(obf + (size_t)row * DM + tid * 4) = ob;
}

// ---------------------------------------------------------------------------
// q/k prep: per-head Poincare projection + attention-layout bf16 buffers.
// k2 prescaled by 0.125*log2(e) so attention can use exp2 directly.
// ---------------------------------------------------------------------------
__global__ __launch_bounds__(256) void qk_prep(const short* __restrict__ qkvB,
                                               short* __restrict__ Qb,
                                               short* __restrict__ Kb,
                                               float* __restrict__ k2) {
    const int tid = threadIdx.x, lane = tid & 63;
    const int vec = blockIdx.x * 4 + (tid >> 6);
    const int row = vec >> 4, h = vec & 15;
    const int b = row >> 11, l = row & 2047;
    const size_t dstv = ((size_t)(b * NH + h) * SEQ_L + l) * HD + lane;
    const float mx = 1.f - 1e-5f;
    {   // q
        const float v = bf2f(qkvB[(size_t)row * QKV_S + h * HD + lane]);
        float s = v * v;
#pragma unroll
        for (int m = 32; m; m >>= 1) s += __shfl_xor(s, m);
        const float n = sqrtf(s);
        const float sc = (n > mx) ? (mx / fmaxf(n, 1e-12f)) : 1.f;
        Qb[dstv] = f2bf(v * sc);
    }
    {   // k (+ prescaled squared norm, in log2 units)
        const float v = bf2f(qkvB[(size_t)row * QKV_S + DM + h * HD + lane]);
        float s = v * v;
#pragma unroll
        for (int m = 32; m; m >>= 1) s += __shfl_xor(s, m);
        const float n = sqrtf(s);
        const float sc = (n > mx) ? (mx / fmaxf(n, 1e-12f)) : 1.f;
        Kb[dstv] = f2bf(v * sc);
        if (lane == 0) k2[(size_t)(b * NH + h) * SEQ_L + l] = s * sc * sc * C_K2;
    }
}

// ---------------------------------------------------------------------------
// v prep: transpose to Vtb [b][h][64 hd][L] bf16, with the columns of each
// 32-wide k-block interleaved as [g0 lo4 | g0 hi4 | g1 lo4 | g1 hi4 | ...]
// so the attention PV A-fragment is ONE contiguous aligned 16B load.
// ---------------------------------------------------------------------------
__global__ __launch_bounds__(256) void v_prep(const short* __restrict__ qkvB,
                                              short* __restrict__ Vtb) {
    const int blk = blockIdx.x;
    const int bh = blk >> 5, kt = blk & 31;
    const int b = bh >> 4, h = bh & 15;
    __shared__ short T[64 * 72];
    const int tid = threadIdx.x;
    {
        const int key = tid >> 2, ch = (tid & 3) * 16;
        const size_t src = ((size_t)b * SEQ_L + kt * 64 + key) * QKV_S + 2 * DM + h * HD + ch;
        *(short8*)&T[key * 72 + ch]     = *(const short8*)(qkvB + src);
        *(short8*)&T[key * 72 + ch + 8] = *(const short8*)(qkvB + src + 8);
    }
    __syncthreads();
    const int hd = tid >> 2, kc = (tid & 3) * 16;
    short8 o0, o1;
#pragma unroll
    for (int j = 0; j < 8; ++j) {
        o0[j] = T[(kc + j) * 72 + hd];
        o1[j] = T[(kc + 8 + j) * 72 + hd];
    }
    const int c32 = (kc >> 5) * 32;          // which 32-block (0 or 32)
    const int h4  = ((kc >> 4) & 1) * 4;     // low/high half of the block
    short* dst = Vtb + ((size_t)bh * HD + hd) * SEQ_L + kt * 64 + c32 + h4;
    const s16x4 w0 = {o0[0], o0[1], o0[2], o0[3]};
    const s16x4 w1 = {o0[4], o0[5], o0[6], o0[7]};
    const s16x4 w2 = {o1[0], o1[1], o1[2], o1[3]};
    const s16x4 w3 = {o1[4], o1[5], o1[6], o1[7]};
    *(s16x4*)(dst)      = w0;
    *(s16x4*)(dst + 8)  = w1;
    *(s16x4*)(dst + 16) = w2;
    *(s16x4*)(dst + 24) = w3;
}

// ---------------------------------------------------------------------------
// bf16 MFMA NT GEMM, round 9: COUNTED-vmcnt depth-2 pipeline (catalog T4).
// r8's single-barrier loop was depth-1 with an implicit vmcnt(0) drain at
// every __syncthreads: the stage issued at iter t was fully waited at the
// barrier of t+1, leaving only ~1 compute phase to cover L2/HBM latency
// (gain was just 5.5us). Now, per BK=32 step (3 LDS buffers):
//   s_waitcnt vmcnt(4)   <- waits ONLY stage(t)'s 4 gload_lds; stage(t+1)'s
//                           4 stay in flight (never drain to 0 in-loop)
//   s_barrier            <- per-wave vmcnt + barrier = all waves' stage(t)
//                           landed in LDS (m201 discipline)
//   issue stage(t+2) -> buf[(t+2)%3]
//   ds_read frags from buf[t%3] -> 16 MFMA
// Each stage has ~2 compute phases (~300-400 cyc) in flight before its wait.
// Race audit: buf[(t+2)%3]'s last readers ran at iter t-1 and their ds_reads
// completed before their MFMAs issued (compiler lgkm waits) -> done before
// they reached barrier t -> overwrite safe. Tail peeled with vmcnt(0).
// sched_barrier(0) pins ordering around the asm waits (rule #18).
// LDS 3x16KB = 48 KB -> 3 blocks/CU. Swizzled gload_lds source + XOR read
// (b128 uniform-bank floor), XCD block swizzle, split-K=2 retained.
// ---------------------------------------------------------------------------
template <int BM, int ACT, int OUTBF, int FUSED, int SPLITK>
__global__ __launch_bounds__(256) void gemm_mfma(
    const short* __restrict__ A, const short* __restrict__ Bw,
    const float* __restrict__ bb0, const float* __restrict__ bb1,
    const float* __restrict__ bb2, void* __restrict__ Cout,
    void* __restrict__ Cout2,
    int M, int N, int K) {
    static_assert(BM == 128, "staging assumes BM=128");
    constexpr int RT = BM / 32;
    constexpr bool VEPI = (OUTBF != 0) && (BM == 128);
    constexpr int BUFSH = 2 * 128 * 32;     // A+B per buffer (8192 shorts)
    constexpr int RAWS = 3 * BUFSH;         // 24576 shorts = 48 KB
    static_assert(RAWS >= 4 * 64 * 72, "VEPI Ot fits in staging buffers");
    __shared__ __align__(16) short raw[RAWS];
    const int tid = threadIdx.x;
    const int wv = tid >> 6, lane = tid & 63;

    // XCD-aware bijective swizzle (grid size % 8 == 0 for all launches)
    const int gx = gridDim.x, gy = gridDim.y;
    const int nwg = gx * gy * gridDim.z;
    int d = blockIdx.x + gx * (blockIdx.y + gy * blockIdx.z);
    d = (d & 7) * (nwg >> 3) + (d >> 3);
    const int bx = d % gx;
    const int byz = d / gx;
    const int by = byz % gy;
    const int bz = byz / gy;

    const int m0 = by * BM, n0 = bx * 128;
    const int wr = (wv & 1) * (BM / 2);
    const int wc = (wv >> 1) * 64;

    const int z = (SPLITK > 1) ? bz : 0;
    const int Kc = K / SPLITK;              // this block's K-chunk length

    // staging: wave wv covers A rows [wv*32, wv*32+32) and B rows same,
    // 2 issues each (16 rows x 32 shorts = 1 KB per issue) -> 4/wave/stage.
    const int srl = lane >> 2;                       // row within 16-row issue
    const int scol = ((lane & 3) ^ ((lane >> 3) & 3)) * 8;  // swizzled src col
    const short* Ag = A + (size_t)(m0 + wv * 32 + srl) * K + z * Kc + scol;
    const short* Bg = Bw + (size_t)(n0 + wv * 32 + srl) * K + z * Kc + scol;
    short* ldsA = raw + (wv * 32) * 32;              // + buf*BUFSH ; +j*16*32
    short* ldsB = raw + 128 * 32 + (wv * 32) * 32;

    const f32x4 z4 = {0.f, 0.f, 0.f, 0.f};
    f32x4 acc[RT][4];
#pragma unroll
    for (int r = 0; r < RT; ++r)
#pragma unroll
        for (int c = 0; c < 4; ++c) acc[r][c] = z4;

    const int lrow = lane & 15;
    const int rdoff = ((lane >> 4) ^ ((lrow >> 1) & 3)) * 8;  // phys slot (shorts)

    // stage: issue 4 async copies (A j0, B j0, A j1, B j1) for K-offset kto
    auto stage = [&](int kto, int buf) {
        const int nb = buf * BUFSH;
#pragma unroll
        for (int j = 0; j < 2; ++j) {
            async_copy16(Ag + (size_t)(16 * j) * K + kto, ldsA + nb + (16 * j) * 32);
            async_copy16(Bg + (size_t)(16 * j) * K + kto, ldsB + nb + (16 * j) * 32);
        }
    };
    // compute: 8 ds_read_b128 + 16 MFMA on buffer buf
    auto compute = [&](int buf) {
        const short* As = raw + buf * BUFSH;
        const short* Bs = As + 128 * 32;
        short8 af[RT], bf[4];
#pragma unroll
        for (int r = 0; r < RT; ++r)
            af[r] = *(const short8*)&As[(wr + r * 16 + lrow) * 32 + rdoff];
#pragma unroll
        for (int c = 0; c < 4; ++c)
            bf[c] = *(const short8*)&Bs[(wc + c * 16 + lrow) * 32 + rdoff];
#pragma unroll
        for (int r = 0; r < RT; ++r)
#pragma unroll
            for (int c = 0; c < 4; ++c)
                acc[r][c] = __builtin_amdgcn_mfma_f32_16x16x32_bf16(af[r], bf[c], acc[r][c], 0, 0, 0);
    };

    // prologue: stages 0 and 1 (Kc >= 512 always, so both exist)
    stage(0, 0);
    stage(32, 1);

    int cur = 0;
    int kt = 0;
    for (; kt + 32 < Kc; kt += 32) {
        asm volatile("s_waitcnt vmcnt(4)" ::: "memory");   // stage(t) landed
        __builtin_amdgcn_sched_barrier(0);
        __builtin_amdgcn_s_barrier();                      // ...for ALL waves
        __builtin_amdgcn_sched_barrier(0);
        if (kt + 64 < Kc) {
            int nb = cur + 2; if (nb >= 3) nb -= 3;
            stage(kt + 64, nb);                            // depth-2 prefetch
        }
        compute(cur);
        cur = (cur == 2) ? 0 : cur + 1;
    }
    asm volatile("s_waitcnt vmcnt(0)" ::: "memory");       // last stage landed
    __builtin_amdgcn_sched_barrier(0);
    __builtin_amdgcn_s_barrier();
    __builtin_amdgcn_sched_barrier(0);
    compute(cur);

    void* Cbase = Cout;
    if constexpr (SPLITK > 1) { if (z) Cbase = Cout2; }

    const int col = lane & 15, rb4 = (lane >> 4) * 4;
    if constexpr (VEPI) {
        __syncthreads();   // staging dead; reuse raw as per-wave transpose buffers
        short* Ot = raw + wv * (64 * 72);
#pragma unroll
        for (int c = 0; c < 4; ++c) {
            const int gn = n0 + wc + c * 16 + col;
            float bias;
            if constexpr (FUSED) {
                const int seg = gn >> 10;
                bias = (seg == 0 ? bb0 : seg == 1 ? bb1 : bb2)[gn & 1023];
            } else {
                bias = bb0[gn];
            }
#pragma unroll
            for (int r = 0; r < RT; ++r)
#pragma unroll
                for (int i = 0; i < 4; ++i) {
                    float v = acc[r][c][i] + bias;
                    if constexpr (ACT) v = gelu_fast(v);
                    Ot[(r * 16 + rb4 + i) * 72 + c * 16 + col] = f2bf(v);
                }
        }
        const int orow = lane >> 3, oc = (lane & 7) * 8;
#pragma unroll
        for (int it = 0; it < 8; ++it) {
            const short8 vv = *(const short8*)&Ot[(it * 8 + orow) * 72 + oc];
            *(short8*)((short*)Cbase + (size_t)(m0 + wr + it * 8 + orow) * N + n0 + wc + oc) = vv;
        }
    } else {
#pragma unroll
        for (int c = 0; c < 4; ++c) {
            const int gn = n0 + wc + c * 16 + col;
            float bias;
            if constexpr (FUSED) {
                const int seg = gn >> 10;
                bias = (seg == 0 ? bb0 : seg == 1 ? bb1 : bb2)[gn & 1023];
            } else {
                bias = bb0[gn];
            }
            if constexpr (SPLITK > 1) { if (z) bias = 0.f; }  // bias only in partial 0
#pragma unroll
            for (int r = 0; r < RT; ++r) {
                const int gm = m0 + wr + r * 16 + rb4;
#pragma unroll
                for (int i = 0; i < 4; ++i) {
                    float v = acc[r][c][i] + bias;
                    if constexpr (ACT) v = gelu_fast(v);
                    if constexpr (OUTBF)
                        ((short*)Cbase)[(size_t)(gm + i) * N + gn] = f2bf(v);
                    else
                        ((float*)Cbase)[(size_t)(gm + i) * N + gn] = v;
                }
            }
        }
    }
}

// ---------------------------------------------------------------------------
// MFMA flash attention: single-barrier LDS double buffer + XCD swizzle.
// Round 9: T5 setprio(1) around the PV MFMA cluster (m191: +4-7% on
// phase-split attn). FETCH 12.5 MB (L2-resident); VALU-limited.
// ---------------------------------------------------------------------------
__global__ __launch_bounds__(256) void attn_mfma2(const short* __restrict__ Qb,
                                                  const short* __restrict__ Kb,
                                                  const short* __restrict__ Vtb,
                                                  const float* __restrict__ k2v,
                                                  short* __restrict__ aO) {
    int d = blockIdx.x + 16 * (blockIdx.y + 16 * blockIdx.z);
    d = (d & 7) * 64 + (d >> 3);            // 512 blocks, bijective
    const int qt = d & 15, h = (d >> 4) & 15, b = d >> 8;
    const int tid = threadIdx.x, wv = tid >> 6, lane = tid & 63;
    const int bh = b * NH + h;
    constexpr int NT = SEQ_L / 64;
    constexpr int BUFS = 64 * 72;    // shorts per K (or V) tile buffer
    __shared__ __align__(16) short smem[4 * BUFS];  // {K,V} x double buffer; Ot reuse
    __shared__ __align__(16) float k2s[SEQ_L];
    const int lrow = lane & 15, q8 = (lane >> 4) * 8, q4 = (lane >> 4) * 4;

    const short* Qh = Qb + (size_t)bh * SEQ_L * HD;
    const short* Kh = Kb + (size_t)bh * SEQ_L * HD;
    const short* Vh = Vtb + (size_t)bh * HD * SEQ_L;
    const float* k2p = k2v + (size_t)bh * SEQ_L;

    short8 qf[2][2];
#pragma unroll
    for (int nt = 0; nt < 2; ++nt)
#pragma unroll
        for (int kc = 0; kc < 2; ++kc)
            qf[nt][kc] = *(const short8*)(Qh +
                (size_t)(qt * 128 + wv * 32 + nt * 16 + lrow) * HD + kc * 32 + q8);

    // k2 -> LDS (2048 floats, 8 per thread)
    {
        const float4 a0 = *(const float4*)(k2p + tid * 4);
        const float4 a1 = *(const float4*)(k2p + 1024 + tid * 4);
        *(float4*)&k2s[tid * 4] = a0;
        *(float4*)&k2s[1024 + tid * 4] = a1;
    }

    const int srow = tid >> 2, sch = (tid & 3) * 16;
    const short* gK = Kh + (size_t)srow * HD + sch;      // + (k0)*HD per tile
    const short* gV = Vh + (size_t)srow * SEQ_L + sch;   // + k0 per tile
    const int woff = srow * 72 + sch;

    // prologue: stage tile 0 into buf 0
    {
        const short8 k0a = *(const short8*)(gK);
        const short8 k0b = *(const short8*)(gK + 8);
        const short8 v0a = *(const short8*)(gV);
        const short8 v0b = *(const short8*)(gV + 8);
        *(short8*)&smem[woff]            = k0a;
        *(short8*)&smem[woff + 8]        = k0b;
        *(short8*)&smem[BUFS + woff]     = v0a;
        *(short8*)&smem[BUFS + woff + 8] = v0b;
    }
    __syncthreads();

    const f32x4 z4 = {0.f, 0.f, 0.f, 0.f};
    f32x4 o[4][2];   // O^T accum: [ht(hd)][nt(qrow)]
#pragma unroll
    for (int ht = 0; ht < 4; ++ht)
#pragma unroll
        for (int nt = 0; nt < 2; ++nt) o[ht][nt] = z4;
    float lsum[2] = {0.f, 0.f};

    for (int kt = 0; kt < NT; ++kt) {
        const int k0 = kt * 64;
        const short* Ks = smem + (kt & 1) * (2 * BUFS);
        const short* Vt = Ks + BUFS;
        // issue next tile's loads FIRST (latency hides under this tile's math)
        short8 nk0, nk1, nv0, nv1;
        const bool more = (kt + 1 < NT);
        if (more) {
            const short* g = gK + (size_t)(k0 + 64) * HD;
            nk0 = *(const short8*)(g);
            nk1 = *(const short8*)(g + 8);
            const short* gv2 = gV + (k0 + 64);
            nv0 = *(const short8*)(gv2);
            nv1 = *(const short8*)(gv2 + 8);
        }

        i32x4 pw[2][2];   // [nt][c] packed bf16 P fragments (short8 each)
#pragma unroll
        for (int mt = 0; mt < 4; ++mt) {
            const short8 kf0 = *(const short8*)&Ks[(mt * 16 + lrow) * 72 + q8];
            const short8 kf1 = *(const short8*)&Ks[(mt * 16 + lrow) * 72 + 32 + q8];
            const float4 kk = *(const float4*)&k2s[k0 + mt * 16 + q4];
            const int c = mt >> 1, wb = (mt & 1) * 2;
#pragma unroll
            for (int nt = 0; nt < 2; ++nt) {
                f32x4 s = z4;
                s = __builtin_amdgcn_mfma_f32_16x16x32_bf16(kf0, qf[nt][0], s, 0, 0, 0);
                s = __builtin_amdgcn_mfma_f32_16x16x32_bf16(kf1, qf[nt][1], s, 0, 0, 0);
                const float p0 = EXP2(fmaf(s[0], C_QK, -kk.x));
                const float p1 = EXP2(fmaf(s[1], C_QK, -kk.y));
                const float p2 = EXP2(fmaf(s[2], C_QK, -kk.z));
                const float p3 = EXP2(fmaf(s[3], C_QK, -kk.w));
                lsum[nt] += (p0 + p1) + (p2 + p3);
                pw[nt][c][wb]     = cvt_pk_bf16(p0, p1);
                pw[nt][c][wb + 1] = cvt_pk_bf16(p2, p3);
            }
        }
        __builtin_amdgcn_s_setprio(1);      // favor the PV MFMA cluster (T5)
#pragma unroll
        for (int ht = 0; ht < 4; ++ht) {
#pragma unroll
            for (int c = 0; c < 2; ++c) {
                const short8 v8 = *(const short8*)&Vt[(ht * 16 + lrow) * 72 + c * 32 + q4 * 2];
#pragma unroll
                for (int nt = 0; nt < 2; ++nt)
                    o[ht][nt] = __builtin_amdgcn_mfma_f32_16x16x32_bf16(
                        v8, __builtin_bit_cast(short8, pw[nt][c]), o[ht][nt], 0, 0, 0);
            }
        }
        __builtin_amdgcn_s_setprio(0);

        if (more) {   // vmcnt wait lands here, AFTER the compute above
            short* Kd = smem + ((kt + 1) & 1) * (2 * BUFS);
            *(short8*)&Kd[woff]            = nk0;
            *(short8*)&Kd[woff + 8]        = nk1;
            *(short8*)&Kd[BUFS + woff]     = nv0;
            *(short8*)&Kd[BUFS + woff + 8] = nv1;
        }
        __syncthreads();                    // single barrier per tile
    }

#pragma unroll
    for (int nt = 0; nt < 2; ++nt) {
        lsum[nt] += __shfl_xor(lsum[nt], 16);
        lsum[nt] += __shfl_xor(lsum[nt], 32);
    }
    const float inv0 = 1.f / lsum[0], inv1 = 1.f / lsum[1];

    // wave-private Ot transpose buffers (all loop reads done: post-barrier)
    short* Ot = smem + wv * (32 * 72);
#pragma unroll
    for (int ht = 0; ht < 4; ++ht)
#pragma unroll
        for (int nt = 0; nt < 2; ++nt) {
            const float iv = nt ? inv1 : inv0;
            const s16x4 ov = {f2bf(o[ht][nt][0] * iv), f2bf(o[ht][nt][1] * iv),
                              f2bf(o[ht][nt][2] * iv), f2bf(o[ht][nt][3] * iv)};
            *(s16x4*)&Ot[(nt * 16 + lrow) * 72 + ht * 16 + q4] = ov;
        }
    const int erow = lane >> 1, ec = (lane & 1) * 32;
    const short8 r0 = *(const short8*)&Ot[erow * 72 + ec + 0];
    const short8 r1 = *(const short8*)&Ot[erow * 72 + ec + 8];
    const short8 r2 = *(const short8*)&Ot[erow * 72 + ec + 16];
    const short8 r3 = *(const short8*)&Ot[erow * 72 + ec + 24];
    short* dst = aO + ((size_t)b * SEQ_L + qt * 128 + wv * 32 + erow) * DM + h * HD + ec;
    *(short8*)(dst + 0)  = r0;
    *(short8*)(dst + 8)  = r1;
    *(short8*)(dst + 16) = r2;
    *(short8*)(dst + 24) = r3;
}

// ---------------------------------------------------------------------------
// Launch
// ---------------------------------------------------------------------------
extern "C" void kernel_launch(void* const* d_in, const int* in_sizes, int n_in,
                              void* d_out, int out_size, void* d_ws, size_t ws_size,
                              hipStream_t stream) {
    const float* x   = (const float*)d_in[0];
    const float* wq  = (const float*)d_in[1];
    const float* bq  = (const float*)d_in[2];
    const float* wk  = (const float*)d_in[3];
    const float* bk  = (const float*)d_in[4];
    const float* wv  = (const float*)d_in[5];
    const float* bv  = (const float*)d_in[6];
    const float* wo  = (const float*)d_in[7];
    const float* bo  = (const float*)d_in[8];
    const float* g1  = (const float*)d_in[9];
    const float* b1  = (const float*)d_in[10];
    const float* g2  = (const float*)d_in[11];
    const float* b2  = (const float*)d_in[12];
    const float* w1  = (const float*)d_in[13];
    const float* bf1 = (const float*)d_in[14];
    const float* w2  = (const float*)d_in[15];
    const float* bf2 = (const float*)d_in[16];
    float* out = (float*)d_out;

    // ws layout (MiB, all offsets within the previously-validated 80.25 MiB):
    // [0,24)    wbf bf16 weights (wq..wo [0,8), w1 [8,16), w2 [16,24))
    // [24,48)   qkvB bf16 [BL][3072]; later hbuf bf16 [BL][4096] = [24,56)
    // [24,40)   P  fp32 out-proj partial 0 (over dead qkvB)
    // [40,56)   P2 fp32 out-proj partial 1 (dead qkvB tail + dead Qb)
    // [48,56)   xnb/Qb (dead after attn)
    // [56,64)   Kb (dead after attn)     [64,72) Vtb/xn2b (dead after FFN1)
    // [72,72.25) k2   [72.25,80.25) aO (dead after out-proj)
    // [0,16)    y0 fp32 FFN2 partial 0 (over dead wq..wo,w1; w2 [16,24) live)
    // [56,72)   y1 fp32 FFN2 partial 1 (over dead Kb,Vtb)
    char* base = (char*)d_ws;
    short* wbf  = (short*)base;
    short* qkvB = (short*)(base + (24u << 20));
    short* xnb  = (short*)(base + (48u << 20));
    short* Qb   = xnb;
    short* Kb   = (short*)(base + (56u << 20));
    short* Vtb  = (short*)(base + (64u << 20));
    float* k2   = (float*)(base + (72u << 20));
    short* aO   = (short*)(base + (72u << 20) + (256u << 10));
    float* P    = (float*)(base + (24u << 20));
    float* P2   = (float*)(base + (40u << 20));
    short* xn2b = Vtb;
    short* hbuf = qkvB;
    float* y0   = (float*)base;                     // FFN2 partial 0
    float* y1   = (float*)(base + (56u << 20));     // FFN2 partial 1

    // 0. weights -> bf16
    cvt6_kernel<<<12288, 256, 0, stream>>>(wq, wk, wv, wo, w1, w2, wbf);
    // 1. LN1 -> bf16
    ln_bf16_kernel<<<BL, 256, 0, stream>>>(x, g1, b1, xnb);
    // 2. fused QKV projection -> bf16 [BL][3072]
    gemm_mfma<128, 0, 1, 1, 1><<<dim3(24, 32), 256, 0, stream>>>(
        xnb, wbf, bq, bk, bv, qkvB, nullptr, BL, QKV_S, DM);
    // 3. prep: project q,k -> Qb/Kb [bh][L][64] + k2; transpose v -> Vtb
    qk_prep<<<16384, 256, 0, stream>>>(qkvB, Qb, Kb, k2);
    v_prep<<<1024, 256, 0, stream>>>(qkvB, Vtb);
    // 4. flash MFMA attention -> aO bf16
    attn_mfma2<<<dim3(16, 16, 2), 256, 0, stream>>>(Qb, Kb, Vtb, k2, aO);
    // 5. output projection, BM=128 split-K=2 -> P,P2 fp32 partials
    gemm_mfma<128, 0, 0, 0, 2><<<dim3(8, 32, 2), 256, 0, stream>>>(
        aO, wbf + 3145728, bo, bo, bo, P, P2, BL, DM, DM);
    // 6+7. x1 = project(x + P + P2) -> d_out, fused with LN2 -> xn2b
    resproj2_ln_kernel<<<BL, 256, 0, stream>>>(x, P, P2, g2, b2, out, xn2b);
    // 8. FFN1 + GELU -> bf16 hidden
    gemm_mfma<128, 1, 1, 0, 1><<<dim3(32, 32), 256, 0, stream>>>(
        xn2b, wbf + 4194304, bf1, bf1, bf1, hbuf, nullptr, BL, DFF, DM);
    // 9. FFN2, BM=128 split-K=2 -> y0,y1 fp32 partials
    gemm_mfma<128, 0, 0, 0, 2><<<dim3(8, 32, 2), 256, 0, stream>>>(
        hbuf, wbf + 8388608, bf2, bf2, bf2, y0, y1, BL, DM, DFF);
    // 10. out = project(x1 + y0 + y1)
    resproj2_kernel<<<BL, 256, 0, stream>>>(out, y0, y1, out);
}

// Round 10
// 352.966 us; speedup vs baseline: 1.3311x; 1.0509x over previous
//
#include <hip/hip_runtime.h>
#include <math.h>

// Problem constants: B=2, L=2048, D=1024, H=16, hd=64, Dff=4096
#define SEQ_L 2048
#define DM    1024
#define NH    16
#define HD    64
#define BL    4096          // B*L
#define DFF   4096
#define QKV_S 3072          // fused qkv row stride

typedef __attribute__((ext_vector_type(8))) short short8;   // 8 bf16 (4 VGPRs)
typedef __attribute__((ext_vector_type(4))) short s16x4;    // 4 bf16
typedef __attribute__((ext_vector_type(4))) float f32x4;    // MFMA C/D frag
typedef __attribute__((ext_vector_type(4))) int   i32x4;    // 4 packed bf16x2

// 0.25*log2(e), 0.125*log2(e) — fold exp->exp2 base change into the scales
#define C_QK  0.36067376022224085f
#define C_K2  0.18033688011112042f

#if __has_builtin(__builtin_amdgcn_exp2f)
#define EXP2(x) __builtin_amdgcn_exp2f(x)
#else
#define EXP2(x) exp2f(x)
#endif

// fp32 -> bf16 round-to-nearest-even
__device__ __forceinline__ short f2bf(float x) {
    unsigned u = __float_as_uint(x);
    u += 0x7fff + ((u >> 16) & 1);
    return (short)(u >> 16);
}
__device__ __forceinline__ float bf2f(short s) {
    return __uint_as_float(((unsigned)(unsigned short)s) << 16);
}
// pack two f32 -> one u32 of 2x bf16 (RNE); no builtin on gfx950 (m240)
__device__ __forceinline__ int cvt_pk_bf16(float lo, float hi) {
    int r;
    asm("v_cvt_pk_bf16_f32 %0, %1, %2" : "=v"(r) : "v"(lo), "v"(hi));
    return r;
}
// async global->LDS, 16 B per lane; LDS dest is wave-uniform base + lane*16
__device__ __forceinline__ void async_copy16(const short* gsrc, short* ldst) {
    __builtin_amdgcn_global_load_lds(
        (const __attribute__((address_space(1))) unsigned int*)gsrc,
        (__attribute__((address_space(3))) unsigned int*)ldst, 16, 0, 0);
}

// branch-free GELU (erf form) via A&S 7.1.26, |abs err| <= ~2e-7.
__device__ __forceinline__ float gelu_fast(float x) {
    const float xa = fabsf(x);
    const float z = xa * 0.70710678118654752440f;
    const float t = __builtin_amdgcn_rcpf(fmaf(0.3275911f, z, 1.f));
    float P = fmaf(t, 1.061405429f, -1.453152027f);
    P = fmaf(t, P, 1.421413741f);
    P = fmaf(t, P, -0.284496736f);
    P = fmaf(t, P, 0.254829592f);
    P *= t;
    const float e = __expf(-z * z);
    const float erfp = fmaf(-P, e, 1.f);   // erf(|x|/sqrt2)
    return 0.5f * fmaf(xa, erfp, x);
}

__device__ __forceinline__ float block_sum(float v, float* red, int tid) {
#pragma unroll
    for (int m = 32; m; m >>= 1) v += __shfl_xor(v, m);
    if ((tid & 63) == 0) red[tid >> 6] = v;
    __syncthreads();
    v = red[0] + red[1] + red[2] + red[3];
    __syncthreads();
    return v;
}

// ---------------------------------------------------------------------------
// Weight fp32 -> bf16: wq|wk|wv|wo|w1|w2 contiguous (fused QKV needs this).
// ---------------------------------------------------------------------------
__global__ __launch_bounds__(256) void cvt6_kernel(
    const float* __restrict__ wq, const float* __restrict__ wk,
    const float* __restrict__ wv, const float* __restrict__ wo,
    const float* __restrict__ w1, const float* __restrict__ w2,
    short* __restrict__ dst) {
    const size_t i = (size_t)blockIdx.x * 256 + threadIdx.x;  // float4 index
    const float* src;
    size_t off;
    if (i < 1048576) {
        const int seg = (int)(i >> 18);
        off = i & 262143;
        src = seg == 0 ? wq : seg == 1 ? wk : seg == 2 ? wv : wo;
    } else if (i < 2097152) { src = w1; off = i - 1048576; }
    else                    { src = w2; off = i - 2097152; }
    const float4 v = ((const float4*)src)[off];
    const s16x4 o = {f2bf(v.x), f2bf(v.y), f2bf(v.z), f2bf(v.w)};
    ((s16x4*)dst)[i] = o;
}

// ---------------------------------------------------------------------------
// LayerNorm over rows of 1024, bf16 output.
// ---------------------------------------------------------------------------
__global__ __launch_bounds__(256) void ln_bf16_kernel(const float* __restrict__ x,
                                                      const float* __restrict__ g,
                                                      const float* __restrict__ b,
                                                      short* __restrict__ out) {
    const int row = blockIdx.x;
    const int tid = threadIdx.x;
    __shared__ float red[4];
    const float4 xv = *(const float4*)(x + (size_t)row * DM + tid * 4);
    float s = xv.x + xv.y + xv.z + xv.w;
    s = block_sum(s, red, tid);
    const float mean = s * (1.f / (float)DM);
    float dx0 = xv.x - mean, dx1 = xv.y - mean, dx2 = xv.z - mean, dx3 = xv.w - mean;
    float ss = dx0 * dx0 + dx1 * dx1 + dx2 * dx2 + dx3 * dx3;
    ss = block_sum(ss, red, tid);
    const float rs = 1.f / sqrtf(ss * (1.f / (float)DM) + 1e-5f);
    const float4 gv = *(const float4*)(g + tid * 4);
    const float4 bv = *(const float4*)(b + tid * 4);
    const s16x4 ob = {f2bf(dx0 * rs * gv.x + bv.x), f2bf(dx1 * rs * gv.y + bv.y),
                      f2bf(dx2 * rs * gv.z + bv.z), f2bf(dx3 * rs * gv.w + bv.w)};
    *(s16x4*)(out + (size_t)row * DM + tid * 4) = ob;
}

// ---------------------------------------------------------------------------
// Residual + TWO split-K partials + Poincare projection (fp32, in-place safe).
// ---------------------------------------------------------------------------
__global__ __launch_bounds__(256) void resproj2_kernel(const float* __restrict__ a,
                                                       const float* __restrict__ c0,
                                                       const float* __restrict__ c1,
                                                       float* __restrict__ out) {
    const int row = blockIdx.x;
    const int tid = threadIdx.x;
    __shared__ float red[4];
    const float4 av = *(const float4*)(a + (size_t)row * DM + tid * 4);
    const float4 cv = *(const float4*)(c0 + (size_t)row * DM + tid * 4);
    const float4 dv = *(const float4*)(c1 + (size_t)row * DM + tid * 4);
    float4 sv;
    sv.x = av.x + cv.x + dv.x; sv.y = av.y + cv.y + dv.y;
    sv.z = av.z + cv.z + dv.z; sv.w = av.w + cv.w + dv.w;
    float ss = sv.x * sv.x + sv.y * sv.y + sv.z * sv.z + sv.w * sv.w;
    ss = block_sum(ss, red, tid);
    const float n = sqrtf(ss);
    const float mx = 1.f - 1e-5f;
    const float scale = (n > mx) ? (mx / fmaxf(n, 1e-12f)) : 1.f;
    sv.x *= scale; sv.y *= scale; sv.z *= scale; sv.w *= scale;
    *(float4*)(out + (size_t)row * DM + tid * 4) = sv;
}

// ---------------------------------------------------------------------------
// FUSED: residual + two split-K partials + Poincare projection + LayerNorm.
// ---------------------------------------------------------------------------
__global__ __launch_bounds__(256) void resproj2_ln_kernel(
    const float* __restrict__ a, const float* __restrict__ c0,
    const float* __restrict__ c1, const float* __restrict__ g,
    const float* __restrict__ b, float* __restrict__ out,
    short* __restrict__ obf) {
    const int row = blockIdx.x;
    const int tid = threadIdx.x;
    __shared__ float red[4];
    const float4 av = *(const float4*)(a + (size_t)row * DM + tid * 4);
    const float4 cv = *(const float4*)(c0 + (size_t)row * DM + tid * 4);
    const float4 dv = *(const float4*)(c1 + (size_t)row * DM + tid * 4);
    float4 sv;
    sv.x = av.x + cv.x + dv.x; sv.y = av.y + cv.y + dv.y;
    sv.z = av.z + cv.z + dv.z; sv.w = av.w + cv.w + dv.w;
    float ss = sv.x * sv.x + sv.y * sv.y + sv.z * sv.z + sv.w * sv.w;
    ss = block_sum(ss, red, tid);
    const float n = sqrtf(ss);
    const float mx = 1.f - 1e-5f;
    const float scale = (n > mx) ? (mx / fmaxf(n, 1e-12f)) : 1.f;
    sv.x *= scale; sv.y *= scale; sv.z *= scale; sv.w *= scale;
    *(float4*)(out + (size_t)row * DM + tid * 4) = sv;
    // LayerNorm on the projected row (values already in registers)
    float s = sv.x + sv.y + sv.z + sv.w;
    s = block_sum(s, red, tid);
    const float mean = s * (1.f / (float)DM);
    const float dx0 = sv.x - mean, dx1 = sv.y - mean,
                dx2 = sv.z - mean, dx3 = sv.w - mean;
    float s2 = dx0 * dx0 + dx1 * dx1 + dx2 * dx2 + dx3 * dx3;
    s2 = block_sum(s2, red, tid);
    const float rs = 1.f / sqrtf(s2 * (1.f / (float)DM) + 1e-5f);
    const float4 gv = *(const float4*)(g + tid * 4);
    const float4 bv = *(const float4*)(b + tid * 4);
    const s16x4 ob = {f2bf(dx0 * rs * gv.x + bv.x), f2bf(dx1 * rs * gv.y + bv.y),
                      f2bf(dx2 * rs * gv.z + bv.z), f2bf(dx3 * rs * gv.w + bv.w)};
    *(s16x4*)(obf + (size_t)row * DM + tid * 4) = ob;
}

// ---------------------------------------------------------------------------
// q/k prep: per-head Poincare projection + attention-layout bf16 buffers.
// k2 prescaled by 0.125*log2(e) so attention can use exp2 directly.
// ---------------------------------------------------------------------------
__global__ __launch_bounds__(256) void qk_prep(const short* __restrict__ qkvB,
                                               short* __restrict__ Qb,
                                               short* __restrict__ Kb,
                                               float* __restrict__ k2) {
    const int tid = threadIdx.x, lane = tid & 63;
    const int vec = blockIdx.x * 4 + (tid >> 6);
    const int row = vec >> 4, h = vec & 15;
    const int b = row >> 11, l = row & 2047;
    const size_t dstv = ((size_t)(b * NH + h) * SEQ_L + l) * HD + lane;
    const float mx = 1.f - 1e-5f;
    {   // q
        const float v = bf2f(qkvB[(size_t)row * QKV_S + h * HD + lane]);
        float s = v * v;
#pragma unroll
        for (int m = 32; m; m >>= 1) s += __shfl_xor(s, m);
        const float n = sqrtf(s);
        const float sc = (n > mx) ? (mx / fmaxf(n, 1e-12f)) : 1.f;
        Qb[dstv] = f2bf(v * sc);
    }
    {   // k (+ prescaled squared norm, in log2 units)
        const float v = bf2f(qkvB[(size_t)row * QKV_S + DM + h * HD + lane]);
        float s = v * v;
#pragma unroll
        for (int m = 32; m; m >>= 1) s += __shfl_xor(s, m);
        const float n = sqrtf(s);
        const float sc = (n > mx) ? (mx / fmaxf(n, 1e-12f)) : 1.f;
        Kb[dstv] = f2bf(v * sc);
        if (lane == 0) k2[(size_t)(b * NH + h) * SEQ_L + l] = s * sc * sc * C_K2;
    }
}

// ---------------------------------------------------------------------------
// v prep: transpose to Vtb [b][h][64 hd][L] bf16, with the columns of each
// 32-wide k-block interleaved as [g0 lo4 | g0 hi4 | g1 lo4 | g1 hi4 | ...]
// so the attention PV A-fragment is ONE contiguous aligned 16B load.
// ---------------------------------------------------------------------------
__global__ __launch_bounds__(256) void v_prep(const short* __restrict__ qkvB,
                                              short* __restrict__ Vtb) {
    const int blk = blockIdx.x;
    const int bh = blk >> 5, kt = blk & 31;
    const int b = bh >> 4, h = bh & 15;
    __shared__ short T[64 * 72];
    const int tid = threadIdx.x;
    {
        const int key = tid >> 2, ch = (tid & 3) * 16;
        const size_t src = ((size_t)b * SEQ_L + kt * 64 + key) * QKV_S + 2 * DM + h * HD + ch;
        *(short8*)&T[key * 72 + ch]     = *(const short8*)(qkvB + src);
        *(short8*)&T[key * 72 + ch + 8] = *(const short8*)(qkvB + src + 8);
    }
    __syncthreads();
    const int hd = tid >> 2, kc = (tid & 3) * 16;
    short8 o0, o1;
#pragma unroll
    for (int j = 0; j < 8; ++j) {
        o0[j] = T[(kc + j) * 72 + hd];
        o1[j] = T[(kc + 8 + j) * 72 + hd];
    }
    const int c32 = (kc >> 5) * 32;          // which 32-block (0 or 32)
    const int h4  = ((kc >> 4) & 1) * 4;     // low/high half of the block
    short* dst = Vtb + ((size_t)bh * HD + hd) * SEQ_L + kt * 64 + c32 + h4;
    const s16x4 w0 = {o0[0], o0[1], o0[2], o0[3]};
    const s16x4 w1 = {o0[4], o0[5], o0[6], o0[7]};
    const s16x4 w2 = {o1[0], o1[1], o1[2], o1[3]};
    const s16x4 w3 = {o1[4], o1[5], o1[6], o1[7]};
    *(s16x4*)(dst)      = w0;
    *(s16x4*)(dst + 8)  = w1;
    *(s16x4*)(dst + 16) = w2;
    *(s16x4*)(dst + 24) = w3;
}

// ---------------------------------------------------------------------------
// 256x256 8-PHASE bf16 GEMM (round 10; m201 template re-derived in plain HIP).
// 8 waves (2M x 4N), per-wave 128x64 output (acc 8x4 f32x4), BK=64.
// LDS = 2 buffers x (A 256x64 + B 256x64) bf16 = 128 KB; buffer par = Ktile&1.
// Per iteration (K-tiles T=2i, T+1): 8 phases, each:
//   ds-read quadrant A frags (4 b128; +8 B frags at K-tile start, held in regs)
//   stage ONE half-tile via 2 swizzled-source global_load_lds
//   s_waitcnt vmcnt(4)  (counted: newest 2 phases stay in flight; last iter
//                        tightens to vmcnt(0) from ph3 to cover the tail)
//   s_barrier ; setprio(1) 16 MFMA setprio(0) ; s_barrier
// Stage rotation A(T+1)@ph0-1, B(T+2)@ph2-3, A(T+2)@ph4-5, B(T+3)@ph6-7:
// every stage lands in a slot whose last reader finished >=1 barrier earlier
// (B of a tile is read only in its first phase into registers; A quadrant q
// is last read at phase q), and vmcnt(4)+barrier publishes each half >=1 full
// phase before its first ds-read. Prologue pre-stages A(0),B(0),B(1).
// Swizzle: LDS row=64 shorts (128B); write lane l -> phys slot l&7 from
// global logical slot (l&7)^(l>>3); read phys = logical ^ (row&7) ->
// uniform 8-access/bank (the b128 floor) on both sides (rule #21).
// ---------------------------------------------------------------------------
template <int ACT, int FUSED>
__global__ __launch_bounds__(512) void gemm256_8ph(
    const short* __restrict__ A, const short* __restrict__ Bw,
    const float* __restrict__ bb0, const float* __restrict__ bb1,
    const float* __restrict__ bb2, short* __restrict__ Cout,
    int M, int N, int K) {
    __shared__ __align__(16) short lds[65536];   // 128 KiB
    const int tid = threadIdx.x;
    const int wv = tid >> 6, lane = tid & 63;

    // XCD-aware bijective swizzle (grid % 8 == 0: 192 and 256)
    const int gx = gridDim.x;
    const int nwg = gx * gridDim.y;
    int d = blockIdx.x + gx * blockIdx.y;
    d = (d & 7) * (nwg >> 3) + (d >> 3);
    const int bx = d % gx, by = d / gx;
    const int m0 = by * 256, n0 = bx * 256;
    const int wm = wv >> 2, wn = wv & 3;

    // staging addressing: chunk = wv*2+j covers 8 LDS rows (1 KB linear)
    const int srl = lane >> 3;                     // row within 8-row chunk
    const int scol = ((lane & 7) ^ srl) * 8;       // pre-swizzled source col
    const short* Asrc = A + (size_t)(m0 + srl) * K + scol;
    const short* Bsrc = Bw + (size_t)(n0 + srl) * K + scol;
    short* dstW = lds + (wv * 2) * 512;            // wave-uniform

    auto stA = [&](int t, int h) {
#pragma unroll
        for (int j = 0; j < 2; ++j)
            async_copy16(Asrc + (size_t)(h * 128 + (wv * 2 + j) * 8) * K + t * 64,
                         dstW + (t & 1) * 32768 + h * 8192 + j * 512);
    };
    auto stB = [&](int t, int h) {
#pragma unroll
        for (int j = 0; j < 2; ++j)
            async_copy16(Bsrc + (size_t)(h * 128 + (wv * 2 + j) * 8) * K + t * 64,
                         dstW + (t & 1) * 32768 + 16384 + h * 8192 + j * 512);
    };

    // fragment addressing (XOR-unswizzled read slots)
    const int lrow = lane & 15, kq4 = lane >> 4;
    const int s0 = (kq4 ^ (lrow & 7)) * 8;         // ks=0 slot offset (shorts)
    const int s1 = ((4 + kq4) ^ (lrow & 7)) * 8;   // ks=1
    const short* ArdB = lds + wm * 8192 + lrow * 64;
    const short* BrdB = lds + 16384 + (wn >> 1) * 8192 + ((wn & 1) * 64 + lrow) * 64;

    const f32x4 z4 = {0.f, 0.f, 0.f, 0.f};
    f32x4 acc[8][4];
#pragma unroll
    for (int r = 0; r < 8; ++r)
#pragma unroll
        for (int c = 0; c < 4; ++c) acc[r][c] = z4;
    short8 bfr[4][2];

    const int NT = K / 64, NIT = NT / 2;   // NT=16 here (even, >=4)

    // prologue: A(0)h0,h1  B(0)h0,h1  B(1)h0,h1 (12 loads/thread, in order)
    stA(0, 0); stA(0, 1); stB(0, 0); stB(0, 1); stB(1, 0); stB(1, 1);
    asm volatile("s_waitcnt vmcnt(4)" ::: "memory");   // A(0),B(0) landed
    __builtin_amdgcn_sched_barrier(0);
    __builtin_amdgcn_s_barrier();

    for (int i = 0; i < NIT; ++i) {
        const int T = 2 * i;
        const bool notlast = (T + 4 <= NT);
#pragma unroll
        for (int pp = 0; pp < 8; ++pp) {
            const int par = pp >> 2, q = pp & 3;
            // ds-load register subtile
            if (q == 0) {
#pragma unroll
                for (int fn = 0; fn < 4; ++fn) {
                    bfr[fn][0] = *(const short8*)(BrdB + par * 32768 + fn * 1024 + s0);
                    bfr[fn][1] = *(const short8*)(BrdB + par * 32768 + fn * 1024 + s1);
                }
            }
            const short8 a00 = *(const short8*)(ArdB + par * 32768 + (2 * q) * 1024 + s0);
            const short8 a01 = *(const short8*)(ArdB + par * 32768 + (2 * q) * 1024 + s1);
            const short8 a10 = *(const short8*)(ArdB + par * 32768 + (2 * q + 1) * 1024 + s0);
            const short8 a11 = *(const short8*)(ArdB + par * 32768 + (2 * q + 1) * 1024 + s1);
            // stage one half-tile
            const int dt = T + (pp < 2 ? 1 : (pp < 6 ? 2 : 3));
            if (dt < NT) {
                if ((pp >> 1) & 1) stB(dt, pp & 1);
                else               stA(dt, pp & 1);
            }
            if (notlast || pp < 3)
                asm volatile("s_waitcnt vmcnt(4)" ::: "memory");
            else
                asm volatile("s_waitcnt vmcnt(0)" ::: "memory");
            __builtin_amdgcn_sched_barrier(0);
            __builtin_amdgcn_s_barrier();
            __builtin_amdgcn_sched_barrier(0);
            __builtin_amdgcn_s_setprio(1);
#pragma unroll
            for (int fn = 0; fn < 4; ++fn) {
                acc[2 * q][fn]     = __builtin_amdgcn_mfma_f32_16x16x32_bf16(a00, bfr[fn][0], acc[2 * q][fn], 0, 0, 0);
                acc[2 * q][fn]     = __builtin_amdgcn_mfma_f32_16x16x32_bf16(a01, bfr[fn][1], acc[2 * q][fn], 0, 0, 0);
                acc[2 * q + 1][fn] = __builtin_amdgcn_mfma_f32_16x16x32_bf16(a10, bfr[fn][0], acc[2 * q + 1][fn], 0, 0, 0);
                acc[2 * q + 1][fn] = __builtin_amdgcn_mfma_f32_16x16x32_bf16(a11, bfr[fn][1], acc[2 * q + 1][fn], 0, 0, 0);
            }
            __builtin_amdgcn_s_setprio(0);
            __builtin_amdgcn_sched_barrier(0);
            __builtin_amdgcn_s_barrier();
        }
    }

    // epilogue: per-wave LDS transpose (two 64x64 passes) -> short8 stores
    __syncthreads();
    short* Ot = lds + wv * (64 * 72);
    const int col = lane & 15, rb4 = (lane >> 4) * 4;
    const int orow = lane >> 3, oc = (lane & 7) * 8;
#pragma unroll
    for (int half = 0; half < 2; ++half) {
#pragma unroll
        for (int fn = 0; fn < 4; ++fn) {
            const int gn = n0 + wn * 64 + fn * 16 + col;
            float bias;
            if constexpr (FUSED) {
                const int seg = gn >> 10;
                bias = (seg == 0 ? bb0 : seg == 1 ? bb1 : bb2)[gn & 1023];
            } else {
                bias = bb0[gn];
            }
#pragma unroll
            for (int fl = 0; fl < 4; ++fl)
#pragma unroll
                for (int ii = 0; ii < 4; ++ii) {
                    float v = acc[half * 4 + fl][fn][ii] + bias;
                    if constexpr (ACT) v = gelu_fast(v);
                    Ot[(fl * 16 + rb4 + ii) * 72 + fn * 16 + col] = f2bf(v);
                }
        }
#pragma unroll
        for (int it = 0; it < 8; ++it) {
            const short8 vv = *(const short8*)&Ot[(it * 8 + orow) * 72 + oc];
            *(short8*)(Cout + (size_t)(m0 + wm * 128 + half * 64 + it * 8 + orow) * N
                       + n0 + wn * 64 + oc) = vv;
        }
    }
}

// ---------------------------------------------------------------------------
// bf16 MFMA NT GEMM (128-tile, counted-vmcnt depth-2) — kept for the N=1024
// GEMMs (out-proj, FFN2) where 256-tiles would collapse occupancy.
// ---------------------------------------------------------------------------
template <int BM, int ACT, int OUTBF, int FUSED, int SPLITK>
__global__ __launch_bounds__(256) void gemm_mfma(
    const short* __restrict__ A, const short* __restrict__ Bw,
    const float* __restrict__ bb0, const float* __restrict__ bb1,
    const float* __restrict__ bb2, void* __restrict__ Cout,
    void* __restrict__ Cout2,
    int M, int N, int K) {
    static_assert(BM == 128, "staging assumes BM=128");
    constexpr int RT = BM / 32;
    constexpr bool VEPI = (OUTBF != 0) && (BM == 128);
    constexpr int BUFSH = 2 * 128 * 32;     // A+B per buffer (8192 shorts)
    constexpr int RAWS = 3 * BUFSH;         // 24576 shorts = 48 KB
    static_assert(RAWS >= 4 * 64 * 72, "VEPI Ot fits in staging buffers");
    __shared__ __align__(16) short raw[RAWS];
    const int tid = threadIdx.x;
    const int wv = tid >> 6, lane = tid & 63;

    const int gx = gridDim.x, gy = gridDim.y;
    const int nwg = gx * gy * gridDim.z;
    int d = blockIdx.x + gx * (blockIdx.y + gy * blockIdx.z);
    d = (d & 7) * (nwg >> 3) + (d >> 3);
    const int bx = d % gx;
    const int byz = d / gx;
    const int by = byz % gy;
    const int bz = byz / gy;

    const int m0 = by * BM, n0 = bx * 128;
    const int wr = (wv & 1) * (BM / 2);
    const int wc = (wv >> 1) * 64;

    const int z = (SPLITK > 1) ? bz : 0;
    const int Kc = K / SPLITK;

    const int srl = lane >> 2;
    const int scol = ((lane & 3) ^ ((lane >> 3) & 3)) * 8;
    const short* Ag = A + (size_t)(m0 + wv * 32 + srl) * K + z * Kc + scol;
    const short* Bg = Bw + (size_t)(n0 + wv * 32 + srl) * K + z * Kc + scol;
    short* ldsA = raw + (wv * 32) * 32;
    short* ldsB = raw + 128 * 32 + (wv * 32) * 32;

    const f32x4 z4 = {0.f, 0.f, 0.f, 0.f};
    f32x4 acc[RT][4];
#pragma unroll
    for (int r = 0; r < RT; ++r)
#pragma unroll
        for (int c = 0; c < 4; ++c) acc[r][c] = z4;

    const int lrow = lane & 15;
    const int rdoff = ((lane >> 4) ^ ((lrow >> 1) & 3)) * 8;

    auto stage = [&](int kto, int buf) {
        const int nb = buf * BUFSH;
#pragma unroll
        for (int j = 0; j < 2; ++j) {
            async_copy16(Ag + (size_t)(16 * j) * K + kto, ldsA + nb + (16 * j) * 32);
            async_copy16(Bg + (size_t)(16 * j) * K + kto, ldsB + nb + (16 * j) * 32);
        }
    };
    auto compute = [&](int buf) {
        const short* As = raw + buf * BUFSH;
        const short* Bs = As + 128 * 32;
        short8 af[RT], bf[4];
#pragma unroll
        for (int r = 0; r < RT; ++r)
            af[r] = *(const short8*)&As[(wr + r * 16 + lrow) * 32 + rdoff];
#pragma unroll
        for (int c = 0; c < 4; ++c)
            bf[c] = *(const short8*)&Bs[(wc + c * 16 + lrow) * 32 + rdoff];
#pragma unroll
        for (int r = 0; r < RT; ++r)
#pragma unroll
            for (int c = 0; c < 4; ++c)
                acc[r][c] = __builtin_amdgcn_mfma_f32_16x16x32_bf16(af[r], bf[c], acc[r][c], 0, 0, 0);
    };

    stage(0, 0);
    stage(32, 1);

    int cur = 0;
    int kt = 0;
    for (; kt + 32 < Kc; kt += 32) {
        asm volatile("s_waitcnt vmcnt(4)" ::: "memory");
        __builtin_amdgcn_sched_barrier(0);
        __builtin_amdgcn_s_barrier();
        __builtin_amdgcn_sched_barrier(0);
        if (kt + 64 < Kc) {
            int nb = cur + 2; if (nb >= 3) nb -= 3;
            stage(kt + 64, nb);
        }
        compute(cur);
        cur = (cur == 2) ? 0 : cur + 1;
    }
    asm volatile("s_waitcnt vmcnt(0)" ::: "memory");
    __builtin_amdgcn_sched_barrier(0);
    __builtin_amdgcn_s_barrier();
    __builtin_amdgcn_sched_barrier(0);
    compute(cur);

    void* Cbase = Cout;
    if constexpr (SPLITK > 1) { if (z) Cbase = Cout2; }

    const int col = lane & 15, rb4 = (lane >> 4) * 4;
    if constexpr (VEPI) {
        __syncthreads();
        short* Ot = raw + wv * (64 * 72);
#pragma unroll
        for (int c = 0; c < 4; ++c) {
            const int gn = n0 + wc + c * 16 + col;
            float bias;
            if constexpr (FUSED) {
                const int seg = gn >> 10;
                bias = (seg == 0 ? bb0 : seg == 1 ? bb1 : bb2)[gn & 1023];
            } else {
                bias = bb0[gn];
            }
#pragma unroll
            for (int r = 0; r < RT; ++r)
#pragma unroll
                for (int i = 0; i < 4; ++i) {
                    float v = acc[r][c][i] + bias;
                    if constexpr (ACT) v = gelu_fast(v);
                    Ot[(r * 16 + rb4 + i) * 72 + c * 16 + col] = f2bf(v);
                }
        }
        const int orow = lane >> 3, oc = (lane & 7) * 8;
#pragma unroll
        for (int it = 0; it < 8; ++it) {
            const short8 vv = *(const short8*)&Ot[(it * 8 + orow) * 72 + oc];
            *(short8*)((short*)Cbase + (size_t)(m0 + wr + it * 8 + orow) * N + n0 + wc + oc) = vv;
        }
    } else {
#pragma unroll
        for (int c = 0; c < 4; ++c) {
            const int gn = n0 + wc + c * 16 + col;
            float bias;
            if constexpr (FUSED) {
                const int seg = gn >> 10;
                bias = (seg == 0 ? bb0 : seg == 1 ? bb1 : bb2)[gn & 1023];
            } else {
                bias = bb0[gn];
            }
            if constexpr (SPLITK > 1) { if (z) bias = 0.f; }
#pragma unroll
            for (int r = 0; r < RT; ++r) {
                const int gm = m0 + wr + r * 16 + rb4;
#pragma unroll
                for (int i = 0; i < 4; ++i) {
                    float v = acc[r][c][i] + bias;
                    if constexpr (ACT) v = gelu_fast(v);
                    if constexpr (OUTBF)
                        ((short*)Cbase)[(size_t)(gm + i) * N + gn] = f2bf(v);
                    else
                        ((float*)Cbase)[(size_t)(gm + i) * N + gn] = v;
                }
            }
        }
    }
}

// ---------------------------------------------------------------------------
// MFMA flash attention: single-barrier LDS double buffer + XCD swizzle +
// setprio around PV MFMA cluster. FETCH 12.5 MB (L2-resident); VALU-limited.
// ---------------------------------------------------------------------------
__global__ __launch_bounds__(256) void attn_mfma2(const short* __restrict__ Qb,
                                                  const short* __restrict__ Kb,
                                                  const short* __restrict__ Vtb,
                                                  const float* __restrict__ k2v,
                                                  short* __restrict__ aO) {
    int d = blockIdx.x + 16 * (blockIdx.y + 16 * blockIdx.z);
    d = (d & 7) * 64 + (d >> 3);            // 512 blocks, bijective
    const int qt = d & 15, h = (d >> 4) & 15, b = d >> 8;
    const int tid = threadIdx.x, wv = tid >> 6, lane = tid & 63;
    const int bh = b * NH + h;
    constexpr int NT = SEQ_L / 64;
    constexpr int BUFS = 64 * 72;    // shorts per K (or V) tile buffer
    __shared__ __align__(16) short smem[4 * BUFS];  // {K,V} x double buffer; Ot reuse
    __shared__ __align__(16) float k2s[SEQ_L];
    const int lrow = lane & 15, q8 = (lane >> 4) * 8, q4 = (lane >> 4) * 4;

    const short* Qh = Qb + (size_t)bh * SEQ_L * HD;
    const short* Kh = Kb + (size_t)bh * SEQ_L * HD;
    const short* Vh = Vtb + (size_t)bh * HD * SEQ_L;
    const float* k2p = k2v + (size_t)bh * SEQ_L;

    short8 qf[2][2];
#pragma unroll
    for (int nt = 0; nt < 2; ++nt)
#pragma unroll
        for (int kc = 0; kc < 2; ++kc)
            qf[nt][kc] = *(const short8*)(Qh +
                (size_t)(qt * 128 + wv * 32 + nt * 16 + lrow) * HD + kc * 32 + q8);

    {
        const float4 a0 = *(const float4*)(k2p + tid * 4);
        const float4 a1 = *(const float4*)(k2p + 1024 + tid * 4);
        *(float4*)&k2s[tid * 4] = a0;
        *(float4*)&k2s[1024 + tid * 4] = a1;
    }

    const int srow = tid >> 2, sch = (tid & 3) * 16;
    const short* gK = Kh + (size_t)srow * HD + sch;
    const short* gV = Vh + (size_t)srow * SEQ_L + sch;
    const int woff = srow * 72 + sch;

    {
        const short8 k0a = *(const short8*)(gK);
        const short8 k0b = *(const short8*)(gK + 8);
        const short8 v0a = *(const short8*)(gV);
        const short8 v0b = *(const short8*)(gV + 8);
        *(short8*)&smem[woff]            = k0a;
        *(short8*)&smem[woff + 8]        = k0b;
        *(short8*)&smem[BUFS + woff]     = v0a;
        *(short8*)&smem[BUFS + woff + 8] = v0b;
    }
    __syncthreads();

    const f32x4 z4 = {0.f, 0.f, 0.f, 0.f};
    f32x4 o[4][2];
#pragma unroll
    for (int ht = 0; ht < 4; ++ht)
#pragma unroll
        for (int nt = 0; nt < 2; ++nt) o[ht][nt] = z4;
    float lsum[2] = {0.f, 0.f};

    for (int kt = 0; kt < NT; ++kt) {
        const int k0 = kt * 64;
        const short* Ks = smem + (kt & 1) * (2 * BUFS);
        const short* Vt = Ks + BUFS;
        short8 nk0, nk1, nv0, nv1;
        const bool more = (kt + 1 < NT);
        if (more) {
            const short* g = gK + (size_t)(k0 + 64) * HD;
            nk0 = *(const short8*)(g);
            nk1 = *(const short8*)(g + 8);
            const short* gv2 = gV + (k0 + 64);
            nv0 = *(const short8*)(gv2);
            nv1 = *(const short8*)(gv2 + 8);
        }

        i32x4 pw[2][2];
#pragma unroll
        for (int mt = 0; mt < 4; ++mt) {
            const short8 kf0 = *(const short8*)&Ks[(mt * 16 + lrow) * 72 + q8];
            const short8 kf1 = *(const short8*)&Ks[(mt * 16 + lrow) * 72 + 32 + q8];
            const float4 kk = *(const float4*)&k2s[k0 + mt * 16 + q4];
            const int c = mt >> 1, wb = (mt & 1) * 2;
#pragma unroll
            for (int nt = 0; nt < 2; ++nt) {
                f32x4 s = z4;
                s = __builtin_amdgcn_mfma_f32_16x16x32_bf16(kf0, qf[nt][0], s, 0, 0, 0);
                s = __builtin_amdgcn_mfma_f32_16x16x32_bf16(kf1, qf[nt][1], s, 0, 0, 0);
                const float p0 = EXP2(fmaf(s[0], C_QK, -kk.x));
                const float p1 = EXP2(fmaf(s[1], C_QK, -kk.y));
                const float p2 = EXP2(fmaf(s[2], C_QK, -kk.z));
                const float p3 = EXP2(fmaf(s[3], C_QK, -kk.w));
                lsum[nt] += (p0 + p1) + (p2 + p3);
                pw[nt][c][wb]     = cvt_pk_bf16(p0, p1);
                pw[nt][c][wb + 1] = cvt_pk_bf16(p2, p3);
            }
        }
        __builtin_amdgcn_s_setprio(1);
#pragma unroll
        for (int ht = 0; ht < 4; ++ht) {
#pragma unroll
            for (int c = 0; c < 2; ++c) {
                const short8 v8 = *(const short8*)&Vt[(ht * 16 + lrow) * 72 + c * 32 + q4 * 2];
#pragma unroll
                for (int nt = 0; nt < 2; ++nt)
                    o[ht][nt] = __builtin_amdgcn_mfma_f32_16x16x32_bf16(
                        v8, __builtin_bit_cast(short8, pw[nt][c]), o[ht][nt], 0, 0, 0);
            }
        }
        __builtin_amdgcn_s_setprio(0);

        if (more) {
            short* Kd = smem + ((kt + 1) & 1) * (2 * BUFS);
            *(short8*)&Kd[woff]            = nk0;
            *(short8*)&Kd[woff + 8]        = nk1;
            *(short8*)&Kd[BUFS + woff]     = nv0;
            *(short8*)&Kd[BUFS + woff + 8] = nv1;
        }
        __syncthreads();
    }

#pragma unroll
    for (int nt = 0; nt < 2; ++nt) {
        lsum[nt] += __shfl_xor(lsum[nt], 16);
        lsum[nt] += __shfl_xor(lsum[nt], 32);
    }
    const float inv0 = 1.f / lsum[0], inv1 = 1.f / lsum[1];

    short* Ot = smem + wv * (32 * 72);
#pragma unroll
    for (int ht = 0; ht < 4; ++ht)
#pragma unroll
        for (int nt = 0; nt < 2; ++nt) {
            const float iv = nt ? inv1 : inv0;
            const s16x4 ov = {f2bf(o[ht][nt][0] * iv), f2bf(o[ht][nt][1] * iv),
                              f2bf(o[ht][nt][2] * iv), f2bf(o[ht][nt][3] * iv)};
            *(s16x4*)&Ot[(nt * 16 + lrow) * 72 + ht * 16 + q4] = ov;
        }
    const int erow = lane >> 1, ec = (lane & 1) * 32;
    const short8 r0 = *(const short8*)&Ot[erow * 72 + ec + 0];
    const short8 r1 = *(const short8*)&Ot[erow * 72 + ec + 8];
    const short8 r2 = *(const short8*)&Ot[erow * 72 + ec + 16];
    const short8 r3 = *(const short8*)&Ot[erow * 72 + ec + 24];
    short* dst = aO + ((size_t)b * SEQ_L + qt * 128 + wv * 32 + erow) * DM + h * HD + ec;
    *(short8*)(dst + 0)  = r0;
    *(short8*)(dst + 8)  = r1;
    *(short8*)(dst + 16) = r2;
    *(short8*)(dst + 24) = r3;
}

// ---------------------------------------------------------------------------
// Launch
// ---------------------------------------------------------------------------
extern "C" void kernel_launch(void* const* d_in, const int* in_sizes, int n_in,
                              void* d_out, int out_size, void* d_ws, size_t ws_size,
                              hipStream_t stream) {
    const float* x   = (const float*)d_in[0];
    const float* wq  = (const float*)d_in[1];
    const float* bq  = (const float*)d_in[2];
    const float* wk  = (const float*)d_in[3];
    const float* bk  = (const float*)d_in[4];
    const float* wv  = (const float*)d_in[5];
    const float* bv  = (const float*)d_in[6];
    const float* wo  = (const float*)d_in[7];
    const float* bo  = (const float*)d_in[8];
    const float* g1  = (const float*)d_in[9];
    const float* b1  = (const float*)d_in[10];
    const float* g2  = (const float*)d_in[11];
    const float* b2  = (const float*)d_in[12];
    const float* w1  = (const float*)d_in[13];
    const float* bf1 = (const float*)d_in[14];
    const float* w2  = (const float*)d_in[15];
    const float* bf2 = (const float*)d_in[16];
    float* out = (float*)d_out;

    // ws layout (MiB): see prior rounds — unchanged.
    char* base = (char*)d_ws;
    short* wbf  = (short*)base;
    short* qkvB = (short*)(base + (24u << 20));
    short* xnb  = (short*)(base + (48u << 20));
    short* Qb   = xnb;
    short* Kb   = (short*)(base + (56u << 20));
    short* Vtb  = (short*)(base + (64u << 20));
    float* k2   = (float*)(base + (72u << 20));
    short* aO   = (short*)(base + (72u << 20) + (256u << 10));
    float* P    = (float*)(base + (24u << 20));
    float* P2   = (float*)(base + (40u << 20));
    short* xn2b = Vtb;
    short* hbuf = qkvB;
    float* y0   = (float*)base;                     // FFN2 partial 0
    float* y1   = (float*)(base + (56u << 20));     // FFN2 partial 1

    // 0. weights -> bf16
    cvt6_kernel<<<12288, 256, 0, stream>>>(wq, wk, wv, wo, w1, w2, wbf);
    // 1. LN1 -> bf16
    ln_bf16_kernel<<<BL, 256, 0, stream>>>(x, g1, b1, xnb);
    // 2. fused QKV projection -> bf16 [BL][3072]  (256^2 8-phase)
    gemm256_8ph<0, 1><<<dim3(12, 16), 512, 0, stream>>>(
        xnb, wbf, bq, bk, bv, qkvB, BL, QKV_S, DM);
    // 3. prep: project q,k -> Qb/Kb [bh][L][64] + k2; transpose v -> Vtb
    qk_prep<<<16384, 256, 0, stream>>>(qkvB, Qb, Kb, k2);
    v_prep<<<1024, 256, 0, stream>>>(qkvB, Vtb);
    // 4. flash MFMA attention -> aO bf16
    attn_mfma2<<<dim3(16, 16, 2), 256, 0, stream>>>(Qb, Kb, Vtb, k2, aO);
    // 5. output projection, BM=128 split-K=2 -> P,P2 fp32 partials
    gemm_mfma<128, 0, 0, 0, 2><<<dim3(8, 32, 2), 256, 0, stream>>>(
        aO, wbf + 3145728, bo, bo, bo, P, P2, BL, DM, DM);
    // 6+7. x1 = project(x + P + P2) -> d_out, fused with LN2 -> xn2b
    resproj2_ln_kernel<<<BL, 256, 0, stream>>>(x, P, P2, g2, b2, out, xn2b);
    // 8. FFN1 + GELU -> bf16 hidden  (256^2 8-phase)
    gemm256_8ph<1, 0><<<dim3(16, 16), 512, 0, stream>>>(
        xn2b, wbf + 4194304, bf1, bf1, bf1, hbuf, BL, DFF, DM);
    // 9. FFN2, BM=128 split-K=2 -> y0,y1 fp32 partials
    gemm_mfma<128, 0, 0, 0, 2><<<dim3(8, 32, 2), 256, 0, stream>>>(
        hbuf, wbf + 8388608, bf2, bf2, bf2, y0, y1, BL, DM, DFF);
    // 10. out = project(x1 + y0 + y1)
    resproj2_kernel<<<BL, 256, 0, stream>>>(out, y0, y1, out);
}